// Round 1
// baseline (6709.692 us; speedup 1.0000x reference)
//
#include <hip/hip_runtime.h>
#include <math.h>

// ---------------- problem constants ----------------
constexpr int NRES = 384;          // N
constexpr int NSEQ = 256;          // S
constexpr int DM   = 64;           // MSA_S
constexpr int DZ   = 128;          // Z_D
constexpr int NH   = 8;            // H
constexpr int DH   = 32;           // C_H
constexpr int HC   = NH * DH;      // 256
constexpr int DOP  = 32;           // C_OPM
constexpr int FF   = 4 * DM;       // 256

constexpr int NPAIR = NRES * NRES;         // 147456
constexpr int NROWS = NSEQ * NRES;         // 98304
constexpr int ZTOT  = NPAIR * DZ;          // 18874368
constexpr int ICHUNK = 48;                 // i-rows per OPM chunk (384/48 = 8 chunks)

__device__ __forceinline__ float wred_sum(float v) {
    #pragma unroll
    for (int off = 32; off; off >>= 1) v += __shfl_xor(v, off, 64);
    return v;
}
__device__ __forceinline__ float wred_max(float v) {
    #pragma unroll
    for (int off = 32; off; off >>= 1) v = fmaxf(v, __shfl_xor(v, off, 64));
    return v;
}
__device__ __forceinline__ float sigm(float x) { return 1.0f / (1.0f + expf(-x)); }

// ---------------- K1: pair bias logits ----------------
// wsf[h][i][j] = dot(ln(z[i,j,:]), proj_z_w[h,:]) - (1-token_mask[i,j])*1e9
__global__ __launch_bounds__(256) void k_bias(const float* __restrict__ z,
                                              const float* __restrict__ tmask,
                                              const float* __restrict__ nzw,
                                              const float* __restrict__ nzb,
                                              const float* __restrict__ pzw,
                                              float* __restrict__ wsf) {
    int wave = threadIdx.x >> 6, lane = threadIdx.x & 63;
    int pair = blockIdx.x * 4 + wave;           // < 147456
    const float* zr = z + (size_t)pair * DZ;
    float x0 = zr[lane], x1 = zr[lane + 64];
    float mu = wred_sum(x0 + x1) * (1.0f / 128.0f);
    float d0 = x0 - mu, d1 = x1 - mu;
    float var = wred_sum(d0 * d0 + d1 * d1) * (1.0f / 128.0f);
    float rs = rsqrtf(var + 1e-5f);
    float n0 = d0 * rs * nzw[lane] + nzb[lane];
    float n1 = d1 * rs * nzw[lane + 64] + nzb[lane + 64];
    float mine = 0.0f;
    #pragma unroll
    for (int h = 0; h < NH; h++) {
        float p = n0 * pzw[h * DZ + lane] + n1 * pzw[h * DZ + lane + 64];
        float t = wred_sum(p);
        if (lane == h) mine = t;
    }
    if (lane < NH) {
        float mb = (1.0f - tmask[pair]) * (-1e9f);
        wsf[(size_t)lane * NPAIR + pair] = mine + mb;
    }
}

// ---------------- K2: softmax over j (rows of length 384) ----------------
__global__ __launch_bounds__(64) void k_softmax(float* __restrict__ wsf) {
    int row = blockIdx.x;                       // h*NRES + i
    float* p = wsf + (size_t)row * NRES;
    int lane = threadIdx.x;
    float v[6];
    float mx = -1e30f;
    #pragma unroll
    for (int q = 0; q < 6; q++) { v[q] = p[lane + q * 64]; mx = fmaxf(mx, v[q]); }
    mx = wred_max(mx);
    float sum = 0.0f;
    #pragma unroll
    for (int q = 0; q < 6; q++) { v[q] = expf(v[q] - mx); sum += v[q]; }
    sum = wred_sum(sum);
    float inv = 1.0f / sum;
    #pragma unroll
    for (int q = 0; q < 6; q++) p[lane + q * 64] = v[q] * inv;
}

// ---------------- K3: mn = ln(m); v_t[h][j][s][d] = mn @ proj_m_w^T ----------------
__global__ __launch_bounds__(256) void k_vproj(const float* __restrict__ m,
                                               const float* __restrict__ nmw,
                                               const float* __restrict__ nmb,
                                               const float* __restrict__ pmw,
                                               float* __restrict__ vt) {
    int wave = threadIdx.x >> 6, lane = threadIdx.x & 63;
    int r = blockIdx.x * 4 + wave;              // < 98304
    int s = r / NRES, n = r % NRES;
    __shared__ float mn[4][64];
    float x = m[(size_t)r * DM + lane];
    float mu = wred_sum(x) * (1.0f / 64.0f);
    float d = x - mu;
    float var = wred_sum(d * d) * (1.0f / 64.0f);
    mn[wave][lane] = d * rsqrtf(var + 1e-5f) * nmw[lane] + nmb[lane];
    __syncthreads();
    #pragma unroll
    for (int q = 0; q < 4; q++) {
        int k = lane + 64 * q;
        float acc = 0.0f;
        for (int c4 = 0; c4 < 64; c4 += 4) {
            float4 wv = *(const float4*)&pmw[k * DM + c4];
            float4 mv = *(const float4*)&mn[wave][c4];
            acc += wv.x * mv.x + wv.y * mv.y + wv.z * mv.z + wv.w * mv.w;
        }
        int h = k >> 5, dd = k & 31;
        vt[(((size_t)h * NRES + n) * NSEQ + s) * DH + dd] = acc;
    }
}

// ---------------- K4: attention GEMM per head ----------------
// C[i][s*32+d] = sum_j A[i][j] * B[j][s*32+d]  (per h); M=384,K=384,N=8192
__global__ __launch_bounds__(256) void k_attn(const float* __restrict__ wsf,
                                              const float* __restrict__ vt,
                                              float* __restrict__ ot) {
    int h = blockIdx.z;
    const float* A = wsf + (size_t)h * NPAIR;                  // [384][384]
    const float* B = vt + (size_t)h * NRES * NSEQ * DH;        // [384][8192]
    float* C = ot + (size_t)h * NRES * NSEQ * DH;
    int m0 = blockIdx.y * 64, n0 = blockIdx.x * 64;
    __shared__ float As[16][64];
    __shared__ float Bs[16][64];
    int t = threadIdx.x;
    int ty = t >> 4, tx = t & 15;
    float acc[4][4] = {};
    for (int k0 = 0; k0 < NRES; k0 += 16) {
        {   // stage A (64 rows x 16 k), transposed into As[k][m]
            int row = t >> 2, c4 = (t & 3) * 4;
            float4 av = *(const float4*)&A[(size_t)(m0 + row) * NRES + k0 + c4];
            As[c4 + 0][row] = av.x; As[c4 + 1][row] = av.y;
            As[c4 + 2][row] = av.z; As[c4 + 3][row] = av.w;
            // stage B (16 k x 64 n)
            int kk = t >> 4, n4 = (t & 15) * 4;
            float4 bv = *(const float4*)&B[(size_t)(k0 + kk) * (NSEQ * DH) + n0 + n4];
            *(float4*)&Bs[kk][n4] = bv;
        }
        __syncthreads();
        #pragma unroll
        for (int k = 0; k < 16; k++) {
            float4 a4 = *(const float4*)&As[k][ty * 4];
            float4 b4 = *(const float4*)&Bs[k][tx * 4];
            float ar[4] = {a4.x, a4.y, a4.z, a4.w};
            float br[4] = {b4.x, b4.y, b4.z, b4.w};
            #pragma unroll
            for (int i2 = 0; i2 < 4; i2++)
                #pragma unroll
                for (int j2 = 0; j2 < 4; j2++)
                    acc[i2][j2] += ar[i2] * br[j2];
        }
        __syncthreads();
    }
    #pragma unroll
    for (int r = 0; r < 4; r++) {
        float4 o4 = make_float4(acc[r][0], acc[r][1], acc[r][2], acc[r][3]);
        *(float4*)&C[(size_t)(m0 + ty * 4 + r) * (NSEQ * DH) + n0 + tx * 4] = o4;
    }
}

// ---------------- K5: gate + PWA output projection ----------------
__global__ __launch_bounds__(256) void k_pwaout(const float* __restrict__ m,
                                                const float* __restrict__ nmw,
                                                const float* __restrict__ nmb,
                                                const float* __restrict__ pgw,
                                                const float* __restrict__ ot,
                                                const float* __restrict__ pow_,
                                                float* __restrict__ mout) {
    int wave = threadIdx.x >> 6, lane = threadIdx.x & 63;
    int r = blockIdx.x * 4 + wave;
    int s = r / NRES, n = r % NRES;
    __shared__ float mn[4][64];
    __shared__ float go[4][256];
    float x = m[(size_t)r * DM + lane];
    float mu = wred_sum(x) * (1.0f / 64.0f);
    float d = x - mu;
    float var = wred_sum(d * d) * (1.0f / 64.0f);
    mn[wave][lane] = d * rsqrtf(var + 1e-5f) * nmw[lane] + nmb[lane];
    __syncthreads();
    #pragma unroll
    for (int q = 0; q < 4; q++) {
        int k = lane + 64 * q;
        float acc = 0.0f;
        for (int c4 = 0; c4 < 64; c4 += 4) {
            float4 wv = *(const float4*)&pgw[k * DM + c4];
            float4 mv = *(const float4*)&mn[wave][c4];
            acc += wv.x * mv.x + wv.y * mv.y + wv.z * mv.z + wv.w * mv.w;
        }
        float gk = sigm(acc);
        int h = k >> 5, dd = k & 31;
        float ov = ot[(((size_t)h * NRES + n) * NSEQ + s) * DH + dd];
        go[wave][k] = gk * ov;
    }
    __syncthreads();
    float acc = 0.0f;
    for (int k4 = 0; k4 < 256; k4 += 4) {
        float4 wv = *(const float4*)&pow_[lane * HC + k4];
        float4 gv = *(const float4*)&go[wave][k4];
        acc += wv.x * gv.x + wv.y * gv.y + wv.z * gv.z + wv.w * gv.w;
    }
    mout[(size_t)r * DM + lane] = x + acc;
}

// ---------------- K6: SwiGLU transition (in-place on mout) ----------------
__global__ __launch_bounds__(256) void k_trans(const float* __restrict__ tnw,
                                               const float* __restrict__ tnb,
                                               const float* __restrict__ f1,
                                               const float* __restrict__ f2,
                                               const float* __restrict__ f3,
                                               float* __restrict__ mio) {
    int wave = threadIdx.x >> 6, lane = threadIdx.x & 63;
    int r = blockIdx.x * 4 + wave;
    __shared__ float tn[4][64];
    __shared__ float hh[4][256];
    float x = mio[(size_t)r * DM + lane];
    float mu = wred_sum(x) * (1.0f / 64.0f);
    float d = x - mu;
    float var = wred_sum(d * d) * (1.0f / 64.0f);
    tn[wave][lane] = d * rsqrtf(var + 1e-5f) * tnw[lane] + tnb[lane];
    __syncthreads();
    #pragma unroll
    for (int q = 0; q < 4; q++) {
        int k = lane + 64 * q;
        float a1 = 0.0f, a2 = 0.0f;
        for (int c4 = 0; c4 < 64; c4 += 4) {
            float4 tv = *(const float4*)&tn[wave][c4];
            float4 w1 = *(const float4*)&f1[k * DM + c4];
            float4 w2 = *(const float4*)&f2[k * DM + c4];
            a1 += w1.x * tv.x + w1.y * tv.y + w1.z * tv.z + w1.w * tv.w;
            a2 += w2.x * tv.x + w2.y * tv.y + w2.z * tv.z + w2.w * tv.w;
        }
        hh[wave][k] = (a1 * sigm(a1)) * a2;      // silu(a1)*a2
    }
    __syncthreads();
    float acc = 0.0f;
    for (int k4 = 0; k4 < 256; k4 += 4) {
        float4 wv = *(const float4*)&f3[lane * FF + k4];
        float4 hv = *(const float4*)&hh[wave][k4];
        acc += wv.x * hv.x + wv.y * hv.y + wv.z * hv.z + wv.w * hv.w;
    }
    mio[(size_t)r * DM + lane] = x + acc;
}

// ---------------- K7: a/b projections for OPM ----------------
// abuf[s][n*32+c], bbuf[s][n*32+c]
__global__ __launch_bounds__(256) void k_ab(const float* __restrict__ mfin,
                                            const float* __restrict__ onw,
                                            const float* __restrict__ onb,
                                            const float* __restrict__ paw,
                                            const float* __restrict__ pbw,
                                            const float* __restrict__ smask,
                                            float* __restrict__ abuf,
                                            float* __restrict__ bbuf) {
    int wave = threadIdx.x >> 6, lane = threadIdx.x & 63;
    int r = blockIdx.x * 4 + wave;
    int s = r / NRES, n = r % NRES;
    __shared__ float mn[4][64];
    float x = mfin[(size_t)r * DM + lane];
    float mu = wred_sum(x) * (1.0f / 64.0f);
    float d = x - mu;
    float var = wred_sum(d * d) * (1.0f / 64.0f);
    mn[wave][lane] = d * rsqrtf(var + 1e-5f) * onw[lane] + onb[lane];
    __syncthreads();
    float msk = smask[r];
    int half = lane >> 5, c = lane & 31;
    const float* w = half ? pbw : paw;
    float acc = 0.0f;
    for (int c4 = 0; c4 < 64; c4 += 4) {
        float4 wv = *(const float4*)&w[c * DM + c4];
        float4 mv = *(const float4*)&mn[wave][c4];
        acc += wv.x * mv.x + wv.y * mv.y + wv.z * mv.z + wv.w * mv.w;
    }
    acc *= msk;
    float* dst = half ? bbuf : abuf;
    dst[(size_t)s * (NRES * DOP) + n * DOP + c] = acc;
}

// ---------------- K8: mask pair-count sum ----------------
__global__ __launch_bounds__(256) void k_msum(const float* __restrict__ smask,
                                              float* __restrict__ msum) {
    int t = blockIdx.x * 256 + threadIdx.x;     // < 147456
    int i = t / NRES, j = t % NRES;
    float sum = 0.0f;
    for (int s = 0; s < NSEQ; s++)
        sum += smask[s * NRES + i] * smask[s * NRES + j];
    msum[t] = fmaxf(sum, 1.0f);
}

// ---------------- K9: OPM chunk GEMM (A^T B over s) ----------------
// opmc[(il*384+j)*1024 + c*32+d] = sum_s abuf[s][(ib+il)*32+c] * bbuf[s][j*32+d]
__global__ __launch_bounds__(256) void k_opm_gemm(const float* __restrict__ abuf,
                                                  const float* __restrict__ bbuf,
                                                  int ib,
                                                  float* __restrict__ opmc) {
    int m0 = blockIdx.y * 64;                   // over 1536 (il,c)
    int n0 = blockIdx.x * 64;                   // over 12288 (j,d)
    __shared__ float As[16][64];
    __shared__ float Bs[16][64];
    int t = threadIdx.x;
    int ty = t >> 4, tx = t & 15;
    float acc[4][4] = {};
    const int LD = NRES * DOP;                  // 12288
    for (int k0 = 0; k0 < NSEQ; k0 += 16) {
        int kk = t >> 4, x4 = (t & 15) * 4;
        *(float4*)&As[kk][x4] = *(const float4*)&abuf[(size_t)(k0 + kk) * LD + ib * DOP + m0 + x4];
        *(float4*)&Bs[kk][x4] = *(const float4*)&bbuf[(size_t)(k0 + kk) * LD + n0 + x4];
        __syncthreads();
        #pragma unroll
        for (int k = 0; k < 16; k++) {
            float4 a4 = *(const float4*)&As[k][ty * 4];
            float4 b4 = *(const float4*)&Bs[k][tx * 4];
            float ar[4] = {a4.x, a4.y, a4.z, a4.w};
            float br[4] = {b4.x, b4.y, b4.z, b4.w};
            #pragma unroll
            for (int i2 = 0; i2 < 4; i2++)
                #pragma unroll
                for (int j2 = 0; j2 < 4; j2++)
                    acc[i2][j2] += ar[i2] * br[j2];
        }
        __syncthreads();
    }
    #pragma unroll
    for (int r = 0; r < 4; r++) {
        int mm = m0 + ty * 4 + r;
        int il = mm >> 5, c = mm & 31;
        int nn = n0 + tx * 4;
        int j = nn >> 5, dd = nn & 31;
        float4 o4 = make_float4(acc[r][0], acc[r][1], acc[r][2], acc[r][3]);
        *(float4*)&opmc[((size_t)(il * NRES + j) << 10) + (c << 5) + dd] = o4;
    }
}

// ---------------- K10: OPM projection + residual into z out ----------------
// zout[G][e] = zin[G][e] + (sum_k opmc[p][k]*W[e][k]) / msum[G] + bias[e]
__global__ __launch_bounds__(256) void k_opm_proj(const float* __restrict__ opmc,
                                                  const float* __restrict__ W,
                                                  const float* __restrict__ bias,
                                                  const float* __restrict__ msum,
                                                  const float* __restrict__ zin,
                                                  float* __restrict__ zout,
                                                  int ib) {
    int m0 = blockIdx.y * 64;                   // over 18432 p
    int n0 = blockIdx.x * 64;                   // over 128 e
    __shared__ float As[16][64];
    __shared__ float Bs[16][64];
    int t = threadIdx.x;
    int ty = t >> 4, tx = t & 15;
    float acc[4][4] = {};
    for (int k0 = 0; k0 < 1024; k0 += 16) {
        {   // stage opm tile transposed
            int row = t >> 2, c4 = (t & 3) * 4;
            float4 av = *(const float4*)&opmc[((size_t)(m0 + row) << 10) + k0 + c4];
            As[c4 + 0][row] = av.x; As[c4 + 1][row] = av.y;
            As[c4 + 2][row] = av.z; As[c4 + 3][row] = av.w;
            // stage W^T tile: Bs[k][e] = W[(n0+e)*1024 + k0+k]
            int e = t >> 2, k4 = (t & 3) * 4;
            float4 wv = *(const float4*)&W[(size_t)(n0 + e) * 1024 + k0 + k4];
            Bs[k4 + 0][e] = wv.x; Bs[k4 + 1][e] = wv.y;
            Bs[k4 + 2][e] = wv.z; Bs[k4 + 3][e] = wv.w;
        }
        __syncthreads();
        #pragma unroll
        for (int k = 0; k < 16; k++) {
            float4 a4 = *(const float4*)&As[k][ty * 4];
            float4 b4 = *(const float4*)&Bs[k][tx * 4];
            float ar[4] = {a4.x, a4.y, a4.z, a4.w};
            float br[4] = {b4.x, b4.y, b4.z, b4.w};
            #pragma unroll
            for (int i2 = 0; i2 < 4; i2++)
                #pragma unroll
                for (int j2 = 0; j2 < 4; j2++)
                    acc[i2][j2] += ar[i2] * br[j2];
        }
        __syncthreads();
    }
    #pragma unroll
    for (int r = 0; r < 4; r++) {
        int p = m0 + ty * 4 + r;
        size_t G = (size_t)ib * NRES + p;       // global pair index
        float inv = 1.0f / msum[G];
        int e = n0 + tx * 4;
        float4 zv = *(const float4*)&zin[G * DZ + e];
        float4 o4;
        o4.x = zv.x + acc[r][0] * inv + bias[e + 0];
        o4.y = zv.y + acc[r][1] * inv + bias[e + 1];
        o4.z = zv.z + acc[r][2] * inv + bias[e + 2];
        o4.w = zv.w + acc[r][3] * inv + bias[e + 3];
        *(float4*)&zout[G * DZ + e] = o4;
    }
}

// ---------------- launch ----------------
extern "C" void kernel_launch(void* const* d_in, const int* in_sizes, int n_in,
                              void* d_out, int out_size, void* d_ws, size_t ws_size,
                              hipStream_t stream) {
    const float* z     = (const float*)d_in[0];
    const float* m     = (const float*)d_in[1];
    const float* tmask = (const float*)d_in[2];
    const float* smask = (const float*)d_in[3];
    const float* nzw   = (const float*)d_in[4];
    const float* nzb   = (const float*)d_in[5];
    const float* pzw   = (const float*)d_in[6];
    const float* nmw   = (const float*)d_in[7];
    const float* nmb   = (const float*)d_in[8];
    const float* pmw   = (const float*)d_in[9];
    const float* pgw   = (const float*)d_in[10];
    const float* pow_  = (const float*)d_in[11];
    const float* tnw   = (const float*)d_in[12];
    const float* tnb   = (const float*)d_in[13];
    const float* f1    = (const float*)d_in[14];
    const float* f2    = (const float*)d_in[15];
    const float* f3    = (const float*)d_in[16];
    const float* onw   = (const float*)d_in[17];
    const float* onb   = (const float*)d_in[18];
    const float* paw   = (const float*)d_in[19];
    const float* pbw   = (const float*)d_in[20];
    const float* opW   = (const float*)d_in[21];
    const float* opB   = (const float*)d_in[22];

    float* zout = (float*)d_out;
    float* mout = zout + ZTOT;

    float* ws   = (float*)d_ws;
    float* wsf  = ws;                               // 1,179,648
    float* vt   = wsf + (size_t)NH * NPAIR;         // 25,165,824
    float* ot   = vt + (size_t)NH * NRES * NSEQ * DH;
    float* abuf = ot + (size_t)NH * NRES * NSEQ * DH;
    float* bbuf = abuf + (size_t)NSEQ * NRES * DOP;
    float* msum = bbuf + (size_t)NSEQ * NRES * DOP;
    float* opmc = vt;                               // alias: vt dead after K4/K5

    // PairWeightedAveraging
    k_bias<<<NPAIR / 4, 256, 0, stream>>>(z, tmask, nzw, nzb, pzw, wsf);
    k_softmax<<<NH * NRES, 64, 0, stream>>>(wsf);
    k_vproj<<<NROWS / 4, 256, 0, stream>>>(m, nmw, nmb, pmw, vt);
    k_attn<<<dim3((NSEQ * DH) / 64, NRES / 64, NH), 256, 0, stream>>>(wsf, vt, ot);
    k_pwaout<<<NROWS / 4, 256, 0, stream>>>(m, nmw, nmb, pgw, ot, pow_, mout);
    // Transition (in place on mout)
    k_trans<<<NROWS / 4, 256, 0, stream>>>(tnw, tnb, f1, f2, f3, mout);
    // OuterProductMean
    k_ab<<<NROWS / 4, 256, 0, stream>>>(mout, onw, onb, paw, pbw, smask, abuf, bbuf);
    k_msum<<<NPAIR / 256, 256, 0, stream>>>(smask, msum);
    for (int cb = 0; cb < NRES / ICHUNK; cb++) {
        int ib = cb * ICHUNK;
        k_opm_gemm<<<dim3((NRES * DOP) / 64, (ICHUNK * DOP) / 64), 256, 0, stream>>>(abuf, bbuf, ib, opmc);
        k_opm_proj<<<dim3(DZ / 64, (ICHUNK * NRES) / 64), 256, 0, stream>>>(opmc, opW, opB, msum, z, zout, ib);
    }
}

// Round 2
// 2923.074 us; speedup vs baseline: 2.2954x; 2.2954x over previous
//
#include <hip/hip_runtime.h>
#include <math.h>

// ---------------- problem constants ----------------
constexpr int NRES = 384;          // N
constexpr int NSEQ = 256;          // S
constexpr int DM   = 64;           // MSA_S
constexpr int DZ   = 128;          // Z_D
constexpr int NH   = 8;            // H
constexpr int DH   = 32;           // C_H
constexpr int HC   = NH * DH;      // 256
constexpr int DOP  = 32;           // C_OPM
constexpr int FF   = 4 * DM;       // 256

constexpr int NPAIR = NRES * NRES;         // 147456
constexpr int NROWS = NSEQ * NRES;         // 98304
constexpr int ZTOT  = NPAIR * DZ;          // 18874368
constexpr int SD    = NSEQ * DH;           // 8192
constexpr int ICHUNK = 48;                 // i-rows per OPM chunk (8 chunks)

typedef unsigned short ushort_t;
typedef __attribute__((ext_vector_type(8))) short short8;
typedef __attribute__((ext_vector_type(4))) float f32x4;

__device__ __forceinline__ float wred_sum(float v) {
    #pragma unroll
    for (int off = 32; off; off >>= 1) v += __shfl_xor(v, off, 64);
    return v;
}
__device__ __forceinline__ float wred_max(float v) {
    #pragma unroll
    for (int off = 32; off; off >>= 1) v = fmaxf(v, __shfl_xor(v, off, 64));
    return v;
}
__device__ __forceinline__ float sigm(float x) { return 1.0f / (1.0f + expf(-x)); }
__device__ __forceinline__ ushort_t cvt_bf(float f) {
    unsigned u = __float_as_uint(f);
    unsigned r = (u + 0x7FFFu + ((u >> 16) & 1u)) >> 16;
    return (ushort_t)r;
}
__device__ __forceinline__ float cvt_f(ushort_t h) {
    return __uint_as_float(((unsigned)h) << 16);
}
__device__ __forceinline__ f32x4 mfma16(short8 a, short8 b, f32x4 c) {
    return __builtin_amdgcn_mfma_f32_16x16x32_bf16(a, b, c, 0, 0, 0);
}

// ---------------- K0: weights -> bf16 ----------------
__global__ __launch_bounds__(256) void k_prep(const float* __restrict__ f1,
                                              const float* __restrict__ f2,
                                              const float* __restrict__ f3,
                                              const float* __restrict__ opW,
                                              ushort_t* __restrict__ f1b,
                                              ushort_t* __restrict__ f2b,
                                              ushort_t* __restrict__ f3b,
                                              ushort_t* __restrict__ opWb) {
    int i = blockIdx.x * 256 + threadIdx.x;      // 131072 threads
    opWb[i] = cvt_bf(opW[i]);
    if (i < FF * DM) {
        f1b[i] = cvt_bf(f1[i]);
        f2b[i] = cvt_bf(f2[i]);
        f3b[i] = cvt_bf(f3[i]);
    }
}

// ---------------- K1: pair bias logits ----------------
__global__ __launch_bounds__(256) void k_bias(const float* __restrict__ z,
                                              const float* __restrict__ tmask,
                                              const float* __restrict__ nzw,
                                              const float* __restrict__ nzb,
                                              const float* __restrict__ pzw,
                                              float* __restrict__ wsf) {
    int wave = threadIdx.x >> 6, lane = threadIdx.x & 63;
    int pair = blockIdx.x * 4 + wave;
    const float* zr = z + (size_t)pair * DZ;
    float x0 = zr[lane], x1 = zr[lane + 64];
    float mu = wred_sum(x0 + x1) * (1.0f / 128.0f);
    float d0 = x0 - mu, d1 = x1 - mu;
    float var = wred_sum(d0 * d0 + d1 * d1) * (1.0f / 128.0f);
    float rs = rsqrtf(var + 1e-5f);
    float n0 = d0 * rs * nzw[lane] + nzb[lane];
    float n1 = d1 * rs * nzw[lane + 64] + nzb[lane + 64];
    float mine = 0.0f;
    #pragma unroll
    for (int h = 0; h < NH; h++) {
        float p = n0 * pzw[h * DZ + lane] + n1 * pzw[h * DZ + lane + 64];
        float t = wred_sum(p);
        if (lane == h) mine = t;
    }
    if (lane < NH) {
        float mb = (1.0f - tmask[pair]) * (-1e9f);
        wsf[(size_t)lane * NPAIR + pair] = mine + mb;
    }
}

// ---------------- K2: softmax over j -> bf16 ----------------
__global__ __launch_bounds__(64) void k_softmax(const float* __restrict__ wsf,
                                                ushort_t* __restrict__ wsb) {
    int row = blockIdx.x;                       // h*NRES + i
    const float* p = wsf + (size_t)row * NRES;
    ushort_t* o = wsb + (size_t)row * NRES;
    int lane = threadIdx.x;
    float v[6];
    float mx = -1e30f;
    #pragma unroll
    for (int q = 0; q < 6; q++) { v[q] = p[lane + q * 64]; mx = fmaxf(mx, v[q]); }
    mx = wred_max(mx);
    float sum = 0.0f;
    #pragma unroll
    for (int q = 0; q < 6; q++) { v[q] = expf(v[q] - mx); sum += v[q]; }
    sum = wred_sum(sum);
    float inv = 1.0f / sum;
    #pragma unroll
    for (int q = 0; q < 6; q++) o[lane + q * 64] = cvt_bf(v[q] * inv);
}

// ---------------- K3: mn = ln(m); vt[h][j][s*32+d] bf16 ----------------
__global__ __launch_bounds__(256) void k_vproj(const float* __restrict__ m,
                                               const float* __restrict__ nmw,
                                               const float* __restrict__ nmb,
                                               const float* __restrict__ pmw,
                                               ushort_t* __restrict__ vt) {
    int wave = threadIdx.x >> 6, lane = threadIdx.x & 63;
    int r = blockIdx.x * 4 + wave;
    int s = r / NRES, n = r % NRES;
    __shared__ float mn[4][64];
    float x = m[(size_t)r * DM + lane];
    float mu = wred_sum(x) * (1.0f / 64.0f);
    float d = x - mu;
    float var = wred_sum(d * d) * (1.0f / 64.0f);
    mn[wave][lane] = d * rsqrtf(var + 1e-5f) * nmw[lane] + nmb[lane];
    __syncthreads();
    #pragma unroll
    for (int q = 0; q < 4; q++) {
        int k = lane + 64 * q;
        float acc = 0.0f;
        for (int c4 = 0; c4 < 64; c4 += 4) {
            float4 wv = *(const float4*)&pmw[k * DM + c4];
            float4 mv = *(const float4*)&mn[wave][c4];
            acc += wv.x * mv.x + wv.y * mv.y + wv.z * mv.z + wv.w * mv.w;
        }
        int h = k >> 5, dd = k & 31;
        vt[(((size_t)h * NRES + n) * NSEQ + s) * DH + dd] = cvt_bf(acc);
    }
}

// ---------------- generic 64x64 bf16 transpose: dst[c][r] = src[r][c] ----------------
__global__ __launch_bounds__(256) void k_tr(const ushort_t* __restrict__ src,
                                            ushort_t* __restrict__ dst,
                                            int R, int C) {
    size_t bs = (size_t)R * C;
    const ushort_t* s = src + blockIdx.z * bs;
    ushort_t* d = dst + blockIdx.z * bs;
    int r0 = blockIdx.y * 64, c0 = blockIdx.x * 64;
    __shared__ ushort_t tile[64][72];
    int t = threadIdx.x;
    int tr = t >> 2, tc = (t & 3) * 16;
    *(short8*)&tile[tr][tc]     = *(const short8*)&s[(size_t)(r0 + tr) * C + c0 + tc];
    *(short8*)&tile[tr][tc + 8] = *(const short8*)&s[(size_t)(r0 + tr) * C + c0 + tc + 8];
    __syncthreads();
    short8 o0, o1;
    #pragma unroll
    for (int i = 0; i < 8; i++) {
        o0[i] = (short)tile[tc + i][tr];
        o1[i] = (short)tile[tc + 8 + i][tr];
    }
    *(short8*)&d[(size_t)(c0 + tr) * R + r0 + tc]     = o0;
    *(short8*)&d[(size_t)(c0 + tr) * R + r0 + tc + 8] = o1;
}

// ---------------- K4: attention GEMM per head (bf16 MFMA, 64x64 tile) ----------------
__global__ __launch_bounds__(256) void k_attn_mfma(const ushort_t* __restrict__ wsb,
                                                   const ushort_t* __restrict__ vtt,
                                                   ushort_t* __restrict__ otb) {
    int h = blockIdx.z;
    const ushort_t* A  = wsb + (size_t)h * NPAIR;        // [384][384]
    const ushort_t* Bt = vtt + (size_t)h * SD * NRES;    // [8192][384]
    ushort_t* C = otb + (size_t)h * NRES * SD;
    int m0 = blockIdx.y * 64, n0 = blockIdx.x * 64;
    __shared__ ushort_t Al[64][40];
    __shared__ ushort_t Bl[64][40];
    int t = threadIdx.x;
    int srow = t >> 2, sko = (t & 3) * 8;
    int wave = t >> 6, lane = t & 63;
    int wr = (wave >> 1) * 32, wc = (wave & 1) * 32;
    int lk = (lane >> 4) * 8, lr = lane & 15;
    f32x4 acc[2][2] = {};
    for (int k0 = 0; k0 < NRES; k0 += 32) {
        *(short8*)&Al[srow][sko] = *(const short8*)&A[(size_t)(m0 + srow) * NRES + k0 + sko];
        *(short8*)&Bl[srow][sko] = *(const short8*)&Bt[(size_t)(n0 + srow) * NRES + k0 + sko];
        __syncthreads();
        short8 a0 = *(const short8*)&Al[wr + lr][lk];
        short8 a1 = *(const short8*)&Al[wr + 16 + lr][lk];
        short8 b0 = *(const short8*)&Bl[wc + lr][lk];
        short8 b1 = *(const short8*)&Bl[wc + 16 + lr][lk];
        acc[0][0] = mfma16(a0, b0, acc[0][0]);
        acc[0][1] = mfma16(a0, b1, acc[0][1]);
        acc[1][0] = mfma16(a1, b0, acc[1][0]);
        acc[1][1] = mfma16(a1, b1, acc[1][1]);
        __syncthreads();
    }
    #pragma unroll
    for (int ri = 0; ri < 2; ri++)
        #pragma unroll
        for (int ci = 0; ci < 2; ci++) {
            int row0 = m0 + wr + 16 * ri + (lane >> 4) * 4;
            int col  = n0 + wc + 16 * ci + lr;
            #pragma unroll
            for (int r = 0; r < 4; r++)
                C[(size_t)(row0 + r) * SD + col] = cvt_bf(acc[ri][ci][r]);
        }
}

// ---------------- K5: gate + PWA output projection ----------------
__global__ __launch_bounds__(256) void k_pwaout(const float* __restrict__ m,
                                                const float* __restrict__ nmw,
                                                const float* __restrict__ nmb,
                                                const float* __restrict__ pgw,
                                                const ushort_t* __restrict__ otb,
                                                const float* __restrict__ pow_,
                                                float* __restrict__ mout) {
    int wave = threadIdx.x >> 6, lane = threadIdx.x & 63;
    int r = blockIdx.x * 4 + wave;
    int s = r / NRES, n = r % NRES;
    __shared__ float mn[4][64];
    __shared__ float go[4][256];
    float x = m[(size_t)r * DM + lane];
    float mu = wred_sum(x) * (1.0f / 64.0f);
    float d = x - mu;
    float var = wred_sum(d * d) * (1.0f / 64.0f);
    mn[wave][lane] = d * rsqrtf(var + 1e-5f) * nmw[lane] + nmb[lane];
    __syncthreads();
    #pragma unroll
    for (int q = 0; q < 4; q++) {
        int k = lane + 64 * q;
        float acc = 0.0f;
        for (int c4 = 0; c4 < 64; c4 += 4) {
            float4 wv = *(const float4*)&pgw[k * DM + c4];
            float4 mv = *(const float4*)&mn[wave][c4];
            acc += wv.x * mv.x + wv.y * mv.y + wv.z * mv.z + wv.w * mv.w;
        }
        float gk = sigm(acc);
        int h = k >> 5, dd = k & 31;
        float ov = cvt_f(otb[((size_t)h * NRES + n) * SD + s * DH + dd]);
        go[wave][k] = gk * ov;
    }
    __syncthreads();
    float acc = 0.0f;
    for (int k4 = 0; k4 < 256; k4 += 4) {
        float4 wv = *(const float4*)&pow_[lane * HC + k4];
        float4 gv = *(const float4*)&go[wave][k4];
        acc += wv.x * gv.x + wv.y * gv.y + wv.z * gv.z + wv.w * gv.w;
    }
    mout[(size_t)r * DM + lane] = x + acc;
}

// ---------------- K6a: LN rows of mout -> bf16 ----------------
__global__ __launch_bounds__(256) void k_ln64(const float* __restrict__ src,
                                              const float* __restrict__ lw,
                                              const float* __restrict__ lb,
                                              ushort_t* __restrict__ dst) {
    int wave = threadIdx.x >> 6, lane = threadIdx.x & 63;
    int r = blockIdx.x * 4 + wave;
    float x = src[(size_t)r * DM + lane];
    float mu = wred_sum(x) * (1.0f / 64.0f);
    float d = x - mu;
    float var = wred_sum(d * d) * (1.0f / 64.0f);
    dst[(size_t)r * DM + lane] = cvt_bf(d * rsqrtf(var + 1e-5f) * lw[lane] + lb[lane]);
}

// ---------------- K6b: fc1/fc2 GEMM + SwiGLU -> hh bf16 ----------------
__global__ __launch_bounds__(256) void k_fc12(const ushort_t* __restrict__ A,
                                              const ushort_t* __restrict__ B1t,
                                              const ushort_t* __restrict__ B2t,
                                              ushort_t* __restrict__ hh) {
    int m0 = blockIdx.y * 64, n0 = blockIdx.x * 64;
    __shared__ ushort_t Al[64][40];
    __shared__ ushort_t B1l[64][40];
    __shared__ ushort_t B2l[64][40];
    int t = threadIdx.x;
    int srow = t >> 2, sko = (t & 3) * 8;
    int wave = t >> 6, lane = t & 63;
    int wr = (wave >> 1) * 32, wc = (wave & 1) * 32;
    int lk = (lane >> 4) * 8, lr = lane & 15;
    f32x4 acc1[2][2] = {}, acc2[2][2] = {};
    for (int k0 = 0; k0 < DM; k0 += 32) {
        *(short8*)&Al[srow][sko]  = *(const short8*)&A[(size_t)(m0 + srow) * DM + k0 + sko];
        *(short8*)&B1l[srow][sko] = *(const short8*)&B1t[(size_t)(n0 + srow) * DM + k0 + sko];
        *(short8*)&B2l[srow][sko] = *(const short8*)&B2t[(size_t)(n0 + srow) * DM + k0 + sko];
        __syncthreads();
        short8 a0 = *(const short8*)&Al[wr + lr][lk];
        short8 a1 = *(const short8*)&Al[wr + 16 + lr][lk];
        short8 p0 = *(const short8*)&B1l[wc + lr][lk];
        short8 p1 = *(const short8*)&B1l[wc + 16 + lr][lk];
        short8 q0 = *(const short8*)&B2l[wc + lr][lk];
        short8 q1 = *(const short8*)&B2l[wc + 16 + lr][lk];
        acc1[0][0] = mfma16(a0, p0, acc1[0][0]);
        acc1[0][1] = mfma16(a0, p1, acc1[0][1]);
        acc1[1][0] = mfma16(a1, p0, acc1[1][0]);
        acc1[1][1] = mfma16(a1, p1, acc1[1][1]);
        acc2[0][0] = mfma16(a0, q0, acc2[0][0]);
        acc2[0][1] = mfma16(a0, q1, acc2[0][1]);
        acc2[1][0] = mfma16(a1, q0, acc2[1][0]);
        acc2[1][1] = mfma16(a1, q1, acc2[1][1]);
        __syncthreads();
    }
    #pragma unroll
    for (int ri = 0; ri < 2; ri++)
        #pragma unroll
        for (int ci = 0; ci < 2; ci++) {
            int row0 = m0 + wr + 16 * ri + (lane >> 4) * 4;
            int col  = n0 + wc + 16 * ci + lr;
            #pragma unroll
            for (int r = 0; r < 4; r++) {
                float a1v = acc1[ri][ci][r], a2v = acc2[ri][ci][r];
                hh[(size_t)(row0 + r) * FF + col] = cvt_bf(a1v * sigm(a1v) * a2v);
            }
        }
}

// ---------------- K6c: fc3 GEMM + residual into mout ----------------
__global__ __launch_bounds__(256) void k_fc3(const ushort_t* __restrict__ A,
                                             const ushort_t* __restrict__ Bt,
                                             float* __restrict__ mio) {
    int m0 = blockIdx.x * 64;
    __shared__ ushort_t Al[64][40];
    __shared__ ushort_t Bl[64][40];
    int t = threadIdx.x;
    int srow = t >> 2, sko = (t & 3) * 8;
    int wave = t >> 6, lane = t & 63;
    int wr = (wave >> 1) * 32, wc = (wave & 1) * 32;
    int lk = (lane >> 4) * 8, lr = lane & 15;
    f32x4 acc[2][2] = {};
    for (int k0 = 0; k0 < FF; k0 += 32) {
        *(short8*)&Al[srow][sko] = *(const short8*)&A[(size_t)(m0 + srow) * FF + k0 + sko];
        *(short8*)&Bl[srow][sko] = *(const short8*)&Bt[(size_t)srow * FF + k0 + sko];
        __syncthreads();
        short8 a0 = *(const short8*)&Al[wr + lr][lk];
        short8 a1 = *(const short8*)&Al[wr + 16 + lr][lk];
        short8 b0 = *(const short8*)&Bl[wc + lr][lk];
        short8 b1 = *(const short8*)&Bl[wc + 16 + lr][lk];
        acc[0][0] = mfma16(a0, b0, acc[0][0]);
        acc[0][1] = mfma16(a0, b1, acc[0][1]);
        acc[1][0] = mfma16(a1, b0, acc[1][0]);
        acc[1][1] = mfma16(a1, b1, acc[1][1]);
        __syncthreads();
    }
    #pragma unroll
    for (int ri = 0; ri < 2; ri++)
        #pragma unroll
        for (int ci = 0; ci < 2; ci++) {
            int row0 = m0 + wr + 16 * ri + (lane >> 4) * 4;
            int col  = wc + 16 * ci + lr;
            #pragma unroll
            for (int r = 0; r < 4; r++)
                mio[(size_t)(row0 + r) * DM + col] += acc[ri][ci][r];
        }
}

// ---------------- K7: a/b projections for OPM (bf16 out) ----------------
__global__ __launch_bounds__(256) void k_ab(const float* __restrict__ mfin,
                                            const float* __restrict__ onw,
                                            const float* __restrict__ onb,
                                            const float* __restrict__ paw,
                                            const float* __restrict__ pbw,
                                            const float* __restrict__ smask,
                                            ushort_t* __restrict__ abuf,
                                            ushort_t* __restrict__ bbuf) {
    int wave = threadIdx.x >> 6, lane = threadIdx.x & 63;
    int r = blockIdx.x * 4 + wave;
    int s = r / NRES, n = r % NRES;
    __shared__ float mn[4][64];
    float x = mfin[(size_t)r * DM + lane];
    float mu = wred_sum(x) * (1.0f / 64.0f);
    float d = x - mu;
    float var = wred_sum(d * d) * (1.0f / 64.0f);
    mn[wave][lane] = d * rsqrtf(var + 1e-5f) * onw[lane] + onb[lane];
    __syncthreads();
    float msk = smask[r];
    int half = lane >> 5, c = lane & 31;
    const float* w = half ? pbw : paw;
    float acc = 0.0f;
    for (int c4 = 0; c4 < 64; c4 += 4) {
        float4 wv = *(const float4*)&w[c * DM + c4];
        float4 mv = *(const float4*)&mn[wave][c4];
        acc += wv.x * mv.x + wv.y * mv.y + wv.z * mv.z + wv.w * mv.w;
    }
    acc *= msk;
    ushort_t* dst = half ? bbuf : abuf;
    dst[(size_t)s * (NRES * DOP) + n * DOP + c] = cvt_bf(acc);
}

// ---------------- K8: mask pair-count sum ----------------
__global__ __launch_bounds__(256) void k_msum(const float* __restrict__ smask,
                                              float* __restrict__ msum) {
    int t = blockIdx.x * 256 + threadIdx.x;
    int i = t / NRES, j = t % NRES;
    float sum = 0.0f;
    for (int s = 0; s < NSEQ; s++)
        sum += smask[s * NRES + i] * smask[s * NRES + j];
    msum[t] = fmaxf(sum, 1.0f);
}

// ---------------- K9: OPM outer GEMM (bf16 MFMA, 128x128 tile) ----------------
__global__ __launch_bounds__(256) void k_opm_mfma(const ushort_t* __restrict__ At,
                                                  const ushort_t* __restrict__ Bt,
                                                  ushort_t* __restrict__ opmc) {
    int m0 = blockIdx.y * 128;                  // over 1536 (il,c)
    int n0 = blockIdx.x * 128;                  // over 12288 (j,d)
    __shared__ ushort_t Al[128][40];
    __shared__ ushort_t Bl[128][40];
    int t = threadIdx.x;
    int srow = t >> 1, sko = (t & 1) * 16;
    int wave = t >> 6, lane = t & 63;
    int wr = (wave >> 1) * 64, wc = (wave & 1) * 64;
    int lk = (lane >> 4) * 8, lr = lane & 15;
    f32x4 acc[4][4] = {};
    for (int k0 = 0; k0 < NSEQ; k0 += 32) {
        *(short8*)&Al[srow][sko]     = *(const short8*)&At[(size_t)(m0 + srow) * NSEQ + k0 + sko];
        *(short8*)&Al[srow][sko + 8] = *(const short8*)&At[(size_t)(m0 + srow) * NSEQ + k0 + sko + 8];
        *(short8*)&Bl[srow][sko]     = *(const short8*)&Bt[(size_t)(n0 + srow) * NSEQ + k0 + sko];
        *(short8*)&Bl[srow][sko + 8] = *(const short8*)&Bt[(size_t)(n0 + srow) * NSEQ + k0 + sko + 8];
        __syncthreads();
        short8 af[4], bf[4];
        #pragma unroll
        for (int i = 0; i < 4; i++) {
            af[i] = *(const short8*)&Al[wr + 16 * i + lr][lk];
            bf[i] = *(const short8*)&Bl[wc + 16 * i + lr][lk];
        }
        #pragma unroll
        for (int ri = 0; ri < 4; ri++)
            #pragma unroll
            for (int ci = 0; ci < 4; ci++)
                acc[ri][ci] = mfma16(af[ri], bf[ci], acc[ri][ci]);
        __syncthreads();
    }
    #pragma unroll
    for (int ri = 0; ri < 4; ri++)
        #pragma unroll
        for (int ci = 0; ci < 4; ci++) {
            int mb = m0 + wr + 16 * ri + (lane >> 4) * 4;
            int n  = n0 + wc + 16 * ci + lr;
            int j = n >> 5, dd = n & 31;
            #pragma unroll
            for (int r = 0; r < 4; r++) {
                int mm = mb + r;
                int il = mm >> 5, c = mm & 31;
                opmc[((size_t)(il * NRES + j) << 10) + (c << 5) + dd] = cvt_bf(acc[ri][ci][r]);
            }
        }
}

// ---------------- K10: OPM projection + residual ----------------
__global__ __launch_bounds__(256) void k_proj_mfma(const ushort_t* __restrict__ A,
                                                   const ushort_t* __restrict__ Bt,
                                                   const float* __restrict__ opB,
                                                   const float* __restrict__ msum,
                                                   const float* __restrict__ zin,
                                                   float* __restrict__ zout,
                                                   int ib) {
    int m0 = blockIdx.y * 64, n0 = blockIdx.x * 64;
    __shared__ ushort_t Al[64][40];
    __shared__ ushort_t Bl[64][40];
    int t = threadIdx.x;
    int srow = t >> 2, sko = (t & 3) * 8;
    int wave = t >> 6, lane = t & 63;
    int wr = (wave >> 1) * 32, wc = (wave & 1) * 32;
    int lk = (lane >> 4) * 8, lr = lane & 15;
    f32x4 acc[2][2] = {};
    for (int k0 = 0; k0 < 1024; k0 += 32) {
        *(short8*)&Al[srow][sko] = *(const short8*)&A[(size_t)(m0 + srow) * 1024 + k0 + sko];
        *(short8*)&Bl[srow][sko] = *(const short8*)&Bt[(size_t)(n0 + srow) * 1024 + k0 + sko];
        __syncthreads();
        short8 a0 = *(const short8*)&Al[wr + lr][lk];
        short8 a1 = *(const short8*)&Al[wr + 16 + lr][lk];
        short8 b0 = *(const short8*)&Bl[wc + lr][lk];
        short8 b1 = *(const short8*)&Bl[wc + 16 + lr][lk];
        acc[0][0] = mfma16(a0, b0, acc[0][0]);
        acc[0][1] = mfma16(a0, b1, acc[0][1]);
        acc[1][0] = mfma16(a1, b0, acc[1][0]);
        acc[1][1] = mfma16(a1, b1, acc[1][1]);
        __syncthreads();
    }
    #pragma unroll
    for (int ri = 0; ri < 2; ri++)
        #pragma unroll
        for (int ci = 0; ci < 2; ci++) {
            int row0 = m0 + wr + 16 * ri + (lane >> 4) * 4;
            int col  = n0 + wc + 16 * ci + lr;
            #pragma unroll
            for (int r = 0; r < 4; r++) {
                size_t G = (size_t)ib * NRES + row0 + r;
                float inv = 1.0f / msum[G];
                zout[G * DZ + col] = zin[G * DZ + col] + acc[ri][ci][r] * inv + opB[col];
            }
        }
}

// ---------------- launch ----------------
extern "C" void kernel_launch(void* const* d_in, const int* in_sizes, int n_in,
                              void* d_out, int out_size, void* d_ws, size_t ws_size,
                              hipStream_t stream) {
    const float* z     = (const float*)d_in[0];
    const float* m     = (const float*)d_in[1];
    const float* tmask = (const float*)d_in[2];
    const float* smask = (const float*)d_in[3];
    const float* nzw   = (const float*)d_in[4];
    const float* nzb   = (const float*)d_in[5];
    const float* pzw   = (const float*)d_in[6];
    const float* nmw   = (const float*)d_in[7];
    const float* nmb   = (const float*)d_in[8];
    const float* pmw   = (const float*)d_in[9];
    const float* pgw   = (const float*)d_in[10];
    const float* pow_  = (const float*)d_in[11];
    const float* tnw   = (const float*)d_in[12];
    const float* tnb_  = (const float*)d_in[13];
    const float* f1    = (const float*)d_in[14];
    const float* f2    = (const float*)d_in[15];
    const float* f3    = (const float*)d_in[16];
    const float* onw   = (const float*)d_in[17];
    const float* onb   = (const float*)d_in[18];
    const float* paw   = (const float*)d_in[19];
    const float* pbw   = (const float*)d_in[20];
    const float* opW   = (const float*)d_in[21];
    const float* opB   = (const float*)d_in[22];

    float* zout = (float*)d_out;
    float* mout = zout + ZTOT;

    char* W = (char*)d_ws;
    float*    wsf  = (float*)(W);                       // 4,718,592 B
    ushort_t* wsb  = (ushort_t*)(W + 4718592);          // 2,359,296
    ushort_t* vt   = (ushort_t*)(W + 7077888);          // 50,331,648
    ushort_t* vtt  = (ushort_t*)(W + 57409536);         // 50,331,648
    ushort_t* otb  = (ushort_t*)(W + 107741184);        // 50,331,648
    ushort_t* abuf = (ushort_t*)(W + 158072832);        // 6,291,456
    ushort_t* bbuf = (ushort_t*)(W + 164364288);        // 6,291,456
    ushort_t* abt  = (ushort_t*)(W + 170655744);        // 6,291,456
    ushort_t* bbt  = (ushort_t*)(W + 176947200);        // 6,291,456
    float*    msum = (float*)(W + 183238656);           // 589,824
    ushort_t* f1b  = (ushort_t*)(W + 183828480);        // 32,768
    ushort_t* f2b  = (ushort_t*)(W + 183861248);        // 32,768
    ushort_t* f3b  = (ushort_t*)(W + 183894016);        // 32,768
    ushort_t* opWb = (ushort_t*)(W + 183926784);        // 262,144 -> ~184.2 MB total
    // aliases (regions dead by the time these are used):
    ushort_t* tn_bf = vtt;   // vtt dead after k_attn_mfma
    ushort_t* hh    = otb;   // otb dead after k_pwaout
    ushort_t* opmc  = vt;    // vt dead after k_tr

    k_prep<<<512, 256, 0, stream>>>(f1, f2, f3, opW, f1b, f2b, f3b, opWb);

    // PairWeightedAveraging
    k_bias<<<NPAIR / 4, 256, 0, stream>>>(z, tmask, nzw, nzb, pzw, wsf);
    k_softmax<<<NH * NRES, 64, 0, stream>>>(wsf, wsb);
    k_vproj<<<NROWS / 4, 256, 0, stream>>>(m, nmw, nmb, pmw, vt);
    k_tr<<<dim3(SD / 64, NRES / 64, NH), 256, 0, stream>>>(vt, vtt, NRES, SD);
    k_attn_mfma<<<dim3(SD / 64, NRES / 64, NH), 256, 0, stream>>>(wsb, vtt, otb);
    k_pwaout<<<NROWS / 4, 256, 0, stream>>>(m, nmw, nmb, pgw, otb, pow_, mout);

    // Transition (MFMA)
    k_ln64<<<NROWS / 4, 256, 0, stream>>>(mout, tnw, tnb_, tn_bf);
    k_fc12<<<dim3(FF / 64, NROWS / 64), 256, 0, stream>>>(tn_bf, f1b, f2b, hh);
    k_fc3<<<NROWS / 64, 256, 0, stream>>>(hh, f3b, mout);

    // OuterProductMean
    k_ab<<<NROWS / 4, 256, 0, stream>>>(mout, onw, onb, paw, pbw, smask, abuf, bbuf);
    k_tr<<<dim3((NRES * DOP) / 64, NSEQ / 64, 2), 256, 0, stream>>>(abuf, abt, NSEQ, NRES * DOP);
    k_msum<<<NPAIR / 256, 256, 0, stream>>>(smask, msum);
    for (int cb = 0; cb < NRES / ICHUNK; cb++) {
        int ib = cb * ICHUNK;
        const ushort_t* Achunk = abt + (size_t)(ib * DOP) * NSEQ;
        k_opm_mfma<<<dim3((NRES * DOP) / 128, (ICHUNK * DOP) / 128), 256, 0, stream>>>(Achunk, bbt, opmc);
        k_proj_mfma<<<dim3(DZ / 64, (ICHUNK * NRES) / 64), 256, 0, stream>>>(opmc, opWb, opB, msum, z, zout, ib);
    }
}

// Round 3
// 923.531 us; speedup vs baseline: 7.2653x; 3.1651x over previous
//
#include <hip/hip_runtime.h>
#include <math.h>

// ---------------- problem constants ----------------
constexpr int NRES = 384;          // N
constexpr int NSEQ = 256;          // S
constexpr int DM   = 64;           // MSA_S
constexpr int DZ   = 128;          // Z_D
constexpr int NH   = 8;            // H
constexpr int DH   = 32;           // C_H
constexpr int HC   = NH * DH;      // 256
constexpr int DOP  = 32;           // C_OPM
constexpr int FF   = 4 * DM;       // 256

constexpr int NPAIR = NRES * NRES;         // 147456
constexpr int NROWS = NSEQ * NRES;         // 98304
constexpr int ZTOT  = NPAIR * DZ;          // 18874368
constexpr int SD    = NSEQ * DH;           // 8192
constexpr int ICHUNK = 48;                 // i-rows per OPM chunk (8 chunks)

typedef unsigned short ushort_t;
typedef __attribute__((ext_vector_type(8))) short short8;
typedef __attribute__((ext_vector_type(4))) float f32x4;

__device__ __forceinline__ float wred_sum(float v) {
    #pragma unroll
    for (int off = 32; off; off >>= 1) v += __shfl_xor(v, off, 64);
    return v;
}
__device__ __forceinline__ float wred_max(float v) {
    #pragma unroll
    for (int off = 32; off; off >>= 1) v = fmaxf(v, __shfl_xor(v, off, 64));
    return v;
}
__device__ __forceinline__ float sigm(float x) { return 1.0f / (1.0f + expf(-x)); }
__device__ __forceinline__ ushort_t cvt_bf(float f) {
    unsigned u = __float_as_uint(f);
    unsigned r = (u + 0x7FFFu + ((u >> 16) & 1u)) >> 16;
    return (ushort_t)r;
}
__device__ __forceinline__ float cvt_f(ushort_t h) {
    return __uint_as_float(((unsigned)h) << 16);
}
__device__ __forceinline__ f32x4 mfma16(short8 a, short8 b, f32x4 c) {
    return __builtin_amdgcn_mfma_f32_16x16x32_bf16(a, b, c, 0, 0, 0);
}

// ---------------- K0: weights -> bf16 ----------------
__global__ __launch_bounds__(256) void k_prep(const float* __restrict__ f1,
                                              const float* __restrict__ f2,
                                              const float* __restrict__ f3,
                                              const float* __restrict__ opW,
                                              const float* __restrict__ pmw,
                                              const float* __restrict__ pgw,
                                              const float* __restrict__ pow_,
                                              ushort_t* __restrict__ f1b,
                                              ushort_t* __restrict__ f2b,
                                              ushort_t* __restrict__ f3b,
                                              ushort_t* __restrict__ opWb,
                                              ushort_t* __restrict__ pmwb,
                                              ushort_t* __restrict__ pgwb,
                                              ushort_t* __restrict__ powb) {
    int i = blockIdx.x * 256 + threadIdx.x;      // 131072 threads
    opWb[i] = cvt_bf(opW[i]);
    if (i < FF * DM) {
        f1b[i] = cvt_bf(f1[i]);
        f2b[i] = cvt_bf(f2[i]);
        f3b[i] = cvt_bf(f3[i]);
    }
    if (i < HC * DM) {
        pmwb[i] = cvt_bf(pmw[i]);
        pgwb[i] = cvt_bf(pgw[i]);
        powb[i] = cvt_bf(pow_[i]);
    }
}

// ---------------- K1: pair bias logits ----------------
__global__ __launch_bounds__(256) void k_bias(const float* __restrict__ z,
                                              const float* __restrict__ tmask,
                                              const float* __restrict__ nzw,
                                              const float* __restrict__ nzb,
                                              const float* __restrict__ pzw,
                                              float* __restrict__ wsf) {
    int wave = threadIdx.x >> 6, lane = threadIdx.x & 63;
    int pair = blockIdx.x * 4 + wave;
    const float* zr = z + (size_t)pair * DZ;
    float x0 = zr[lane], x1 = zr[lane + 64];
    float mu = wred_sum(x0 + x1) * (1.0f / 128.0f);
    float d0 = x0 - mu, d1 = x1 - mu;
    float var = wred_sum(d0 * d0 + d1 * d1) * (1.0f / 128.0f);
    float rs = rsqrtf(var + 1e-5f);
    float n0 = d0 * rs * nzw[lane] + nzb[lane];
    float n1 = d1 * rs * nzw[lane + 64] + nzb[lane + 64];
    float mine = 0.0f;
    #pragma unroll
    for (int h = 0; h < NH; h++) {
        float p = n0 * pzw[h * DZ + lane] + n1 * pzw[h * DZ + lane + 64];
        float t = wred_sum(p);
        if (lane == h) mine = t;
    }
    if (lane < NH) {
        float mb = (1.0f - tmask[pair]) * (-1e9f);
        wsf[(size_t)lane * NPAIR + pair] = mine + mb;
    }
}

// ---------------- K2: softmax over j -> bf16 ----------------
__global__ __launch_bounds__(64) void k_softmax(const float* __restrict__ wsf,
                                                ushort_t* __restrict__ wsb) {
    int row = blockIdx.x;                       // h*NRES + i
    const float* p = wsf + (size_t)row * NRES;
    ushort_t* o = wsb + (size_t)row * NRES;
    int lane = threadIdx.x;
    float v[6];
    float mx = -1e30f;
    #pragma unroll
    for (int q = 0; q < 6; q++) { v[q] = p[lane + q * 64]; mx = fmaxf(mx, v[q]); }
    mx = wred_max(mx);
    float sum = 0.0f;
    #pragma unroll
    for (int q = 0; q < 6; q++) { v[q] = expf(v[q] - mx); sum += v[q]; }
    sum = wred_sum(sum);
    float inv = 1.0f / sum;
    #pragma unroll
    for (int q = 0; q < 6; q++) o[lane + q * 64] = cvt_bf(v[q] * inv);
}

// ---------------- K3: LN rows (64-wide) fp32 -> bf16 ----------------
__global__ __launch_bounds__(256) void k_ln64(const float* __restrict__ src,
                                              const float* __restrict__ lw,
                                              const float* __restrict__ lb,
                                              ushort_t* __restrict__ dst) {
    int wave = threadIdx.x >> 6, lane = threadIdx.x & 63;
    int r = blockIdx.x * 4 + wave;
    float x = src[(size_t)r * DM + lane];
    float mu = wred_sum(x) * (1.0f / 64.0f);
    float d = x - mu;
    float var = wred_sum(d * d) * (1.0f / 64.0f);
    dst[(size_t)r * DM + lane] = cvt_bf(d * rsqrtf(var + 1e-5f) * lw[lane] + lb[lane]);
}

// ---------------- K3b: v projection GEMM (mnb @ pmwb^T) -> vt[h][n][s][d] ----------------
__global__ __launch_bounds__(256) void k_vproj_mfma(const ushort_t* __restrict__ A,
                                                    const ushort_t* __restrict__ Bt,
                                                    ushort_t* __restrict__ vt) {
    int m0 = blockIdx.y * 64, n0 = blockIdx.x * 64;
    __shared__ ushort_t Al[64][40];
    __shared__ ushort_t Bl[64][40];
    int t = threadIdx.x;
    int srow = t >> 2, sko = (t & 3) * 8;
    int wave = t >> 6, lane = t & 63;
    int wr = (wave >> 1) * 32, wc = (wave & 1) * 32;
    int lk = (lane >> 4) * 8, lr = lane & 15;
    f32x4 acc[2][2] = {};
    for (int k0 = 0; k0 < DM; k0 += 32) {
        *(short8*)&Al[srow][sko] = *(const short8*)&A[(size_t)(m0 + srow) * DM + k0 + sko];
        *(short8*)&Bl[srow][sko] = *(const short8*)&Bt[(size_t)(n0 + srow) * DM + k0 + sko];
        __syncthreads();
        short8 a0 = *(const short8*)&Al[wr + lr][lk];
        short8 a1 = *(const short8*)&Al[wr + 16 + lr][lk];
        short8 b0 = *(const short8*)&Bl[wc + lr][lk];
        short8 b1 = *(const short8*)&Bl[wc + 16 + lr][lk];
        acc[0][0] = mfma16(a0, b0, acc[0][0]);
        acc[0][1] = mfma16(a0, b1, acc[0][1]);
        acc[1][0] = mfma16(a1, b0, acc[1][0]);
        acc[1][1] = mfma16(a1, b1, acc[1][1]);
        __syncthreads();
    }
    #pragma unroll
    for (int ri = 0; ri < 2; ri++)
        #pragma unroll
        for (int ci = 0; ci < 2; ci++) {
            int row0 = m0 + wr + 16 * ri + (lane >> 4) * 4;
            int col  = n0 + wc + 16 * ci + lr;      // k = h*32+dd
            int h = col >> 5, dd = col & 31;
            #pragma unroll
            for (int r = 0; r < 4; r++) {
                int rr = row0 + r;                  // s*NRES+n
                int s = rr / NRES, n = rr % NRES;
                vt[(((size_t)h * NRES + n) * NSEQ + s) * DH + dd] = cvt_bf(acc[ri][ci][r]);
            }
        }
}

// ---------------- generic 64x64 bf16 transpose ----------------
__global__ __launch_bounds__(256) void k_tr(const ushort_t* __restrict__ src,
                                            ushort_t* __restrict__ dst,
                                            int R, int C) {
    size_t bs = (size_t)R * C;
    const ushort_t* s = src + blockIdx.z * bs;
    ushort_t* d = dst + blockIdx.z * bs;
    int r0 = blockIdx.y * 64, c0 = blockIdx.x * 64;
    __shared__ ushort_t tile[64][72];
    int t = threadIdx.x;
    int tr = t >> 2, tc = (t & 3) * 16;
    *(short8*)&tile[tr][tc]     = *(const short8*)&s[(size_t)(r0 + tr) * C + c0 + tc];
    *(short8*)&tile[tr][tc + 8] = *(const short8*)&s[(size_t)(r0 + tr) * C + c0 + tc + 8];
    __syncthreads();
    short8 o0, o1;
    #pragma unroll
    for (int i = 0; i < 8; i++) {
        o0[i] = (short)tile[tc + i][tr];
        o1[i] = (short)tile[tc + 8 + i][tr];
    }
    *(short8*)&d[(size_t)(c0 + tr) * R + r0 + tc]     = o0;
    *(short8*)&d[(size_t)(c0 + tr) * R + r0 + tc + 8] = o1;
}

// ---------------- K4: attention GEMM per head -> otb2[(s*N+i)][h*32+d] ----------------
__global__ __launch_bounds__(256) void k_attn_mfma(const ushort_t* __restrict__ wsb,
                                                   const ushort_t* __restrict__ vtt,
                                                   ushort_t* __restrict__ otb2) {
    int h = blockIdx.z;
    const ushort_t* A  = wsb + (size_t)h * NPAIR;        // [384][384]
    const ushort_t* Bt = vtt + (size_t)h * SD * NRES;    // [8192][384]
    int m0 = blockIdx.y * 64, n0 = blockIdx.x * 64;
    __shared__ ushort_t Al[64][40];
    __shared__ ushort_t Bl[64][40];
    int t = threadIdx.x;
    int srow = t >> 2, sko = (t & 3) * 8;
    int wave = t >> 6, lane = t & 63;
    int wr = (wave >> 1) * 32, wc = (wave & 1) * 32;
    int lk = (lane >> 4) * 8, lr = lane & 15;
    f32x4 acc[2][2] = {};
    for (int k0 = 0; k0 < NRES; k0 += 32) {
        *(short8*)&Al[srow][sko] = *(const short8*)&A[(size_t)(m0 + srow) * NRES + k0 + sko];
        *(short8*)&Bl[srow][sko] = *(const short8*)&Bt[(size_t)(n0 + srow) * NRES + k0 + sko];
        __syncthreads();
        short8 a0 = *(const short8*)&Al[wr + lr][lk];
        short8 a1 = *(const short8*)&Al[wr + 16 + lr][lk];
        short8 b0 = *(const short8*)&Bl[wc + lr][lk];
        short8 b1 = *(const short8*)&Bl[wc + 16 + lr][lk];
        acc[0][0] = mfma16(a0, b0, acc[0][0]);
        acc[0][1] = mfma16(a0, b1, acc[0][1]);
        acc[1][0] = mfma16(a1, b0, acc[1][0]);
        acc[1][1] = mfma16(a1, b1, acc[1][1]);
        __syncthreads();
    }
    #pragma unroll
    for (int ri = 0; ri < 2; ri++)
        #pragma unroll
        for (int ci = 0; ci < 2; ci++) {
            int row0 = m0 + wr + 16 * ri + (lane >> 4) * 4;   // i
            int col  = n0 + wc + 16 * ci + lr;                // s*32+d
            int s = col >> 5, dd = col & 31;
            #pragma unroll
            for (int r = 0; r < 4; r++)
                otb2[((size_t)s * NRES + row0 + r) * HC + h * DH + dd] = cvt_bf(acc[ri][ci][r]);
        }
}

// ---------------- K5a: gate GEMM + sigmoid*o -> gob ----------------
__global__ __launch_bounds__(256) void k_gate_mfma(const ushort_t* __restrict__ A,
                                                   const ushort_t* __restrict__ Bt,
                                                   const ushort_t* __restrict__ otb2,
                                                   ushort_t* __restrict__ gob) {
    int m0 = blockIdx.y * 64, n0 = blockIdx.x * 64;
    __shared__ ushort_t Al[64][40];
    __shared__ ushort_t Bl[64][40];
    int t = threadIdx.x;
    int srow = t >> 2, sko = (t & 3) * 8;
    int wave = t >> 6, lane = t & 63;
    int wr = (wave >> 1) * 32, wc = (wave & 1) * 32;
    int lk = (lane >> 4) * 8, lr = lane & 15;
    f32x4 acc[2][2] = {};
    for (int k0 = 0; k0 < DM; k0 += 32) {
        *(short8*)&Al[srow][sko] = *(const short8*)&A[(size_t)(m0 + srow) * DM + k0 + sko];
        *(short8*)&Bl[srow][sko] = *(const short8*)&Bt[(size_t)(n0 + srow) * DM + k0 + sko];
        __syncthreads();
        short8 a0 = *(const short8*)&Al[wr + lr][lk];
        short8 a1 = *(const short8*)&Al[wr + 16 + lr][lk];
        short8 b0 = *(const short8*)&Bl[wc + lr][lk];
        short8 b1 = *(const short8*)&Bl[wc + 16 + lr][lk];
        acc[0][0] = mfma16(a0, b0, acc[0][0]);
        acc[0][1] = mfma16(a0, b1, acc[0][1]);
        acc[1][0] = mfma16(a1, b0, acc[1][0]);
        acc[1][1] = mfma16(a1, b1, acc[1][1]);
        __syncthreads();
    }
    #pragma unroll
    for (int ri = 0; ri < 2; ri++)
        #pragma unroll
        for (int ci = 0; ci < 2; ci++) {
            int row0 = m0 + wr + 16 * ri + (lane >> 4) * 4;
            int col  = n0 + wc + 16 * ci + lr;
            #pragma unroll
            for (int r = 0; r < 4; r++) {
                size_t idx = (size_t)(row0 + r) * HC + col;
                float ov = cvt_f(otb2[idx]);
                gob[idx] = cvt_bf(sigm(acc[ri][ci][r]) * ov);
            }
        }
}

// ---------------- K5b: output GEMM + residual -> mout ----------------
__global__ __launch_bounds__(256) void k_out_mfma(const ushort_t* __restrict__ A,
                                                  const ushort_t* __restrict__ Bt,
                                                  const float* __restrict__ m,
                                                  float* __restrict__ mout) {
    int m0 = blockIdx.x * 64;
    __shared__ ushort_t Al[64][40];
    __shared__ ushort_t Bl[64][40];
    int t = threadIdx.x;
    int srow = t >> 2, sko = (t & 3) * 8;
    int wave = t >> 6, lane = t & 63;
    int wr = (wave >> 1) * 32, wc = (wave & 1) * 32;
    int lk = (lane >> 4) * 8, lr = lane & 15;
    f32x4 acc[2][2] = {};
    for (int k0 = 0; k0 < HC; k0 += 32) {
        *(short8*)&Al[srow][sko] = *(const short8*)&A[(size_t)(m0 + srow) * HC + k0 + sko];
        *(short8*)&Bl[srow][sko] = *(const short8*)&Bt[(size_t)srow * HC + k0 + sko];
        __syncthreads();
        short8 a0 = *(const short8*)&Al[wr + lr][lk];
        short8 a1 = *(const short8*)&Al[wr + 16 + lr][lk];
        short8 b0 = *(const short8*)&Bl[wc + lr][lk];
        short8 b1 = *(const short8*)&Bl[wc + 16 + lr][lk];
        acc[0][0] = mfma16(a0, b0, acc[0][0]);
        acc[0][1] = mfma16(a0, b1, acc[0][1]);
        acc[1][0] = mfma16(a1, b0, acc[1][0]);
        acc[1][1] = mfma16(a1, b1, acc[1][1]);
        __syncthreads();
    }
    #pragma unroll
    for (int ri = 0; ri < 2; ri++)
        #pragma unroll
        for (int ci = 0; ci < 2; ci++) {
            int row0 = m0 + wr + 16 * ri + (lane >> 4) * 4;
            int col  = wc + 16 * ci + lr;
            #pragma unroll
            for (int r = 0; r < 4; r++) {
                size_t idx = (size_t)(row0 + r) * DM + col;
                mout[idx] = m[idx] + acc[ri][ci][r];
            }
        }
}

// ---------------- K6b: fc1/fc2 GEMM + SwiGLU -> hh bf16 ----------------
__global__ __launch_bounds__(256) void k_fc12(const ushort_t* __restrict__ A,
                                              const ushort_t* __restrict__ B1t,
                                              const ushort_t* __restrict__ B2t,
                                              ushort_t* __restrict__ hh) {
    int m0 = blockIdx.y * 64, n0 = blockIdx.x * 64;
    __shared__ ushort_t Al[64][40];
    __shared__ ushort_t B1l[64][40];
    __shared__ ushort_t B2l[64][40];
    int t = threadIdx.x;
    int srow = t >> 2, sko = (t & 3) * 8;
    int wave = t >> 6, lane = t & 63;
    int wr = (wave >> 1) * 32, wc = (wave & 1) * 32;
    int lk = (lane >> 4) * 8, lr = lane & 15;
    f32x4 acc1[2][2] = {}, acc2[2][2] = {};
    for (int k0 = 0; k0 < DM; k0 += 32) {
        *(short8*)&Al[srow][sko]  = *(const short8*)&A[(size_t)(m0 + srow) * DM + k0 + sko];
        *(short8*)&B1l[srow][sko] = *(const short8*)&B1t[(size_t)(n0 + srow) * DM + k0 + sko];
        *(short8*)&B2l[srow][sko] = *(const short8*)&B2t[(size_t)(n0 + srow) * DM + k0 + sko];
        __syncthreads();
        short8 a0 = *(const short8*)&Al[wr + lr][lk];
        short8 a1 = *(const short8*)&Al[wr + 16 + lr][lk];
        short8 p0 = *(const short8*)&B1l[wc + lr][lk];
        short8 p1 = *(const short8*)&B1l[wc + 16 + lr][lk];
        short8 q0 = *(const short8*)&B2l[wc + lr][lk];
        short8 q1 = *(const short8*)&B2l[wc + 16 + lr][lk];
        acc1[0][0] = mfma16(a0, p0, acc1[0][0]);
        acc1[0][1] = mfma16(a0, p1, acc1[0][1]);
        acc1[1][0] = mfma16(a1, p0, acc1[1][0]);
        acc1[1][1] = mfma16(a1, p1, acc1[1][1]);
        acc2[0][0] = mfma16(a0, q0, acc2[0][0]);
        acc2[0][1] = mfma16(a0, q1, acc2[0][1]);
        acc2[1][0] = mfma16(a1, q0, acc2[1][0]);
        acc2[1][1] = mfma16(a1, q1, acc2[1][1]);
        __syncthreads();
    }
    #pragma unroll
    for (int ri = 0; ri < 2; ri++)
        #pragma unroll
        for (int ci = 0; ci < 2; ci++) {
            int row0 = m0 + wr + 16 * ri + (lane >> 4) * 4;
            int col  = n0 + wc + 16 * ci + lr;
            #pragma unroll
            for (int r = 0; r < 4; r++) {
                float a1v = acc1[ri][ci][r], a2v = acc2[ri][ci][r];
                hh[(size_t)(row0 + r) * FF + col] = cvt_bf(a1v * sigm(a1v) * a2v);
            }
        }
}

// ---------------- K6c: fc3 GEMM + residual into mout ----------------
__global__ __launch_bounds__(256) void k_fc3(const ushort_t* __restrict__ A,
                                             const ushort_t* __restrict__ Bt,
                                             float* __restrict__ mio) {
    int m0 = blockIdx.x * 64;
    __shared__ ushort_t Al[64][40];
    __shared__ ushort_t Bl[64][40];
    int t = threadIdx.x;
    int srow = t >> 2, sko = (t & 3) * 8;
    int wave = t >> 6, lane = t & 63;
    int wr = (wave >> 1) * 32, wc = (wave & 1) * 32;
    int lk = (lane >> 4) * 8, lr = lane & 15;
    f32x4 acc[2][2] = {};
    for (int k0 = 0; k0 < FF; k0 += 32) {
        *(short8*)&Al[srow][sko] = *(const short8*)&A[(size_t)(m0 + srow) * FF + k0 + sko];
        *(short8*)&Bl[srow][sko] = *(const short8*)&Bt[(size_t)srow * FF + k0 + sko];
        __syncthreads();
        short8 a0 = *(const short8*)&Al[wr + lr][lk];
        short8 a1 = *(const short8*)&Al[wr + 16 + lr][lk];
        short8 b0 = *(const short8*)&Bl[wc + lr][lk];
        short8 b1 = *(const short8*)&Bl[wc + 16 + lr][lk];
        acc[0][0] = mfma16(a0, b0, acc[0][0]);
        acc[0][1] = mfma16(a0, b1, acc[0][1]);
        acc[1][0] = mfma16(a1, b0, acc[1][0]);
        acc[1][1] = mfma16(a1, b1, acc[1][1]);
        __syncthreads();
    }
    #pragma unroll
    for (int ri = 0; ri < 2; ri++)
        #pragma unroll
        for (int ci = 0; ci < 2; ci++) {
            int row0 = m0 + wr + 16 * ri + (lane >> 4) * 4;
            int col  = wc + 16 * ci + lr;
            #pragma unroll
            for (int r = 0; r < 4; r++)
                mio[(size_t)(row0 + r) * DM + col] += acc[ri][ci][r];
        }
}

// ---------------- K7: a/b projections for OPM (bf16 out) ----------------
__global__ __launch_bounds__(256) void k_ab(const float* __restrict__ mfin,
                                            const float* __restrict__ onw,
                                            const float* __restrict__ onb,
                                            const float* __restrict__ paw,
                                            const float* __restrict__ pbw,
                                            const float* __restrict__ smask,
                                            ushort_t* __restrict__ abuf,
                                            ushort_t* __restrict__ bbuf) {
    int wave = threadIdx.x >> 6, lane = threadIdx.x & 63;
    int r = blockIdx.x * 4 + wave;
    int s = r / NRES, n = r % NRES;
    __shared__ float mn[4][64];
    float x = mfin[(size_t)r * DM + lane];
    float mu = wred_sum(x) * (1.0f / 64.0f);
    float d = x - mu;
    float var = wred_sum(d * d) * (1.0f / 64.0f);
    mn[wave][lane] = d * rsqrtf(var + 1e-5f) * onw[lane] + onb[lane];
    __syncthreads();
    float msk = smask[r];
    int half = lane >> 5, c = lane & 31;
    const float* w = half ? pbw : paw;
    float acc = 0.0f;
    for (int c4 = 0; c4 < 64; c4 += 4) {
        float4 wv = *(const float4*)&w[c * DM + c4];
        float4 mv = *(const float4*)&mn[wave][c4];
        acc += wv.x * mv.x + wv.y * mv.y + wv.z * mv.z + wv.w * mv.w;
    }
    acc *= msk;
    ushort_t* dst = half ? bbuf : abuf;
    dst[(size_t)s * (NRES * DOP) + n * DOP + c] = cvt_bf(acc);
}

// ---------------- K8: mask pair-count sum ----------------
__global__ __launch_bounds__(256) void k_msum(const float* __restrict__ smask,
                                              float* __restrict__ msum) {
    int t = blockIdx.x * 256 + threadIdx.x;
    int i = t / NRES, j = t % NRES;
    float sum = 0.0f;
    for (int s = 0; s < NSEQ; s++)
        sum += smask[s * NRES + i] * smask[s * NRES + j];
    msum[t] = fmaxf(sum, 1.0f);
}

// ---------------- K9: OPM outer GEMM (bf16 MFMA, 128x128 tile) ----------------
__global__ __launch_bounds__(256) void k_opm_mfma(const ushort_t* __restrict__ At,
                                                  const ushort_t* __restrict__ Bt,
                                                  ushort_t* __restrict__ opmc) {
    int m0 = blockIdx.y * 128;                  // over 1536 (il,c)
    int n0 = blockIdx.x * 128;                  // over 12288 (j,d)
    __shared__ ushort_t Al[128][40];
    __shared__ ushort_t Bl[128][40];
    int t = threadIdx.x;
    int srow = t >> 1, sko = (t & 1) * 16;
    int wave = t >> 6, lane = t & 63;
    int wr = (wave >> 1) * 64, wc = (wave & 1) * 64;
    int lk = (lane >> 4) * 8, lr = lane & 15;
    f32x4 acc[4][4] = {};
    for (int k0 = 0; k0 < NSEQ; k0 += 32) {
        *(short8*)&Al[srow][sko]     = *(const short8*)&At[(size_t)(m0 + srow) * NSEQ + k0 + sko];
        *(short8*)&Al[srow][sko + 8] = *(const short8*)&At[(size_t)(m0 + srow) * NSEQ + k0 + sko + 8];
        *(short8*)&Bl[srow][sko]     = *(const short8*)&Bt[(size_t)(n0 + srow) * NSEQ + k0 + sko];
        *(short8*)&Bl[srow][sko + 8] = *(const short8*)&Bt[(size_t)(n0 + srow) * NSEQ + k0 + sko + 8];
        __syncthreads();
        short8 af[4], bf[4];
        #pragma unroll
        for (int i = 0; i < 4; i++) {
            af[i] = *(const short8*)&Al[wr + 16 * i + lr][lk];
            bf[i] = *(const short8*)&Bl[wc + 16 * i + lr][lk];
        }
        #pragma unroll
        for (int ri = 0; ri < 4; ri++)
            #pragma unroll
            for (int ci = 0; ci < 4; ci++)
                acc[ri][ci] = mfma16(af[ri], bf[ci], acc[ri][ci]);
        __syncthreads();
    }
    #pragma unroll
    for (int ri = 0; ri < 4; ri++)
        #pragma unroll
        for (int ci = 0; ci < 4; ci++) {
            int mb = m0 + wr + 16 * ri + (lane >> 4) * 4;
            int n  = n0 + wc + 16 * ci + lr;
            int j = n >> 5, dd = n & 31;
            #pragma unroll
            for (int r = 0; r < 4; r++) {
                int mm = mb + r;
                int il = mm >> 5, c = mm & 31;
                opmc[((size_t)(il * NRES + j) << 10) + (c << 5) + dd] = cvt_bf(acc[ri][ci][r]);
            }
        }
}

// ---------------- K10: OPM projection + residual ----------------
__global__ __launch_bounds__(256) void k_proj_mfma(const ushort_t* __restrict__ A,
                                                   const ushort_t* __restrict__ Bt,
                                                   const float* __restrict__ opB,
                                                   const float* __restrict__ msum,
                                                   const float* __restrict__ zin,
                                                   float* __restrict__ zout,
                                                   int ib) {
    int m0 = blockIdx.y * 64, n0 = blockIdx.x * 64;
    __shared__ ushort_t Al[64][40];
    __shared__ ushort_t Bl[64][40];
    int t = threadIdx.x;
    int srow = t >> 2, sko = (t & 3) * 8;
    int wave = t >> 6, lane = t & 63;
    int wr = (wave >> 1) * 32, wc = (wave & 1) * 32;
    int lk = (lane >> 4) * 8, lr = lane & 15;
    f32x4 acc[2][2] = {};
    for (int k0 = 0; k0 < 1024; k0 += 32) {
        *(short8*)&Al[srow][sko] = *(const short8*)&A[(size_t)(m0 + srow) * 1024 + k0 + sko];
        *(short8*)&Bl[srow][sko] = *(const short8*)&Bt[(size_t)(n0 + srow) * 1024 + k0 + sko];
        __syncthreads();
        short8 a0 = *(const short8*)&Al[wr + lr][lk];
        short8 a1 = *(const short8*)&Al[wr + 16 + lr][lk];
        short8 b0 = *(const short8*)&Bl[wc + lr][lk];
        short8 b1 = *(const short8*)&Bl[wc + 16 + lr][lk];
        acc[0][0] = mfma16(a0, b0, acc[0][0]);
        acc[0][1] = mfma16(a0, b1, acc[0][1]);
        acc[1][0] = mfma16(a1, b0, acc[1][0]);
        acc[1][1] = mfma16(a1, b1, acc[1][1]);
        __syncthreads();
    }
    #pragma unroll
    for (int ri = 0; ri < 2; ri++)
        #pragma unroll
        for (int ci = 0; ci < 2; ci++) {
            int row0 = m0 + wr + 16 * ri + (lane >> 4) * 4;
            int col  = n0 + wc + 16 * ci + lr;
            #pragma unroll
            for (int r = 0; r < 4; r++) {
                size_t G = (size_t)ib * NRES + row0 + r;
                float inv = 1.0f / msum[G];
                zout[G * DZ + col] = zin[G * DZ + col] + acc[ri][ci][r] * inv + opB[col];
            }
        }
}

// ---------------- launch ----------------
extern "C" void kernel_launch(void* const* d_in, const int* in_sizes, int n_in,
                              void* d_out, int out_size, void* d_ws, size_t ws_size,
                              hipStream_t stream) {
    const float* z     = (const float*)d_in[0];
    const float* m     = (const float*)d_in[1];
    const float* tmask = (const float*)d_in[2];
    const float* smask = (const float*)d_in[3];
    const float* nzw   = (const float*)d_in[4];
    const float* nzb   = (const float*)d_in[5];
    const float* pzw   = (const float*)d_in[6];
    const float* nmw   = (const float*)d_in[7];
    const float* nmb   = (const float*)d_in[8];
    const float* pmw   = (const float*)d_in[9];
    const float* pgw   = (const float*)d_in[10];
    const float* pow_  = (const float*)d_in[11];
    const float* tnw   = (const float*)d_in[12];
    const float* tnb_  = (const float*)d_in[13];
    const float* f1    = (const float*)d_in[14];
    const float* f2    = (const float*)d_in[15];
    const float* f3    = (const float*)d_in[16];
    const float* onw   = (const float*)d_in[17];
    const float* onb   = (const float*)d_in[18];
    const float* paw   = (const float*)d_in[19];
    const float* pbw   = (const float*)d_in[20];
    const float* opW   = (const float*)d_in[21];
    const float* opB   = (const float*)d_in[22];

    float* zout = (float*)d_out;
    float* mout = zout + ZTOT;

    char* W = (char*)d_ws;
    float*    wsf  = (float*)(W);                       //     0 .. 4,718,592
    ushort_t* wsb  = (ushort_t*)(W + 4718592);          //  .. 7,077,888
    ushort_t* mnb  = (ushort_t*)(W + 7077888);          //  .. 19,660,800 (12.6MB)
    ushort_t* vt   = (ushort_t*)(W + 19660800);         //  .. 69,992,448 (50.3MB)
    ushort_t* vtt  = (ushort_t*)(W + 69992448);         //  .. 120,324,096 (50.3MB)
    ushort_t* otb2 = (ushort_t*)(W + 120324096);        //  .. 170,655,744 (50.3MB)
    float*    msum = (float*)(W + 170655744);           //  .. 171,245,568
    ushort_t* f1b  = (ushort_t*)(W + 171245568);
    ushort_t* f2b  = (ushort_t*)(W + 171278336);
    ushort_t* f3b  = (ushort_t*)(W + 171311104);
    ushort_t* opWb = (ushort_t*)(W + 171343872);        //  .. 171,606,016
    ushort_t* pmwb = (ushort_t*)(W + 171606016);
    ushort_t* pgwb = (ushort_t*)(W + 171638784);
    ushort_t* powb = (ushort_t*)(W + 171671552);        //  .. 171,704,320
    // region aliases (dead-by-then):
    ushort_t* gob  = vt;                    // vt dead after k_tr (attn reads vtt)
    ushort_t* tn_bf = vtt;                  // vtt dead after k_attn_mfma
    ushort_t* abuf = (ushort_t*)(W + 69992448 + 12582912);   // vtt+12.6MB
    ushort_t* bbuf = (ushort_t*)(W + 69992448 + 18874368);   // vtt+18.9MB
    ushort_t* hh   = otb2;                  // otb2 dead after k_gate_mfma
    ushort_t* abt  = otb2;                  // hh dead after k_fc3
    ushort_t* bbt  = (ushort_t*)(W + 120324096 + 6291456);
    ushort_t* opmc = vt;                    // gob dead after k_out_mfma

    k_prep<<<512, 256, 0, stream>>>(f1, f2, f3, opW, pmw, pgw, pow_,
                                    f1b, f2b, f3b, opWb, pmwb, pgwb, powb);

    // PairWeightedAveraging
    k_bias<<<NPAIR / 4, 256, 0, stream>>>(z, tmask, nzw, nzb, pzw, wsf);
    k_softmax<<<NH * NRES, 64, 0, stream>>>(wsf, wsb);
    k_ln64<<<NROWS / 4, 256, 0, stream>>>(m, nmw, nmb, mnb);
    k_vproj_mfma<<<dim3(HC / 64, NROWS / 64), 256, 0, stream>>>(mnb, pmwb, vt);
    k_tr<<<dim3(SD / 64, NRES / 64, NH), 256, 0, stream>>>(vt, vtt, NRES, SD);
    k_attn_mfma<<<dim3(SD / 64, NRES / 64, NH), 256, 0, stream>>>(wsb, vtt, otb2);
    k_gate_mfma<<<dim3(HC / 64, NROWS / 64), 256, 0, stream>>>(mnb, pgwb, otb2, gob);
    k_out_mfma<<<NROWS / 64, 256, 0, stream>>>(gob, powb, m, mout);

    // Transition (MFMA)
    k_ln64<<<NROWS / 4, 256, 0, stream>>>(mout, tnw, tnb_, tn_bf);
    k_fc12<<<dim3(FF / 64, NROWS / 64), 256, 0, stream>>>(tn_bf, f1b, f2b, hh);
    k_fc3<<<NROWS / 64, 256, 0, stream>>>(hh, f3b, mout);

    // OuterProductMean
    k_ab<<<NROWS / 4, 256, 0, stream>>>(mout, onw, onb, paw, pbw, smask, abuf, bbuf);
    k_tr<<<dim3((NRES * DOP) / 64, NSEQ / 64, 2), 256, 0, stream>>>(abuf, abt, NSEQ, NRES * DOP);
    k_msum<<<NPAIR / 256, 256, 0, stream>>>(smask, msum);
    for (int cb = 0; cb < NRES / ICHUNK; cb++) {
        int ib = cb * ICHUNK;
        const ushort_t* Achunk = abt + (size_t)(ib * DOP) * NSEQ;
        k_opm_mfma<<<dim3((NRES * DOP) / 128, (ICHUNK * DOP) / 128), 256, 0, stream>>>(Achunk, bbt, opmc);
        k_proj_mfma<<<dim3(DZ / 64, (ICHUNK * NRES) / 64), 256, 0, stream>>>(opmc, opWb, opB, msum, z, zout, ib);
    }
}

// Round 4
// 698.853 us; speedup vs baseline: 9.6010x; 1.3215x over previous
//
#include <hip/hip_runtime.h>
#include <math.h>

// ---------------- problem constants ----------------
constexpr int NRES = 384;          // N
constexpr int NSEQ = 256;          // S
constexpr int DM   = 64;           // MSA_S
constexpr int DZ   = 128;          // Z_D
constexpr int NH   = 8;            // H
constexpr int DH   = 32;           // C_H
constexpr int HC   = NH * DH;      // 256
constexpr int DOP  = 32;           // C_OPM
constexpr int FF   = 4 * DM;       // 256

constexpr int NPAIR = NRES * NRES;         // 147456
constexpr int NROWS = NSEQ * NRES;         // 98304
constexpr int ZTOT  = NPAIR * DZ;          // 18874368
constexpr int SD    = NSEQ * DH;           // 8192
constexpr int ICHUNK = 96;                 // i-rows per OPM chunk (4 chunks)

typedef unsigned short ushort_t;
typedef __attribute__((ext_vector_type(8))) short short8;
typedef __attribute__((ext_vector_type(4))) float f32x4;

__device__ __forceinline__ float wred_sum(float v) {
    #pragma unroll
    for (int off = 32; off; off >>= 1) v += __shfl_xor(v, off, 64);
    return v;
}
__device__ __forceinline__ float wred_max(float v) {
    #pragma unroll
    for (int off = 32; off; off >>= 1) v = fmaxf(v, __shfl_xor(v, off, 64));
    return v;
}
__device__ __forceinline__ float sigm(float x) { return 1.0f / (1.0f + expf(-x)); }
__device__ __forceinline__ ushort_t cvt_bf(float f) {
    unsigned u = __float_as_uint(f);
    unsigned r = (u + 0x7FFFu + ((u >> 16) & 1u)) >> 16;
    return (ushort_t)r;
}
__device__ __forceinline__ float cvt_f(ushort_t h) {
    return __uint_as_float(((unsigned)h) << 16);
}
__device__ __forceinline__ f32x4 mfma16(short8 a, short8 b, f32x4 c) {
    return __builtin_amdgcn_mfma_f32_16x16x32_bf16(a, b, c, 0, 0, 0);
}

// ---------------- K0: weights -> bf16 ----------------
__global__ __launch_bounds__(256) void k_prep(const float* __restrict__ f1,
                                              const float* __restrict__ f2,
                                              const float* __restrict__ f3,
                                              const float* __restrict__ opW,
                                              const float* __restrict__ pmw,
                                              const float* __restrict__ pgw,
                                              const float* __restrict__ pow_,
                                              const float* __restrict__ paw,
                                              const float* __restrict__ pbw,
                                              ushort_t* __restrict__ f1b,
                                              ushort_t* __restrict__ f2b,
                                              ushort_t* __restrict__ f3b,
                                              ushort_t* __restrict__ opWb,
                                              ushort_t* __restrict__ pmwb,
                                              ushort_t* __restrict__ pgwb,
                                              ushort_t* __restrict__ powb,
                                              ushort_t* __restrict__ abwb) {
    int i = blockIdx.x * 256 + threadIdx.x;      // 131072 threads
    opWb[i] = cvt_bf(opW[i]);
    if (i < FF * DM) {
        f1b[i] = cvt_bf(f1[i]);
        f2b[i] = cvt_bf(f2[i]);
        f3b[i] = cvt_bf(f3[i]);
    }
    if (i < HC * DM) {
        pmwb[i] = cvt_bf(pmw[i]);
        pgwb[i] = cvt_bf(pgw[i]);
        powb[i] = cvt_bf(pow_[i]);
    }
    if (i < 2 * DOP * DM) {                      // combined [64][64]: rows 0..31 paw, 32..63 pbw
        abwb[i] = cvt_bf(i < DOP * DM ? paw[i] : pbw[i - DOP * DM]);
    }
}

// ---------------- K1: pair bias logits (ILP reductions) ----------------
__global__ __launch_bounds__(256) void k_bias(const float* __restrict__ z,
                                              const float* __restrict__ tmask,
                                              const float* __restrict__ nzw,
                                              const float* __restrict__ nzb,
                                              const float* __restrict__ pzw,
                                              float* __restrict__ wsf) {
    int wave = threadIdx.x >> 6, lane = threadIdx.x & 63;
    int pair = blockIdx.x * 4 + wave;
    const float* zr = z + (size_t)pair * DZ;
    float x0 = zr[lane], x1 = zr[lane + 64];
    float s1 = x0 + x1, s2 = x0 * x0 + x1 * x1;
    #pragma unroll
    for (int off = 32; off; off >>= 1) {
        s1 += __shfl_xor(s1, off, 64);
        s2 += __shfl_xor(s2, off, 64);
    }
    float mu = s1 * (1.0f / 128.0f);
    float var = s2 * (1.0f / 128.0f) - mu * mu;
    float rs = rsqrtf(var + 1e-5f);
    float n0 = (x0 - mu) * rs * nzw[lane] + nzb[lane];
    float n1 = (x1 - mu) * rs * nzw[lane + 64] + nzb[lane + 64];
    float p[8];
    #pragma unroll
    for (int h = 0; h < NH; h++)
        p[h] = n0 * pzw[h * DZ + lane] + n1 * pzw[h * DZ + lane + 64];
    #pragma unroll
    for (int off = 32; off; off >>= 1)
        #pragma unroll
        for (int h = 0; h < NH; h++)
            p[h] += __shfl_xor(p[h], off, 64);
    if (lane < NH) {
        float out = p[0];
        #pragma unroll
        for (int h = 1; h < NH; h++) if (lane == h) out = p[h];
        float mb = (1.0f - tmask[pair]) * (-1e9f);
        wsf[(size_t)lane * NPAIR + pair] = out + mb;
    }
}

// ---------------- K2: softmax over j -> bf16 ----------------
__global__ __launch_bounds__(64) void k_softmax(const float* __restrict__ wsf,
                                                ushort_t* __restrict__ wsb) {
    int row = blockIdx.x;                       // h*NRES + i
    const float* p = wsf + (size_t)row * NRES;
    ushort_t* o = wsb + (size_t)row * NRES;
    int lane = threadIdx.x;
    float v[6];
    float mx = -1e30f;
    #pragma unroll
    for (int q = 0; q < 6; q++) { v[q] = p[lane + q * 64]; mx = fmaxf(mx, v[q]); }
    mx = wred_max(mx);
    float sum = 0.0f;
    #pragma unroll
    for (int q = 0; q < 6; q++) { v[q] = expf(v[q] - mx); sum += v[q]; }
    sum = wred_sum(sum);
    float inv = 1.0f / sum;
    #pragma unroll
    for (int q = 0; q < 6; q++) o[lane + q * 64] = cvt_bf(v[q] * inv);
}

// ---------------- K3: LN rows (64-wide) fp32 -> bf16 ----------------
__global__ __launch_bounds__(256) void k_ln64(const float* __restrict__ src,
                                              const float* __restrict__ lw,
                                              const float* __restrict__ lb,
                                              ushort_t* __restrict__ dst) {
    int wave = threadIdx.x >> 6, lane = threadIdx.x & 63;
    int r = blockIdx.x * 4 + wave;
    float x = src[(size_t)r * DM + lane];
    float mu = wred_sum(x) * (1.0f / 64.0f);
    float d = x - mu;
    float var = wred_sum(d * d) * (1.0f / 64.0f);
    dst[(size_t)r * DM + lane] = cvt_bf(d * rsqrtf(var + 1e-5f) * lw[lane] + lb[lane]);
}

// ---------------- K3b: v projection GEMM (mnb @ pmwb^T) -> vt[h][n][s][d] ----------------
__global__ __launch_bounds__(256) void k_vproj_mfma(const ushort_t* __restrict__ A,
                                                    const ushort_t* __restrict__ Bt,
                                                    ushort_t* __restrict__ vt) {
    int m0 = blockIdx.y * 64, n0 = blockIdx.x * 64;
    __shared__ ushort_t Al[64][40];
    __shared__ ushort_t Bl[64][40];
    int t = threadIdx.x;
    int srow = t >> 2, sko = (t & 3) * 8;
    int wave = t >> 6, lane = t & 63;
    int wr = (wave >> 1) * 32, wc = (wave & 1) * 32;
    int lk = (lane >> 4) * 8, lr = lane & 15;
    f32x4 acc[2][2] = {};
    for (int k0 = 0; k0 < DM; k0 += 32) {
        *(short8*)&Al[srow][sko] = *(const short8*)&A[(size_t)(m0 + srow) * DM + k0 + sko];
        *(short8*)&Bl[srow][sko] = *(const short8*)&Bt[(size_t)(n0 + srow) * DM + k0 + sko];
        __syncthreads();
        short8 a0 = *(const short8*)&Al[wr + lr][lk];
        short8 a1 = *(const short8*)&Al[wr + 16 + lr][lk];
        short8 b0 = *(const short8*)&Bl[wc + lr][lk];
        short8 b1 = *(const short8*)&Bl[wc + 16 + lr][lk];
        acc[0][0] = mfma16(a0, b0, acc[0][0]);
        acc[0][1] = mfma16(a0, b1, acc[0][1]);
        acc[1][0] = mfma16(a1, b0, acc[1][0]);
        acc[1][1] = mfma16(a1, b1, acc[1][1]);
        __syncthreads();
    }
    #pragma unroll
    for (int ri = 0; ri < 2; ri++)
        #pragma unroll
        for (int ci = 0; ci < 2; ci++) {
            int row0 = m0 + wr + 16 * ri + (lane >> 4) * 4;
            int col  = n0 + wc + 16 * ci + lr;      // k = h*32+dd
            int h = col >> 5, dd = col & 31;
            #pragma unroll
            for (int r = 0; r < 4; r++) {
                int rr = row0 + r;                  // s*NRES+n
                int s = rr / NRES, n = rr % NRES;
                vt[(((size_t)h * NRES + n) * NSEQ + s) * DH + dd] = cvt_bf(acc[ri][ci][r]);
            }
        }
}

// ---------------- generic 64x64 bf16 transpose ----------------
__global__ __launch_bounds__(256) void k_tr(const ushort_t* __restrict__ src,
                                            ushort_t* __restrict__ dst,
                                            int R, int C) {
    size_t bs = (size_t)R * C;
    const ushort_t* s = src + blockIdx.z * bs;
    ushort_t* d = dst + blockIdx.z * bs;
    int r0 = blockIdx.y * 64, c0 = blockIdx.x * 64;
    __shared__ ushort_t tile[64][72];
    int t = threadIdx.x;
    int tr = t >> 2, tc = (t & 3) * 16;
    *(short8*)&tile[tr][tc]     = *(const short8*)&s[(size_t)(r0 + tr) * C + c0 + tc];
    *(short8*)&tile[tr][tc + 8] = *(const short8*)&s[(size_t)(r0 + tr) * C + c0 + tc + 8];
    __syncthreads();
    short8 o0, o1;
    #pragma unroll
    for (int i = 0; i < 8; i++) {
        o0[i] = (short)tile[tc + i][tr];
        o1[i] = (short)tile[tc + 8 + i][tr];
    }
    *(short8*)&d[(size_t)(c0 + tr) * R + r0 + tc]     = o0;
    *(short8*)&d[(size_t)(c0 + tr) * R + r0 + tc + 8] = o1;
}

// ---------------- K4: attention GEMM per head (128x128 tile) -> otb2[(s*N+i)][h*32+d] ----------------
__global__ __launch_bounds__(256) void k_attn_mfma(const ushort_t* __restrict__ wsb,
                                                   const ushort_t* __restrict__ vtt,
                                                   ushort_t* __restrict__ otb2) {
    int h = blockIdx.z;
    const ushort_t* A  = wsb + (size_t)h * NPAIR;        // [384][384]
    const ushort_t* Bt = vtt + (size_t)h * SD * NRES;    // [8192][384]
    int m0 = blockIdx.y * 128, n0 = blockIdx.x * 128;
    __shared__ ushort_t Al[128][40];
    __shared__ ushort_t Bl[128][40];
    int t = threadIdx.x;
    int srow = t >> 1, sko = (t & 1) * 16;
    int wave = t >> 6, lane = t & 63;
    int wr = (wave >> 1) * 64, wc = (wave & 1) * 64;
    int lk = (lane >> 4) * 8, lr = lane & 15;
    f32x4 acc[4][4] = {};
    for (int k0 = 0; k0 < NRES; k0 += 32) {
        *(short8*)&Al[srow][sko]     = *(const short8*)&A[(size_t)(m0 + srow) * NRES + k0 + sko];
        *(short8*)&Al[srow][sko + 8] = *(const short8*)&A[(size_t)(m0 + srow) * NRES + k0 + sko + 8];
        *(short8*)&Bl[srow][sko]     = *(const short8*)&Bt[(size_t)(n0 + srow) * NRES + k0 + sko];
        *(short8*)&Bl[srow][sko + 8] = *(const short8*)&Bt[(size_t)(n0 + srow) * NRES + k0 + sko + 8];
        __syncthreads();
        short8 af[4], bf2[4];
        #pragma unroll
        for (int i = 0; i < 4; i++) {
            af[i]  = *(const short8*)&Al[wr + 16 * i + lr][lk];
            bf2[i] = *(const short8*)&Bl[wc + 16 * i + lr][lk];
        }
        #pragma unroll
        for (int ri = 0; ri < 4; ri++)
            #pragma unroll
            for (int ci = 0; ci < 4; ci++)
                acc[ri][ci] = mfma16(af[ri], bf2[ci], acc[ri][ci]);
        __syncthreads();
    }
    #pragma unroll
    for (int ri = 0; ri < 4; ri++)
        #pragma unroll
        for (int ci = 0; ci < 4; ci++) {
            int row0 = m0 + wr + 16 * ri + (lane >> 4) * 4;   // i
            int col  = n0 + wc + 16 * ci + lr;                // s*32+d
            int s = col >> 5, dd = col & 31;
            #pragma unroll
            for (int r = 0; r < 4; r++)
                otb2[((size_t)s * NRES + row0 + r) * HC + h * DH + dd] = cvt_bf(acc[ri][ci][r]);
        }
}

// ---------------- K5a: gate GEMM + sigmoid*o -> gob ----------------
__global__ __launch_bounds__(256) void k_gate_mfma(const ushort_t* __restrict__ A,
                                                   const ushort_t* __restrict__ Bt,
                                                   const ushort_t* __restrict__ otb2,
                                                   ushort_t* __restrict__ gob) {
    int m0 = blockIdx.y * 64, n0 = blockIdx.x * 64;
    __shared__ ushort_t Al[64][40];
    __shared__ ushort_t Bl[64][40];
    int t = threadIdx.x;
    int srow = t >> 2, sko = (t & 3) * 8;
    int wave = t >> 6, lane = t & 63;
    int wr = (wave >> 1) * 32, wc = (wave & 1) * 32;
    int lk = (lane >> 4) * 8, lr = lane & 15;
    f32x4 acc[2][2] = {};
    for (int k0 = 0; k0 < DM; k0 += 32) {
        *(short8*)&Al[srow][sko] = *(const short8*)&A[(size_t)(m0 + srow) * DM + k0 + sko];
        *(short8*)&Bl[srow][sko] = *(const short8*)&Bt[(size_t)(n0 + srow) * DM + k0 + sko];
        __syncthreads();
        short8 a0 = *(const short8*)&Al[wr + lr][lk];
        short8 a1 = *(const short8*)&Al[wr + 16 + lr][lk];
        short8 b0 = *(const short8*)&Bl[wc + lr][lk];
        short8 b1 = *(const short8*)&Bl[wc + 16 + lr][lk];
        acc[0][0] = mfma16(a0, b0, acc[0][0]);
        acc[0][1] = mfma16(a0, b1, acc[0][1]);
        acc[1][0] = mfma16(a1, b0, acc[1][0]);
        acc[1][1] = mfma16(a1, b1, acc[1][1]);
        __syncthreads();
    }
    #pragma unroll
    for (int ri = 0; ri < 2; ri++)
        #pragma unroll
        for (int ci = 0; ci < 2; ci++) {
            int row0 = m0 + wr + 16 * ri + (lane >> 4) * 4;
            int col  = n0 + wc + 16 * ci + lr;
            #pragma unroll
            for (int r = 0; r < 4; r++) {
                size_t idx = (size_t)(row0 + r) * HC + col;
                float ov = cvt_f(otb2[idx]);
                gob[idx] = cvt_bf(sigm(acc[ri][ci][r]) * ov);
            }
        }
}

// ---------------- K5b: output GEMM + residual -> mout ----------------
__global__ __launch_bounds__(256) void k_out_mfma(const ushort_t* __restrict__ A,
                                                  const ushort_t* __restrict__ Bt,
                                                  const float* __restrict__ m,
                                                  float* __restrict__ mout) {
    int m0 = blockIdx.x * 64;
    __shared__ ushort_t Al[64][40];
    __shared__ ushort_t Bl[64][40];
    int t = threadIdx.x;
    int srow = t >> 2, sko = (t & 3) * 8;
    int wave = t >> 6, lane = t & 63;
    int wr = (wave >> 1) * 32, wc = (wave & 1) * 32;
    int lk = (lane >> 4) * 8, lr = lane & 15;
    f32x4 acc[2][2] = {};
    for (int k0 = 0; k0 < HC; k0 += 32) {
        *(short8*)&Al[srow][sko] = *(const short8*)&A[(size_t)(m0 + srow) * HC + k0 + sko];
        *(short8*)&Bl[srow][sko] = *(const short8*)&Bt[(size_t)srow * HC + k0 + sko];
        __syncthreads();
        short8 a0 = *(const short8*)&Al[wr + lr][lk];
        short8 a1 = *(const short8*)&Al[wr + 16 + lr][lk];
        short8 b0 = *(const short8*)&Bl[wc + lr][lk];
        short8 b1 = *(const short8*)&Bl[wc + 16 + lr][lk];
        acc[0][0] = mfma16(a0, b0, acc[0][0]);
        acc[0][1] = mfma16(a0, b1, acc[0][1]);
        acc[1][0] = mfma16(a1, b0, acc[1][0]);
        acc[1][1] = mfma16(a1, b1, acc[1][1]);
        __syncthreads();
    }
    #pragma unroll
    for (int ri = 0; ri < 2; ri++)
        #pragma unroll
        for (int ci = 0; ci < 2; ci++) {
            int row0 = m0 + wr + 16 * ri + (lane >> 4) * 4;
            int col  = wc + 16 * ci + lr;
            #pragma unroll
            for (int r = 0; r < 4; r++) {
                size_t idx = (size_t)(row0 + r) * DM + col;
                mout[idx] = m[idx] + acc[ri][ci][r];
            }
        }
}

// ---------------- K6b: fc1/fc2 GEMM + SwiGLU -> hh bf16 ----------------
__global__ __launch_bounds__(256) void k_fc12(const ushort_t* __restrict__ A,
                                              const ushort_t* __restrict__ B1t,
                                              const ushort_t* __restrict__ B2t,
                                              ushort_t* __restrict__ hh) {
    int m0 = blockIdx.y * 64, n0 = blockIdx.x * 64;
    __shared__ ushort_t Al[64][40];
    __shared__ ushort_t B1l[64][40];
    __shared__ ushort_t B2l[64][40];
    int t = threadIdx.x;
    int srow = t >> 2, sko = (t & 3) * 8;
    int wave = t >> 6, lane = t & 63;
    int wr = (wave >> 1) * 32, wc = (wave & 1) * 32;
    int lk = (lane >> 4) * 8, lr = lane & 15;
    f32x4 acc1[2][2] = {}, acc2[2][2] = {};
    for (int k0 = 0; k0 < DM; k0 += 32) {
        *(short8*)&Al[srow][sko]  = *(const short8*)&A[(size_t)(m0 + srow) * DM + k0 + sko];
        *(short8*)&B1l[srow][sko] = *(const short8*)&B1t[(size_t)(n0 + srow) * DM + k0 + sko];
        *(short8*)&B2l[srow][sko] = *(const short8*)&B2t[(size_t)(n0 + srow) * DM + k0 + sko];
        __syncthreads();
        short8 a0 = *(const short8*)&Al[wr + lr][lk];
        short8 a1 = *(const short8*)&Al[wr + 16 + lr][lk];
        short8 p0 = *(const short8*)&B1l[wc + lr][lk];
        short8 p1 = *(const short8*)&B1l[wc + 16 + lr][lk];
        short8 q0 = *(const short8*)&B2l[wc + lr][lk];
        short8 q1 = *(const short8*)&B2l[wc + 16 + lr][lk];
        acc1[0][0] = mfma16(a0, p0, acc1[0][0]);
        acc1[0][1] = mfma16(a0, p1, acc1[0][1]);
        acc1[1][0] = mfma16(a1, p0, acc1[1][0]);
        acc1[1][1] = mfma16(a1, p1, acc1[1][1]);
        acc2[0][0] = mfma16(a0, q0, acc2[0][0]);
        acc2[0][1] = mfma16(a0, q1, acc2[0][1]);
        acc2[1][0] = mfma16(a1, q0, acc2[1][0]);
        acc2[1][1] = mfma16(a1, q1, acc2[1][1]);
        __syncthreads();
    }
    #pragma unroll
    for (int ri = 0; ri < 2; ri++)
        #pragma unroll
        for (int ci = 0; ci < 2; ci++) {
            int row0 = m0 + wr + 16 * ri + (lane >> 4) * 4;
            int col  = n0 + wc + 16 * ci + lr;
            #pragma unroll
            for (int r = 0; r < 4; r++) {
                float a1v = acc1[ri][ci][r], a2v = acc2[ri][ci][r];
                hh[(size_t)(row0 + r) * FF + col] = cvt_bf(a1v * sigm(a1v) * a2v);
            }
        }
}

// ---------------- K6c: fc3 GEMM + residual into mout ----------------
__global__ __launch_bounds__(256) void k_fc3(const ushort_t* __restrict__ A,
                                             const ushort_t* __restrict__ Bt,
                                             float* __restrict__ mio) {
    int m0 = blockIdx.x * 64;
    __shared__ ushort_t Al[64][40];
    __shared__ ushort_t Bl[64][40];
    int t = threadIdx.x;
    int srow = t >> 2, sko = (t & 3) * 8;
    int wave = t >> 6, lane = t & 63;
    int wr = (wave >> 1) * 32, wc = (wave & 1) * 32;
    int lk = (lane >> 4) * 8, lr = lane & 15;
    f32x4 acc[2][2] = {};
    for (int k0 = 0; k0 < FF; k0 += 32) {
        *(short8*)&Al[srow][sko] = *(const short8*)&A[(size_t)(m0 + srow) * FF + k0 + sko];
        *(short8*)&Bl[srow][sko] = *(const short8*)&Bt[(size_t)srow * FF + k0 + sko];
        __syncthreads();
        short8 a0 = *(const short8*)&Al[wr + lr][lk];
        short8 a1 = *(const short8*)&Al[wr + 16 + lr][lk];
        short8 b0 = *(const short8*)&Bl[wc + lr][lk];
        short8 b1 = *(const short8*)&Bl[wc + 16 + lr][lk];
        acc[0][0] = mfma16(a0, b0, acc[0][0]);
        acc[0][1] = mfma16(a0, b1, acc[0][1]);
        acc[1][0] = mfma16(a1, b0, acc[1][0]);
        acc[1][1] = mfma16(a1, b1, acc[1][1]);
        __syncthreads();
    }
    #pragma unroll
    for (int ri = 0; ri < 2; ri++)
        #pragma unroll
        for (int ci = 0; ci < 2; ci++) {
            int row0 = m0 + wr + 16 * ri + (lane >> 4) * 4;
            int col  = wc + 16 * ci + lr;
            #pragma unroll
            for (int r = 0; r < 4; r++)
                mio[(size_t)(row0 + r) * DM + col] += acc[ri][ci][r];
        }
}

// ---------------- K7: a/b projection GEMM + mask -> abuf/bbuf [s][n*32+c] ----------------
__global__ __launch_bounds__(256) void k_ab_mfma(const ushort_t* __restrict__ A,
                                                 const ushort_t* __restrict__ Bt,
                                                 const float* __restrict__ smask,
                                                 ushort_t* __restrict__ abuf,
                                                 ushort_t* __restrict__ bbuf) {
    int m0 = blockIdx.x * 64;
    __shared__ ushort_t Al[64][40];
    __shared__ ushort_t Bl[64][40];
    int t = threadIdx.x;
    int srow = t >> 2, sko = (t & 3) * 8;
    int wave = t >> 6, lane = t & 63;
    int wr = (wave >> 1) * 32, wc = (wave & 1) * 32;
    int lk = (lane >> 4) * 8, lr = lane & 15;
    f32x4 acc[2][2] = {};
    for (int k0 = 0; k0 < DM; k0 += 32) {
        *(short8*)&Al[srow][sko] = *(const short8*)&A[(size_t)(m0 + srow) * DM + k0 + sko];
        *(short8*)&Bl[srow][sko] = *(const short8*)&Bt[(size_t)srow * DM + k0 + sko];
        __syncthreads();
        short8 a0 = *(const short8*)&Al[wr + lr][lk];
        short8 a1 = *(const short8*)&Al[wr + 16 + lr][lk];
        short8 b0 = *(const short8*)&Bl[wc + lr][lk];
        short8 b1 = *(const short8*)&Bl[wc + 16 + lr][lk];
        acc[0][0] = mfma16(a0, b0, acc[0][0]);
        acc[0][1] = mfma16(a0, b1, acc[0][1]);
        acc[1][0] = mfma16(a1, b0, acc[1][0]);
        acc[1][1] = mfma16(a1, b1, acc[1][1]);
        __syncthreads();
    }
    #pragma unroll
    for (int ri = 0; ri < 2; ri++)
        #pragma unroll
        for (int ci = 0; ci < 2; ci++) {
            int row0 = m0 + wr + 16 * ri + (lane >> 4) * 4;
            int col  = wc + 16 * ci + lr;               // 0..63
            #pragma unroll
            for (int r = 0; r < 4; r++) {
                int rr = row0 + r;                      // s*NRES+n
                int s = rr / NRES, n = rr % NRES;
                float v = acc[ri][ci][r] * smask[rr];
                if (col < DOP)
                    abuf[(size_t)s * (NRES * DOP) + n * DOP + col] = cvt_bf(v);
                else
                    bbuf[(size_t)s * (NRES * DOP) + n * DOP + (col - DOP)] = cvt_bf(v);
            }
        }
}

// ---------------- K8: mask pair-count Gram tile ----------------
__global__ __launch_bounds__(256) void k_msum(const float* __restrict__ smask,
                                              float* __restrict__ msum) {
    int i0 = blockIdx.y * 64, j0 = blockIdx.x * 64;
    __shared__ float As[16][64];
    __shared__ float Bs[16][64];
    int t = threadIdx.x;
    int ty = t >> 4, tx = t & 15;
    float acc[4][4] = {};
    for (int k0 = 0; k0 < NSEQ; k0 += 16) {
        int kk = t >> 4, x4 = (t & 15) * 4;
        *(float4*)&As[kk][x4] = *(const float4*)&smask[(size_t)(k0 + kk) * NRES + i0 + x4];
        *(float4*)&Bs[kk][x4] = *(const float4*)&smask[(size_t)(k0 + kk) * NRES + j0 + x4];
        __syncthreads();
        #pragma unroll
        for (int k = 0; k < 16; k++) {
            float4 a4 = *(const float4*)&As[k][ty * 4];
            float4 b4 = *(const float4*)&Bs[k][tx * 4];
            float ar[4] = {a4.x, a4.y, a4.z, a4.w};
            float br[4] = {b4.x, b4.y, b4.z, b4.w};
            #pragma unroll
            for (int i2 = 0; i2 < 4; i2++)
                #pragma unroll
                for (int j2 = 0; j2 < 4; j2++)
                    acc[i2][j2] += ar[i2] * br[j2];
        }
        __syncthreads();
    }
    #pragma unroll
    for (int r = 0; r < 4; r++) {
        float4 o4 = make_float4(fmaxf(acc[r][0], 1.0f), fmaxf(acc[r][1], 1.0f),
                                fmaxf(acc[r][2], 1.0f), fmaxf(acc[r][3], 1.0f));
        *(float4*)&msum[(size_t)(i0 + ty * 4 + r) * NRES + j0 + tx * 4] = o4;
    }
}

// ---------------- K9: OPM outer GEMM (bf16 MFMA, 128x128 tile) ----------------
__global__ __launch_bounds__(256) void k_opm_mfma(const ushort_t* __restrict__ At,
                                                  const ushort_t* __restrict__ Bt,
                                                  ushort_t* __restrict__ opmc) {
    int m0 = blockIdx.y * 128;                  // over ICHUNK*32 (il,c)
    int n0 = blockIdx.x * 128;                  // over 12288 (j,d)
    __shared__ ushort_t Al[128][40];
    __shared__ ushort_t Bl[128][40];
    int t = threadIdx.x;
    int srow = t >> 1, sko = (t & 1) * 16;
    int wave = t >> 6, lane = t & 63;
    int wr = (wave >> 1) * 64, wc = (wave & 1) * 64;
    int lk = (lane >> 4) * 8, lr = lane & 15;
    f32x4 acc[4][4] = {};
    for (int k0 = 0; k0 < NSEQ; k0 += 32) {
        *(short8*)&Al[srow][sko]     = *(const short8*)&At[(size_t)(m0 + srow) * NSEQ + k0 + sko];
        *(short8*)&Al[srow][sko + 8] = *(const short8*)&At[(size_t)(m0 + srow) * NSEQ + k0 + sko + 8];
        *(short8*)&Bl[srow][sko]     = *(const short8*)&Bt[(size_t)(n0 + srow) * NSEQ + k0 + sko];
        *(short8*)&Bl[srow][sko + 8] = *(const short8*)&Bt[(size_t)(n0 + srow) * NSEQ + k0 + sko + 8];
        __syncthreads();
        short8 af[4], bf2[4];
        #pragma unroll
        for (int i = 0; i < 4; i++) {
            af[i]  = *(const short8*)&Al[wr + 16 * i + lr][lk];
            bf2[i] = *(const short8*)&Bl[wc + 16 * i + lr][lk];
        }
        #pragma unroll
        for (int ri = 0; ri < 4; ri++)
            #pragma unroll
            for (int ci = 0; ci < 4; ci++)
                acc[ri][ci] = mfma16(af[ri], bf2[ci], acc[ri][ci]);
        __syncthreads();
    }
    #pragma unroll
    for (int ri = 0; ri < 4; ri++)
        #pragma unroll
        for (int ci = 0; ci < 4; ci++) {
            int mb = m0 + wr + 16 * ri + (lane >> 4) * 4;
            int n  = n0 + wc + 16 * ci + lr;
            int j = n >> 5, dd = n & 31;
            #pragma unroll
            for (int r = 0; r < 4; r++) {
                int mm = mb + r;
                int il = mm >> 5, c = mm & 31;
                opmc[((size_t)(il * NRES + j) << 10) + (c << 5) + dd] = cvt_bf(acc[ri][ci][r]);
            }
        }
}

// ---------------- K10: OPM projection + residual ----------------
__global__ __launch_bounds__(256) void k_proj_mfma(const ushort_t* __restrict__ A,
                                                   const ushort_t* __restrict__ Bt,
                                                   const float* __restrict__ opB,
                                                   const float* __restrict__ msum,
                                                   const float* __restrict__ zin,
                                                   float* __restrict__ zout,
                                                   int ib) {
    int m0 = blockIdx.y * 64, n0 = blockIdx.x * 64;
    __shared__ ushort_t Al[64][40];
    __shared__ ushort_t Bl[64][40];
    int t = threadIdx.x;
    int srow = t >> 2, sko = (t & 3) * 8;
    int wave = t >> 6, lane = t & 63;
    int wr = (wave >> 1) * 32, wc = (wave & 1) * 32;
    int lk = (lane >> 4) * 8, lr = lane & 15;
    f32x4 acc[2][2] = {};
    for (int k0 = 0; k0 < 1024; k0 += 32) {
        *(short8*)&Al[srow][sko] = *(const short8*)&A[(size_t)(m0 + srow) * 1024 + k0 + sko];
        *(short8*)&Bl[srow][sko] = *(const short8*)&Bt[(size_t)(n0 + srow) * 1024 + k0 + sko];
        __syncthreads();
        short8 a0 = *(const short8*)&Al[wr + lr][lk];
        short8 a1 = *(const short8*)&Al[wr + 16 + lr][lk];
        short8 b0 = *(const short8*)&Bl[wc + lr][lk];
        short8 b1 = *(const short8*)&Bl[wc + 16 + lr][lk];
        acc[0][0] = mfma16(a0, b0, acc[0][0]);
        acc[0][1] = mfma16(a0, b1, acc[0][1]);
        acc[1][0] = mfma16(a1, b0, acc[1][0]);
        acc[1][1] = mfma16(a1, b1, acc[1][1]);
        __syncthreads();
    }
    #pragma unroll
    for (int ri = 0; ri < 2; ri++)
        #pragma unroll
        for (int ci = 0; ci < 2; ci++) {
            int row0 = m0 + wr + 16 * ri + (lane >> 4) * 4;
            int col  = n0 + wc + 16 * ci + lr;
            #pragma unroll
            for (int r = 0; r < 4; r++) {
                size_t G = (size_t)ib * NRES + row0 + r;
                float inv = 1.0f / msum[G];
                zout[G * DZ + col] = zin[G * DZ + col] + acc[ri][ci][r] * inv + opB[col];
            }
        }
}

// ---------------- launch ----------------
extern "C" void kernel_launch(void* const* d_in, const int* in_sizes, int n_in,
                              void* d_out, int out_size, void* d_ws, size_t ws_size,
                              hipStream_t stream) {
    const float* z     = (const float*)d_in[0];
    const float* m     = (const float*)d_in[1];
    const float* tmask = (const float*)d_in[2];
    const float* smask = (const float*)d_in[3];
    const float* nzw   = (const float*)d_in[4];
    const float* nzb   = (const float*)d_in[5];
    const float* pzw   = (const float*)d_in[6];
    const float* nmw   = (const float*)d_in[7];
    const float* nmb   = (const float*)d_in[8];
    const float* pmw   = (const float*)d_in[9];
    const float* pgw   = (const float*)d_in[10];
    const float* pow_  = (const float*)d_in[11];
    const float* tnw   = (const float*)d_in[12];
    const float* tnb_  = (const float*)d_in[13];
    const float* f1    = (const float*)d_in[14];
    const float* f2    = (const float*)d_in[15];
    const float* f3    = (const float*)d_in[16];
    const float* onw   = (const float*)d_in[17];
    const float* onb   = (const float*)d_in[18];
    const float* paw   = (const float*)d_in[19];
    const float* pbw   = (const float*)d_in[20];
    const float* opW   = (const float*)d_in[21];
    const float* opB   = (const float*)d_in[22];

    float* zout = (float*)d_out;
    float* mout = zout + ZTOT;

    char* W = (char*)d_ws;
    float*    wsf  = (float*)(W);                       //     0 .. 4,718,592
    ushort_t* wsb  = (ushort_t*)(W + 4718592);          //  .. 7,077,888
    ushort_t* mnb  = (ushort_t*)(W + 7077888);          //  .. 19,660,800 (12.6MB)
    ushort_t* vt   = (ushort_t*)(W + 19660800);         //  .. 69,992,448 (50.3MB)
    ushort_t* vtt  = (ushort_t*)(W + 69992448);         //  .. 120,324,096 (50.3MB)
    ushort_t* otb2 = (ushort_t*)(W + 120324096);        //  .. 170,655,744 (50.3MB)
    float*    msum = (float*)(W + 170655744);           //  .. 171,245,568
    ushort_t* f1b  = (ushort_t*)(W + 171245568);
    ushort_t* f2b  = (ushort_t*)(W + 171278336);
    ushort_t* f3b  = (ushort_t*)(W + 171311104);
    ushort_t* opWb = (ushort_t*)(W + 171343872);        //  .. 171,606,016
    ushort_t* pmwb = (ushort_t*)(W + 171606016);
    ushort_t* pgwb = (ushort_t*)(W + 171638784);
    ushort_t* powb = (ushort_t*)(W + 171671552);        //  .. 171,704,320
    ushort_t* abwb = (ushort_t*)(W + 171704320);        //  .. 171,712,512 (8KB)
    // region aliases (dead-by-then):
    ushort_t* gob   = vt;                   // vt dead after k_tr (attn reads vtt)
    ushort_t* tn_bf = vtt;                  // vtt dead after k_attn_mfma
    ushort_t* onb_bf = mnb;                 // mnb dead after k_gate_mfma
    ushort_t* abuf = (ushort_t*)(W + 69992448 + 12582912);   // vtt+12.6MB (dead after k_tr ab)
    ushort_t* bbuf = (ushort_t*)(W + 69992448 + 18874368);   // vtt+18.9MB
    ushort_t* hh   = otb2;                  // otb2 dead after k_gate_mfma
    ushort_t* abt  = otb2;                  // hh dead after k_fc3
    ushort_t* bbt  = (ushort_t*)(W + 120324096 + 6291456);
    ushort_t* opmc = vt;                    // spans vt..vtt (100MB region, all dead at OPM time; needs 75.5MB)

    k_prep<<<512, 256, 0, stream>>>(f1, f2, f3, opW, pmw, pgw, pow_, paw, pbw,
                                    f1b, f2b, f3b, opWb, pmwb, pgwb, powb, abwb);

    // PairWeightedAveraging
    k_bias<<<NPAIR / 4, 256, 0, stream>>>(z, tmask, nzw, nzb, pzw, wsf);
    k_softmax<<<NH * NRES, 64, 0, stream>>>(wsf, wsb);
    k_ln64<<<NROWS / 4, 256, 0, stream>>>(m, nmw, nmb, mnb);
    k_vproj_mfma<<<dim3(HC / 64, NROWS / 64), 256, 0, stream>>>(mnb, pmwb, vt);
    k_tr<<<dim3(SD / 64, NRES / 64, NH), 256, 0, stream>>>(vt, vtt, NRES, SD);
    k_attn_mfma<<<dim3(SD / 128, NRES / 128, NH), 256, 0, stream>>>(wsb, vtt, otb2);
    k_gate_mfma<<<dim3(HC / 64, NROWS / 64), 256, 0, stream>>>(mnb, pgwb, otb2, gob);
    k_out_mfma<<<NROWS / 64, 256, 0, stream>>>(gob, powb, m, mout);

    // Transition (MFMA)
    k_ln64<<<NROWS / 4, 256, 0, stream>>>(mout, tnw, tnb_, tn_bf);
    k_fc12<<<dim3(FF / 64, NROWS / 64), 256, 0, stream>>>(tn_bf, f1b, f2b, hh);
    k_fc3<<<NROWS / 64, 256, 0, stream>>>(hh, f3b, mout);

    // OuterProductMean
    k_ln64<<<NROWS / 4, 256, 0, stream>>>(mout, onw, onb, onb_bf);
    k_ab_mfma<<<NROWS / 64, 256, 0, stream>>>(onb_bf, abwb, smask, abuf, bbuf);
    k_tr<<<dim3((NRES * DOP) / 64, NSEQ / 64, 2), 256, 0, stream>>>(abuf, abt, NSEQ, NRES * DOP);
    k_msum<<<dim3(NRES / 64, NRES / 64), 256, 0, stream>>>(smask, msum);
    for (int cb = 0; cb < NRES / ICHUNK; cb++) {
        int ib = cb * ICHUNK;
        const ushort_t* Achunk = abt + (size_t)(ib * DOP) * NSEQ;
        k_opm_mfma<<<dim3((NRES * DOP) / 128, (ICHUNK * DOP) / 128), 256, 0, stream>>>(Achunk, bbt, opmc);
        k_proj_mfma<<<dim3(DZ / 64, (ICHUNK * NRES) / 64), 256, 0, stream>>>(opmc, opWb, opB, msum, z, zout, ib);
    }
}

// Round 7
// 602.384 us; speedup vs baseline: 11.1386x; 1.1601x over previous
//
#include <hip/hip_runtime.h>
#include <math.h>

// ---------------- problem constants ----------------
constexpr int NRES = 384;          // N
constexpr int NSEQ = 256;          // S
constexpr int DM   = 64;           // MSA_S
constexpr int DZ   = 128;          // Z_D
constexpr int NH   = 8;            // H
constexpr int DH   = 32;           // C_H
constexpr int HC   = NH * DH;      // 256
constexpr int DOP  = 32;           // C_OPM
constexpr int FF   = 4 * DM;       // 256

constexpr int NPAIR = NRES * NRES;         // 147456
constexpr int NROWS = NSEQ * NRES;         // 98304
constexpr int ZTOT  = NPAIR * DZ;          // 18874368
constexpr int SD    = NSEQ * DH;           // 8192
constexpr int ICHUNK = 96;                 // i-rows per OPM chunk (4 chunks)

typedef unsigned short ushort_t;
typedef __attribute__((ext_vector_type(8))) short short8;
typedef __attribute__((ext_vector_type(4))) float f32x4;

__device__ __forceinline__ float wred_sum(float v) {
    #pragma unroll
    for (int off = 32; off; off >>= 1) v += __shfl_xor(v, off, 64);
    return v;
}
__device__ __forceinline__ float sigm(float x) { return 1.0f / (1.0f + expf(-x)); }
__device__ __forceinline__ ushort_t cvt_bf(float f) {
    unsigned u = __float_as_uint(f);
    unsigned r = (u + 0x7FFFu + ((u >> 16) & 1u)) >> 16;
    return (ushort_t)r;
}
__device__ __forceinline__ float cvt_f(ushort_t h) {
    return __uint_as_float(((unsigned)h) << 16);
}
__device__ __forceinline__ f32x4 mfma16(short8 a, short8 b, f32x4 c) {
    return __builtin_amdgcn_mfma_f32_16x16x32_bf16(a, b, c, 0, 0, 0);
}

// ---------------- K0: weights -> bf16 ----------------
__global__ __launch_bounds__(256) void k_prep(const float* __restrict__ f1,
                                              const float* __restrict__ f2,
                                              const float* __restrict__ f3,
                                              const float* __restrict__ opW,
                                              const float* __restrict__ pmw,
                                              const float* __restrict__ pgw,
                                              const float* __restrict__ pow_,
                                              const float* __restrict__ paw,
                                              const float* __restrict__ pbw,
                                              const float* __restrict__ pzw,
                                              ushort_t* __restrict__ f1b,
                                              ushort_t* __restrict__ f2b,
                                              ushort_t* __restrict__ f3b,
                                              ushort_t* __restrict__ opWb,
                                              ushort_t* __restrict__ pmwb,
                                              ushort_t* __restrict__ pgwb,
                                              ushort_t* __restrict__ powb,
                                              ushort_t* __restrict__ abwb,
                                              ushort_t* __restrict__ pzwb) {
    int i = blockIdx.x * 256 + threadIdx.x;      // 131072 threads
    opWb[i] = cvt_bf(opW[i]);
    if (i < FF * DM) {
        f1b[i] = cvt_bf(f1[i]);
        f2b[i] = cvt_bf(f2[i]);
        f3b[i] = cvt_bf(f3[i]);
    }
    if (i < HC * DM) {
        pmwb[i] = cvt_bf(pmw[i]);
        pgwb[i] = cvt_bf(pgw[i]);
        powb[i] = cvt_bf(pow_[i]);
    }
    if (i < 2 * DOP * DM) {                      // combined [64][64]: rows 0..31 paw, 32..63 pbw
        abwb[i] = cvt_bf(i < DOP * DM ? paw[i] : pbw[i - DOP * DM]);
    }
    if (i < 16 * DZ) {                           // [16][128]: rows 0..7 pzw, rows 8..15 zero
        pzwb[i] = (i < NH * DZ) ? cvt_bf(pzw[i]) : (ushort_t)0;
    }
}

// ---------------- K1a: LN(z) -> bf16 zlnb ----------------
__global__ __launch_bounds__(256) void k_lnz(const float* __restrict__ z,
                                             const float* __restrict__ nzw,
                                             const float* __restrict__ nzb,
                                             ushort_t* __restrict__ zlnb) {
    int wave = threadIdx.x >> 6, lane = threadIdx.x & 63;
    int pair = blockIdx.x * 4 + wave;
    const float* zr = z + (size_t)pair * DZ;
    float x0 = zr[lane], x1 = zr[lane + 64];
    float s1 = x0 + x1, s2 = x0 * x0 + x1 * x1;
    #pragma unroll
    for (int off = 32; off; off >>= 1) {
        s1 += __shfl_xor(s1, off, 64);
        s2 += __shfl_xor(s2, off, 64);
    }
    float mu = s1 * (1.0f / 128.0f);
    float var = s2 * (1.0f / 128.0f) - mu * mu;
    float rs = rsqrtf(var + 1e-5f);
    zlnb[(size_t)pair * DZ + lane]      = cvt_bf((x0 - mu) * rs * nzw[lane] + nzb[lane]);
    zlnb[(size_t)pair * DZ + lane + 64] = cvt_bf((x1 - mu) * rs * nzw[lane + 64] + nzb[lane + 64]);
}

// ---------------- K1b: pair bias proj + mask + softmax -> wsb (one block per i) ----------------
__global__ __launch_bounds__(256) void k_biassm(const ushort_t* __restrict__ zlnb,
                                                const ushort_t* __restrict__ pzwb,
                                                const float* __restrict__ tmask,
                                                ushort_t* __restrict__ wsb) {
    int i = blockIdx.x;                         // 0..383
    __shared__ ushort_t Azl[128][136];
    __shared__ ushort_t Bl[16][136];
    __shared__ float ob[8][388];
    int t = threadIdx.x;
    int wave = t >> 6, lane = t & 63;
    int lk = (lane >> 4) * 8, lr = lane & 15;
    int wr = wave * 32;
    // stage B once
    for (int idx = t * 8; idx < 16 * DZ; idx += 256 * 8) {
        int row = idx >> 7, col = idx & 127;
        *(short8*)&Bl[row][col] = *(const short8*)&pzwb[idx];
    }
    __syncthreads();
    for (int c = 0; c < 3; c++) {
        // stage A chunk: rows j = c*128 .. +127
        {
            int jl = t >> 1, cb = (t & 1) * 64;
            const ushort_t* src = &zlnb[((size_t)i * NRES + c * 128 + jl) * DZ + cb];
            #pragma unroll
            for (int q = 0; q < 8; q++)
                *(short8*)&Azl[jl][cb + q * 8] = *(const short8*)&src[q * 8];
        }
        __syncthreads();
        f32x4 acc[2] = {};
        #pragma unroll
        for (int ks = 0; ks < 4; ks++) {
            short8 b = *(const short8*)&Bl[lr][ks * 32 + lk];
            short8 a0 = *(const short8*)&Azl[wr + lr][ks * 32 + lk];
            short8 a1 = *(const short8*)&Azl[wr + 16 + lr][ks * 32 + lk];
            acc[0] = mfma16(a0, b, acc[0]);
            acc[1] = mfma16(a1, b, acc[1]);
        }
        if (lr < NH) {
            #pragma unroll
            for (int ri = 0; ri < 2; ri++) {
                int jb = c * 128 + wr + 16 * ri + (lane >> 4) * 4;
                #pragma unroll
                for (int r = 0; r < 4; r++)
                    ob[lr][jb + r] = acc[ri][r];
            }
        }
        __syncthreads();
    }
    // softmax over j per head (half-wave = one head)
    int h = wave * 2 + (lane >> 5);
    int l32 = lane & 31;
    int jb = l32 * 12;
    const float* tm = &tmask[(size_t)i * NRES];
    float vals[12];
    float mx = -1e30f;
    #pragma unroll
    for (int q = 0; q < 12; q++) {
        float v = ob[h][jb + q] + (1.0f - tm[jb + q]) * (-1e9f);
        vals[q] = v;
        mx = fmaxf(mx, v);
    }
    #pragma unroll
    for (int off = 16; off; off >>= 1) mx = fmaxf(mx, __shfl_xor(mx, off, 64));
    float sum = 0.0f;
    #pragma unroll
    for (int q = 0; q < 12; q++) { vals[q] = expf(vals[q] - mx); sum += vals[q]; }
    #pragma unroll
    for (int off = 16; off; off >>= 1) sum += __shfl_xor(sum, off, 64);
    float inv = 1.0f / sum;
    ushort_t* o = &wsb[(size_t)h * NPAIR + (size_t)i * NRES + jb];
    #pragma unroll
    for (int q = 0; q < 12; q++) o[q] = cvt_bf(vals[q] * inv);
}

// ---------------- K3: LN rows (64-wide) fp32 -> bf16 ----------------
__global__ __launch_bounds__(256) void k_ln64(const float* __restrict__ src,
                                              const float* __restrict__ lw,
                                              const float* __restrict__ lb,
                                              ushort_t* __restrict__ dst) {
    int wave = threadIdx.x >> 6, lane = threadIdx.x & 63;
    int r = blockIdx.x * 4 + wave;
    float x = src[(size_t)r * DM + lane];
    float mu = wred_sum(x) * (1.0f / 64.0f);
    float d = x - mu;
    float var = wred_sum(d * d) * (1.0f / 64.0f);
    dst[(size_t)r * DM + lane] = cvt_bf(d * rsqrtf(var + 1e-5f) * lw[lane] + lb[lane]);
}

// ---------------- K3b: v projection GEMM -> vtt[h][s*32+d][n] directly ----------------
__global__ __launch_bounds__(256) void k_vproj_mfma(const ushort_t* __restrict__ A,
                                                    const ushort_t* __restrict__ Bt,
                                                    ushort_t* __restrict__ vtt) {
    int m0 = blockIdx.y * 64, n0c = blockIdx.x * 64;
    __shared__ ushort_t Al[64][40];
    __shared__ ushort_t Bl[64][40];
    __shared__ ushort_t ot[64][72];
    int t = threadIdx.x;
    int srow = t >> 2, sko = (t & 3) * 8;
    int wave = t >> 6, lane = t & 63;
    int wr = (wave >> 1) * 32, wc = (wave & 1) * 32;
    int lk = (lane >> 4) * 8, lr = lane & 15;
    f32x4 acc[2][2] = {};
    for (int k0 = 0; k0 < DM; k0 += 32) {
        *(short8*)&Al[srow][sko] = *(const short8*)&A[(size_t)(m0 + srow) * DM + k0 + sko];
        *(short8*)&Bl[srow][sko] = *(const short8*)&Bt[(size_t)(n0c + srow) * DM + k0 + sko];
        __syncthreads();
        short8 a0 = *(const short8*)&Al[wr + lr][lk];
        short8 a1 = *(const short8*)&Al[wr + 16 + lr][lk];
        short8 b0 = *(const short8*)&Bl[wc + lr][lk];
        short8 b1 = *(const short8*)&Bl[wc + 16 + lr][lk];
        acc[0][0] = mfma16(a0, b0, acc[0][0]);
        acc[0][1] = mfma16(a0, b1, acc[0][1]);
        acc[1][0] = mfma16(a1, b0, acc[1][0]);
        acc[1][1] = mfma16(a1, b1, acc[1][1]);
        __syncthreads();
    }
    // transpose in LDS: ot[col][row]
    #pragma unroll
    for (int ri = 0; ri < 2; ri++)
        #pragma unroll
        for (int ci = 0; ci < 2; ci++) {
            int rowb = wr + 16 * ri + (lane >> 4) * 4;
            int colb = wc + 16 * ci + lr;
            #pragma unroll
            for (int r = 0; r < 4; r++)
                ot[colb][rowb + r] = cvt_bf(acc[ri][ci][r]);
        }
    __syncthreads();
    int s = m0 / NRES, n0 = m0 % NRES;
    int h0 = n0c >> 5;                          // two heads h0, h0+1
    int orow = t >> 2, seg = (t & 3) * 16;
    short8 v0 = *(const short8*)&ot[orow][seg];
    short8 v1 = *(const short8*)&ot[orow][seg + 8];
    int hh = orow >> 5, dd = orow & 31;
    ushort_t* dst = &vtt[(((size_t)(h0 + hh) * SD) + s * DH + dd) * NRES + n0 + seg];
    *(short8*)&dst[0] = v0;
    *(short8*)&dst[8] = v1;
}

// ---------------- generic 64x64 bf16 transpose ----------------
__global__ __launch_bounds__(256) void k_tr(const ushort_t* __restrict__ src,
                                            ushort_t* __restrict__ dst,
                                            int R, int C) {
    size_t bs = (size_t)R * C;
    const ushort_t* s = src + blockIdx.z * bs;
    ushort_t* d = dst + blockIdx.z * bs;
    int r0 = blockIdx.y * 64, c0 = blockIdx.x * 64;
    __shared__ ushort_t tile[64][72];
    int t = threadIdx.x;
    int tr = t >> 2, tc = (t & 3) * 16;
    *(short8*)&tile[tr][tc]     = *(const short8*)&s[(size_t)(r0 + tr) * C + c0 + tc];
    *(short8*)&tile[tr][tc + 8] = *(const short8*)&s[(size_t)(r0 + tr) * C + c0 + tc + 8];
    __syncthreads();
    short8 o0, o1;
    #pragma unroll
    for (int i = 0; i < 8; i++) {
        o0[i] = (short)tile[tc + i][tr];
        o1[i] = (short)tile[tc + 8 + i][tr];
    }
    *(short8*)&d[(size_t)(c0 + tr) * R + r0 + tc]     = o0;
    *(short8*)&d[(size_t)(c0 + tr) * R + r0 + tc + 8] = o1;
}

// ---------------- K4: attention GEMM per head (128x128 tile) -> otb2[(s*N+i)][h*32+d] ----------------
__global__ __launch_bounds__(256) void k_attn_mfma(const ushort_t* __restrict__ wsb,
                                                   const ushort_t* __restrict__ vtt,
                                                   ushort_t* __restrict__ otb2) {
    int h = blockIdx.z;
    const ushort_t* A  = wsb + (size_t)h * NPAIR;        // [384][384]
    const ushort_t* Bt = vtt + (size_t)h * SD * NRES;    // [8192][384]
    int m0 = blockIdx.y * 128, n0 = blockIdx.x * 128;
    __shared__ ushort_t Al[128][40];
    __shared__ ushort_t Bl[128][40];
    int t = threadIdx.x;
    int srow = t >> 1, sko = (t & 1) * 16;
    int wave = t >> 6, lane = t & 63;
    int wr = (wave >> 1) * 64, wc = (wave & 1) * 64;
    int lk = (lane >> 4) * 8, lr = lane & 15;
    f32x4 acc[4][4] = {};
    for (int k0 = 0; k0 < NRES; k0 += 32) {
        *(short8*)&Al[srow][sko]     = *(const short8*)&A[(size_t)(m0 + srow) * NRES + k0 + sko];
        *(short8*)&Al[srow][sko + 8] = *(const short8*)&A[(size_t)(m0 + srow) * NRES + k0 + sko + 8];
        *(short8*)&Bl[srow][sko]     = *(const short8*)&Bt[(size_t)(n0 + srow) * NRES + k0 + sko];
        *(short8*)&Bl[srow][sko + 8] = *(const short8*)&Bt[(size_t)(n0 + srow) * NRES + k0 + sko + 8];
        __syncthreads();
        short8 af[4], bf2[4];
        #pragma unroll
        for (int i = 0; i < 4; i++) {
            af[i]  = *(const short8*)&Al[wr + 16 * i + lr][lk];
            bf2[i] = *(const short8*)&Bl[wc + 16 * i + lr][lk];
        }
        #pragma unroll
        for (int ri = 0; ri < 4; ri++)
            #pragma unroll
            for (int ci = 0; ci < 4; ci++)
                acc[ri][ci] = mfma16(af[ri], bf2[ci], acc[ri][ci]);
        __syncthreads();
    }
    #pragma unroll
    for (int ri = 0; ri < 4; ri++)
        #pragma unroll
        for (int ci = 0; ci < 4; ci++) {
            int row0 = m0 + wr + 16 * ri + (lane >> 4) * 4;   // i
            int col  = n0 + wc + 16 * ci + lr;                // s*32+d
            int s = col >> 5, dd = col & 31;
            #pragma unroll
            for (int r = 0; r < 4; r++)
                otb2[((size_t)s * NRES + row0 + r) * HC + h * DH + dd] = cvt_bf(acc[ri][ci][r]);
        }
}

// ---------------- K5a: gate GEMM + sigmoid*o -> gob ----------------
__global__ __launch_bounds__(256) void k_gate_mfma(const ushort_t* __restrict__ A,
                                                   const ushort_t* __restrict__ Bt,
                                                   const ushort_t* __restrict__ otb2,
                                                   ushort_t* __restrict__ gob) {
    int m0 = blockIdx.y * 64, n0 = blockIdx.x * 64;
    __shared__ ushort_t Al[64][40];
    __shared__ ushort_t Bl[64][40];
    int t = threadIdx.x;
    int srow = t >> 2, sko = (t & 3) * 8;
    int wave = t >> 6, lane = t & 63;
    int wr = (wave >> 1) * 32, wc = (wave & 1) * 32;
    int lk = (lane >> 4) * 8, lr = lane & 15;
    f32x4 acc[2][2] = {};
    for (int k0 = 0; k0 < DM; k0 += 32) {
        *(short8*)&Al[srow][sko] = *(const short8*)&A[(size_t)(m0 + srow) * DM + k0 + sko];
        *(short8*)&Bl[srow][sko] = *(const short8*)&Bt[(size_t)(n0 + srow) * DM + k0 + sko];
        __syncthreads();
        short8 a0 = *(const short8*)&Al[wr + lr][lk];
        short8 a1 = *(const short8*)&Al[wr + 16 + lr][lk];
        short8 b0 = *(const short8*)&Bl[wc + lr][lk];
        short8 b1 = *(const short8*)&Bl[wc + 16 + lr][lk];
        acc[0][0] = mfma16(a0, b0, acc[0][0]);
        acc[0][1] = mfma16(a0, b1, acc[0][1]);
        acc[1][0] = mfma16(a1, b0, acc[1][0]);
        acc[1][1] = mfma16(a1, b1, acc[1][1]);
        __syncthreads();
    }
    #pragma unroll
    for (int ri = 0; ri < 2; ri++)
        #pragma unroll
        for (int ci = 0; ci < 2; ci++) {
            int row0 = m0 + wr + 16 * ri + (lane >> 4) * 4;
            int col  = n0 + wc + 16 * ci + lr;
            #pragma unroll
            for (int r = 0; r < 4; r++) {
                size_t idx = (size_t)(row0 + r) * HC + col;
                float ov = cvt_f(otb2[idx]);
                gob[idx] = cvt_bf(sigm(acc[ri][ci][r]) * ov);
            }
        }
}

// ---------------- K5b: output GEMM + residual -> mout ----------------
__global__ __launch_bounds__(256) void k_out_mfma(const ushort_t* __restrict__ A,
                                                  const ushort_t* __restrict__ Bt,
                                                  const float* __restrict__ m,
                                                  float* __restrict__ mout) {
    int m0 = blockIdx.x * 64;
    __shared__ ushort_t Al[64][40];
    __shared__ ushort_t Bl[64][40];
    int t = threadIdx.x;
    int srow = t >> 2, sko = (t & 3) * 8;
    int wave = t >> 6, lane = t & 63;
    int wr = (wave >> 1) * 32, wc = (wave & 1) * 32;
    int lk = (lane >> 4) * 8, lr = lane & 15;
    f32x4 acc[2][2] = {};
    for (int k0 = 0; k0 < HC; k0 += 32) {
        *(short8*)&Al[srow][sko] = *(const short8*)&A[(size_t)(m0 + srow) * HC + k0 + sko];
        *(short8*)&Bl[srow][sko] = *(const short8*)&Bt[(size_t)srow * HC + k0 + sko];
        __syncthreads();
        short8 a0 = *(const short8*)&Al[wr + lr][lk];
        short8 a1 = *(const short8*)&Al[wr + 16 + lr][lk];
        short8 b0 = *(const short8*)&Bl[wc + lr][lk];
        short8 b1 = *(const short8*)&Bl[wc + 16 + lr][lk];
        acc[0][0] = mfma16(a0, b0, acc[0][0]);
        acc[0][1] = mfma16(a0, b1, acc[0][1]);
        acc[1][0] = mfma16(a1, b0, acc[1][0]);
        acc[1][1] = mfma16(a1, b1, acc[1][1]);
        __syncthreads();
    }
    #pragma unroll
    for (int ri = 0; ri < 2; ri++)
        #pragma unroll
        for (int ci = 0; ci < 2; ci++) {
            int row0 = m0 + wr + 16 * ri + (lane >> 4) * 4;
            int col  = wc + 16 * ci + lr;
            #pragma unroll
            for (int r = 0; r < 4; r++) {
                size_t idx = (size_t)(row0 + r) * DM + col;
                mout[idx] = m[idx] + acc[ri][ci][r];
            }
        }
}

// ---------------- K6b: fc1/fc2 GEMM + SwiGLU -> hh bf16 ----------------
__global__ __launch_bounds__(256) void k_fc12(const ushort_t* __restrict__ A,
                                              const ushort_t* __restrict__ B1t,
                                              const ushort_t* __restrict__ B2t,
                                              ushort_t* __restrict__ hh) {
    int m0 = blockIdx.y * 64, n0 = blockIdx.x * 64;
    __shared__ ushort_t Al[64][40];
    __shared__ ushort_t B1l[64][40];
    __shared__ ushort_t B2l[64][40];
    int t = threadIdx.x;
    int srow = t >> 2, sko = (t & 3) * 8;
    int wave = t >> 6, lane = t & 63;
    int wr = (wave >> 1) * 32, wc = (wave & 1) * 32;
    int lk = (lane >> 4) * 8, lr = lane & 15;
    f32x4 acc1[2][2] = {}, acc2[2][2] = {};
    for (int k0 = 0; k0 < DM; k0 += 32) {
        *(short8*)&Al[srow][sko]  = *(const short8*)&A[(size_t)(m0 + srow) * DM + k0 + sko];
        *(short8*)&B1l[srow][sko] = *(const short8*)&B1t[(size_t)(n0 + srow) * DM + k0 + sko];
        *(short8*)&B2l[srow][sko] = *(const short8*)&B2t[(size_t)(n0 + srow) * DM + k0 + sko];
        __syncthreads();
        short8 a0 = *(const short8*)&Al[wr + lr][lk];
        short8 a1 = *(const short8*)&Al[wr + 16 + lr][lk];
        short8 p0 = *(const short8*)&B1l[wc + lr][lk];
        short8 p1 = *(const short8*)&B1l[wc + 16 + lr][lk];
        short8 q0 = *(const short8*)&B2l[wc + lr][lk];
        short8 q1 = *(const short8*)&B2l[wc + 16 + lr][lk];
        acc1[0][0] = mfma16(a0, p0, acc1[0][0]);
        acc1[0][1] = mfma16(a0, p1, acc1[0][1]);
        acc1[1][0] = mfma16(a1, p0, acc1[1][0]);
        acc1[1][1] = mfma16(a1, p1, acc1[1][1]);
        acc2[0][0] = mfma16(a0, q0, acc2[0][0]);
        acc2[0][1] = mfma16(a0, q1, acc2[0][1]);
        acc2[1][0] = mfma16(a1, q0, acc2[1][0]);
        acc2[1][1] = mfma16(a1, q1, acc2[1][1]);
        __syncthreads();
    }
    #pragma unroll
    for (int ri = 0; ri < 2; ri++)
        #pragma unroll
        for (int ci = 0; ci < 2; ci++) {
            int row0 = m0 + wr + 16 * ri + (lane >> 4) * 4;
            int col  = n0 + wc + 16 * ci + lr;
            #pragma unroll
            for (int r = 0; r < 4; r++) {
                float a1v = acc1[ri][ci][r], a2v = acc2[ri][ci][r];
                hh[(size_t)(row0 + r) * FF + col] = cvt_bf(a1v * sigm(a1v) * a2v);
            }
        }
}

// ---------------- K6c: fc3 GEMM + residual into mout ----------------
__global__ __launch_bounds__(256) void k_fc3(const ushort_t* __restrict__ A,
                                             const ushort_t* __restrict__ Bt,
                                             float* __restrict__ mio) {
    int m0 = blockIdx.x * 64;
    __shared__ ushort_t Al[64][40];
    __shared__ ushort_t Bl[64][40];
    int t = threadIdx.x;
    int srow = t >> 2, sko = (t & 3) * 8;
    int wave = t >> 6, lane = t & 63;
    int wr = (wave >> 1) * 32, wc = (wave & 1) * 32;
    int lk = (lane >> 4) * 8, lr = lane & 15;
    f32x4 acc[2][2] = {};
    for (int k0 = 0; k0 < FF; k0 += 32) {
        *(short8*)&Al[srow][sko] = *(const short8*)&A[(size_t)(m0 + srow) * FF + k0 + sko];
        *(short8*)&Bl[srow][sko] = *(const short8*)&Bt[(size_t)srow * FF + k0 + sko];
        __syncthreads();
        short8 a0 = *(const short8*)&Al[wr + lr][lk];
        short8 a1 = *(const short8*)&Al[wr + 16 + lr][lk];
        short8 b0 = *(const short8*)&Bl[wc + lr][lk];
        short8 b1 = *(const short8*)&Bl[wc + 16 + lr][lk];
        acc[0][0] = mfma16(a0, b0, acc[0][0]);
        acc[0][1] = mfma16(a0, b1, acc[0][1]);
        acc[1][0] = mfma16(a1, b0, acc[1][0]);
        acc[1][1] = mfma16(a1, b1, acc[1][1]);
        __syncthreads();
    }
    #pragma unroll
    for (int ri = 0; ri < 2; ri++)
        #pragma unroll
        for (int ci = 0; ci < 2; ci++) {
            int row0 = m0 + wr + 16 * ri + (lane >> 4) * 4;
            int col  = wc + 16 * ci + lr;
            #pragma unroll
            for (int r = 0; r < 4; r++)
                mio[(size_t)(row0 + r) * DM + col] += acc[ri][ci][r];
        }
}

// ---------------- K7: a/b projection GEMM + mask -> abuf/bbuf [s][n*32+c] ----------------
__global__ __launch_bounds__(256) void k_ab_mfma(const ushort_t* __restrict__ A,
                                                 const ushort_t* __restrict__ Bt,
                                                 const float* __restrict__ smask,
                                                 ushort_t* __restrict__ abuf,
                                                 ushort_t* __restrict__ bbuf) {
    int m0 = blockIdx.x * 64;
    __shared__ ushort_t Al[64][40];
    __shared__ ushort_t Bl[64][40];
    int t = threadIdx.x;
    int srow = t >> 2, sko = (t & 3) * 8;
    int wave = t >> 6, lane = t & 63;
    int wr = (wave >> 1) * 32, wc = (wave & 1) * 32;
    int lk = (lane >> 4) * 8, lr = lane & 15;
    f32x4 acc[2][2] = {};
    for (int k0 = 0; k0 < DM; k0 += 32) {
        *(short8*)&Al[srow][sko] = *(const short8*)&A[(size_t)(m0 + srow) * DM + k0 + sko];
        *(short8*)&Bl[srow][sko] = *(const short8*)&Bt[(size_t)srow * DM + k0 + sko];
        __syncthreads();
        short8 a0 = *(const short8*)&Al[wr + lr][lk];
        short8 a1 = *(const short8*)&Al[wr + 16 + lr][lk];
        short8 b0 = *(const short8*)&Bl[wc + lr][lk];
        short8 b1 = *(const short8*)&Bl[wc + 16 + lr][lk];
        acc[0][0] = mfma16(a0, b0, acc[0][0]);
        acc[0][1] = mfma16(a0, b1, acc[0][1]);
        acc[1][0] = mfma16(a1, b0, acc[1][0]);
        acc[1][1] = mfma16(a1, b1, acc[1][1]);
        __syncthreads();
    }
    #pragma unroll
    for (int ri = 0; ri < 2; ri++)
        #pragma unroll
        for (int ci = 0; ci < 2; ci++) {
            int row0 = m0 + wr + 16 * ri + (lane >> 4) * 4;
            int col  = wc + 16 * ci + lr;               // 0..63
            #pragma unroll
            for (int r = 0; r < 4; r++) {
                int rr = row0 + r;                      // s*NRES+n
                int s = rr / NRES, n = rr % NRES;
                float v = acc[ri][ci][r] * smask[rr];
                if (col < DOP)
                    abuf[(size_t)s * (NRES * DOP) + n * DOP + col] = cvt_bf(v);
                else
                    bbuf[(size_t)s * (NRES * DOP) + n * DOP + (col - DOP)] = cvt_bf(v);
            }
        }
}

// ---------------- K8: mask pair-count Gram tile ----------------
__global__ __launch_bounds__(256) void k_msum(const float* __restrict__ smask,
                                              float* __restrict__ msum) {
    int i0 = blockIdx.y * 64, j0 = blockIdx.x * 64;
    __shared__ float As[16][64];
    __shared__ float Bs[16][64];
    int t = threadIdx.x;
    int ty = t >> 4, tx = t & 15;
    float acc[4][4] = {};
    for (int k0 = 0; k0 < NSEQ; k0 += 16) {
        int kk = t >> 4, x4 = (t & 15) * 4;
        *(float4*)&As[kk][x4] = *(const float4*)&smask[(size_t)(k0 + kk) * NRES + i0 + x4];
        *(float4*)&Bs[kk][x4] = *(const float4*)&smask[(size_t)(k0 + kk) * NRES + j0 + x4];
        __syncthreads();
        #pragma unroll
        for (int k = 0; k < 16; k++) {
            float4 a4 = *(const float4*)&As[k][ty * 4];
            float4 b4 = *(const float4*)&Bs[k][tx * 4];
            float ar[4] = {a4.x, a4.y, a4.z, a4.w};
            float br[4] = {b4.x, b4.y, b4.z, b4.w};
            #pragma unroll
            for (int i2 = 0; i2 < 4; i2++)
                #pragma unroll
                for (int j2 = 0; j2 < 4; j2++)
                    acc[i2][j2] += ar[i2] * br[j2];
        }
        __syncthreads();
    }
    #pragma unroll
    for (int r = 0; r < 4; r++) {
        float4 o4 = make_float4(fmaxf(acc[r][0], 1.0f), fmaxf(acc[r][1], 1.0f),
                                fmaxf(acc[r][2], 1.0f), fmaxf(acc[r][3], 1.0f));
        *(float4*)&msum[(size_t)(i0 + ty * 4 + r) * NRES + j0 + tx * 4] = o4;
    }
}

// ---------------- K9: OPM outer GEMM (bf16 MFMA, 128x128 tile) ----------------
__global__ __launch_bounds__(256) void k_opm_mfma(const ushort_t* __restrict__ At,
                                                  const ushort_t* __restrict__ Bt,
                                                  ushort_t* __restrict__ opmc) {
    int m0 = blockIdx.y * 128;                  // over ICHUNK*32 (il,c)
    int n0 = blockIdx.x * 128;                  // over 12288 (j,d)
    __shared__ ushort_t Al[128][40];
    __shared__ ushort_t Bl[128][40];
    int t = threadIdx.x;
    int srow = t >> 1, sko = (t & 1) * 16;
    int wave = t >> 6, lane = t & 63;
    int wr = (wave >> 1) * 64, wc = (wave & 1) * 64;
    int lk = (lane >> 4) * 8, lr = lane & 15;
    f32x4 acc[4][4] = {};
    for (int k0 = 0; k0 < NSEQ; k0 += 32) {
        *(short8*)&Al[srow][sko]     = *(const short8*)&At[(size_t)(m0 + srow) * NSEQ + k0 + sko];
        *(short8*)&Al[srow][sko + 8] = *(const short8*)&At[(size_t)(m0 + srow) * NSEQ + k0 + sko + 8];
        *(short8*)&Bl[srow][sko]     = *(const short8*)&Bt[(size_t)(n0 + srow) * NSEQ + k0 + sko];
        *(short8*)&Bl[srow][sko + 8] = *(const short8*)&Bt[(size_t)(n0 + srow) * NSEQ + k0 + sko + 8];
        __syncthreads();
        short8 af[4], bf2[4];
        #pragma unroll
        for (int i = 0; i < 4; i++) {
            af[i]  = *(const short8*)&Al[wr + 16 * i + lr][lk];
            bf2[i] = *(const short8*)&Bl[wc + 16 * i + lr][lk];
        }
        #pragma unroll
        for (int ri = 0; ri < 4; ri++)
            #pragma unroll
            for (int ci = 0; ci < 4; ci++)
                acc[ri][ci] = mfma16(af[ri], bf2[ci], acc[ri][ci]);
        __syncthreads();
    }
    #pragma unroll
    for (int ri = 0; ri < 4; ri++)
        #pragma unroll
        for (int ci = 0; ci < 4; ci++) {
            int mb = m0 + wr + 16 * ri + (lane >> 4) * 4;
            int n  = n0 + wc + 16 * ci + lr;
            int j = n >> 5, dd = n & 31;
            #pragma unroll
            for (int r = 0; r < 4; r++) {
                int mm = mb + r;
                int il = mm >> 5, c = mm & 31;
                opmc[((size_t)(il * NRES + j) << 10) + (c << 5) + dd] = cvt_bf(acc[ri][ci][r]);
            }
        }
}

// ---------------- K10: OPM projection + residual ----------------
__global__ __launch_bounds__(256) void k_proj_mfma(const ushort_t* __restrict__ A,
                                                   const ushort_t* __restrict__ Bt,
                                                   const float* __restrict__ opB,
                                                   const float* __restrict__ msum,
                                                   const float* __restrict__ zin,
                                                   float* __restrict__ zout,
                                                   int ib) {
    int m0 = blockIdx.y * 64, n0 = blockIdx.x * 64;
    __shared__ ushort_t Al[64][40];
    __shared__ ushort_t Bl[64][40];
    int t = threadIdx.x;
    int srow = t >> 2, sko = (t & 3) * 8;
    int wave = t >> 6, lane = t & 63;
    int wr = (wave >> 1) * 32, wc = (wave & 1) * 32;
    int lk = (lane >> 4) * 8, lr = lane & 15;
    f32x4 acc[2][2] = {};
    for (int k0 = 0; k0 < 1024; k0 += 32) {
        *(short8*)&Al[srow][sko] = *(const short8*)&A[(size_t)(m0 + srow) * 1024 + k0 + sko];
        *(short8*)&Bl[srow][sko] = *(const short8*)&Bt[(size_t)(n0 + srow) * 1024 + k0 + sko];
        __syncthreads();
        short8 a0 = *(const short8*)&Al[wr + lr][lk];
        short8 a1 = *(const short8*)&Al[wr + 16 + lr][lk];
        short8 b0 = *(const short8*)&Bl[wc + lr][lk];
        short8 b1 = *(const short8*)&Bl[wc + 16 + lr][lk];
        acc[0][0] = mfma16(a0, b0, acc[0][0]);
        acc[0][1] = mfma16(a0, b1, acc[0][1]);
        acc[1][0] = mfma16(a1, b0, acc[1][0]);
        acc[1][1] = mfma16(a1, b1, acc[1][1]);
        __syncthreads();
    }
    #pragma unroll
    for (int ri = 0; ri < 2; ri++)
        #pragma unroll
        for (int ci = 0; ci < 2; ci++) {
            int row0 = m0 + wr + 16 * ri + (lane >> 4) * 4;
            int col  = n0 + wc + 16 * ci + lr;
            #pragma unroll
            for (int r = 0; r < 4; r++) {
                size_t G = (size_t)ib * NRES + row0 + r;
                float inv = 1.0f / msum[G];
                zout[G * DZ + col] = zin[G * DZ + col] + acc[ri][ci][r] * inv + opB[col];
            }
        }
}

// ---------------- launch ----------------
extern "C" void kernel_launch(void* const* d_in, const int* in_sizes, int n_in,
                              void* d_out, int out_size, void* d_ws, size_t ws_size,
                              hipStream_t stream) {
    const float* z     = (const float*)d_in[0];
    const float* m     = (const float*)d_in[1];
    const float* tmask = (const float*)d_in[2];
    const float* smask = (const float*)d_in[3];
    const float* nzw   = (const float*)d_in[4];
    const float* nzb   = (const float*)d_in[5];
    const float* pzw   = (const float*)d_in[6];
    const float* nmw   = (const float*)d_in[7];
    const float* nmb   = (const float*)d_in[8];
    const float* pmw   = (const float*)d_in[9];
    const float* pgw   = (const float*)d_in[10];
    const float* pow_  = (const float*)d_in[11];
    const float* tnw   = (const float*)d_in[12];
    const float* tnb_  = (const float*)d_in[13];
    const float* f1    = (const float*)d_in[14];
    const float* f2    = (const float*)d_in[15];
    const float* f3    = (const float*)d_in[16];
    const float* onw   = (const float*)d_in[17];
    const float* onb   = (const float*)d_in[18];
    const float* paw   = (const float*)d_in[19];
    const float* pbw   = (const float*)d_in[20];
    const float* opW   = (const float*)d_in[21];
    const float* opB   = (const float*)d_in[22];

    float* zout = (float*)d_out;
    float* mout = zout + ZTOT;

    char* W = (char*)d_ws;
    ushort_t* wsb  = (ushort_t*)(W + 4718592);          //  .. 7,077,888 (bf16 softmax wts)
    ushort_t* mnb  = (ushort_t*)(W + 7077888);          //  .. 19,660,800 (12.6MB)
    ushort_t* vtR  = (ushort_t*)(W + 19660800);         //  .. 69,992,448 (50.3MB, multi-use)
    ushort_t* vtt  = (ushort_t*)(W + 69992448);         //  .. 120,324,096 (50.3MB)
    ushort_t* otb2 = (ushort_t*)(W + 120324096);        //  .. 170,655,744 (50.3MB)
    float*    msum = (float*)(W + 170655744);           //  .. 171,245,568
    ushort_t* f1b  = (ushort_t*)(W + 171245568);
    ushort_t* f2b  = (ushort_t*)(W + 171278336);
    ushort_t* f3b  = (ushort_t*)(W + 171311104);
    ushort_t* opWb = (ushort_t*)(W + 171343872);        //  .. 171,606,016
    ushort_t* pmwb = (ushort_t*)(W + 171606016);
    ushort_t* pgwb = (ushort_t*)(W + 171638784);
    ushort_t* powb = (ushort_t*)(W + 171671552);        //  .. 171,704,320
    ushort_t* abwb = (ushort_t*)(W + 171704320);        //  .. 171,712,512 (8KB)
    ushort_t* pzwb = (ushort_t*)(W + 171712512);        //  .. 171,716,608 (4KB)
    // region aliases (dead-by-then):
    ushort_t* zlnb = vtR;                   // LN(z) bf16 (37.7MB), dead after k_biassm
    ushort_t* gob  = vtR;                   // gate output, written after biassm
    ushort_t* tn_bf = vtt;                  // vtt dead after k_attn_mfma
    ushort_t* onb_bf = mnb;                 // mnb dead after k_gate_mfma
    ushort_t* abuf = (ushort_t*)(W + 69992448 + 12582912);   // vtt+12.6MB
    ushort_t* bbuf = (ushort_t*)(W + 69992448 + 18874368);   // vtt+18.9MB
    ushort_t* hh   = otb2;                  // otb2 dead after k_gate_mfma
    ushort_t* abt  = otb2;                  // hh dead after k_fc3
    ushort_t* bbt  = (ushort_t*)(W + 120324096 + 6291456);
    ushort_t* opmc = vtR;                   // spans vtR..vtt (dead at OPM time; needs 75.5MB < 100.6MB)

    k_prep<<<512, 256, 0, stream>>>(f1, f2, f3, opW, pmw, pgw, pow_, paw, pbw, pzw,
                                    f1b, f2b, f3b, opWb, pmwb, pgwb, powb, abwb, pzwb);

    // PairWeightedAveraging
    k_lnz<<<NPAIR / 4, 256, 0, stream>>>(z, nzw, nzb, zlnb);
    k_biassm<<<NRES, 256, 0, stream>>>(zlnb, pzwb, tmask, wsb);
    k_ln64<<<NROWS / 4, 256, 0, stream>>>(m, nmw, nmb, mnb);
    k_vproj_mfma<<<dim3(HC / 64, NROWS / 64), 256, 0, stream>>>(mnb, pmwb, vtt);
    k_attn_mfma<<<dim3(SD / 128, NRES / 128, NH), 256, 0, stream>>>(wsb, vtt, otb2);
    k_gate_mfma<<<dim3(HC / 64, NROWS / 64), 256, 0, stream>>>(mnb, pgwb, otb2, gob);
    k_out_mfma<<<NROWS / 64, 256, 0, stream>>>(gob, powb, m, mout);

    // Transition (MFMA)
    k_ln64<<<NROWS / 4, 256, 0, stream>>>(mout, tnw, tnb_, tn_bf);
    k_fc12<<<dim3(FF / 64, NROWS / 64), 256, 0, stream>>>(tn_bf, f1b, f2b, hh);
    k_fc3<<<NROWS / 64, 256, 0, stream>>>(hh, f3b, mout);

    // OuterProductMean
    k_ln64<<<NROWS / 4, 256, 0, stream>>>(mout, onw, onb, onb_bf);
    k_ab_mfma<<<NROWS / 64, 256, 0, stream>>>(onb_bf, abwb, smask, abuf, bbuf);
    k_tr<<<dim3((NRES * DOP) / 64, NSEQ / 64, 2), 256, 0, stream>>>(abuf, abt, NSEQ, NRES * DOP);
    k_msum<<<dim3(NRES / 64, NRES / 64), 256, 0, stream>>>(smask, msum);
    for (int cb = 0; cb < NRES / ICHUNK; cb++) {
        int ib = cb * ICHUNK;
        const ushort_t* Achunk = abt + (size_t)(ib * DOP) * NSEQ;
        k_opm_mfma<<<dim3((NRES * DOP) / 128, (ICHUNK * DOP) / 128), 256, 0, stream>>>(Achunk, bbt, opmc);
        k_proj_mfma<<<dim3(DZ / 64, (ICHUNK * NRES) / 64), 256, 0, stream>>>(opmc, opWb, opB, msum, z, zout, ib);
    }
}

// Round 8
// 584.780 us; speedup vs baseline: 11.4739x; 1.0301x over previous
//
#include <hip/hip_runtime.h>
#include <math.h>

// ---------------- problem constants ----------------
constexpr int NRES = 384;          // N
constexpr int NSEQ = 256;          // S
constexpr int DM   = 64;           // MSA_S
constexpr int DZ   = 128;          // Z_D
constexpr int NH   = 8;            // H
constexpr int DH   = 32;           // C_H
constexpr int HC   = NH * DH;      // 256
constexpr int DOP  = 32;           // C_OPM
constexpr int FF   = 4 * DM;       // 256

constexpr int NPAIR = NRES * NRES;         // 147456
constexpr int NROWS = NSEQ * NRES;         // 98304
constexpr int ZTOT  = NPAIR * DZ;          // 18874368
constexpr int SD    = NSEQ * DH;           // 8192
constexpr int ICHUNK = 96;                 // i-rows per OPM chunk (4 chunks)

typedef unsigned short ushort_t;
typedef __attribute__((ext_vector_type(8))) short short8;
typedef __attribute__((ext_vector_type(4))) float f32x4;

__device__ __forceinline__ float wred_sum(float v) {
    #pragma unroll
    for (int off = 32; off; off >>= 1) v += __shfl_xor(v, off, 64);
    return v;
}
__device__ __forceinline__ float sigm(float x) { return 1.0f / (1.0f + expf(-x)); }
__device__ __forceinline__ ushort_t cvt_bf(float f) {
    unsigned u = __float_as_uint(f);
    unsigned r = (u + 0x7FFFu + ((u >> 16) & 1u)) >> 16;
    return (ushort_t)r;
}
__device__ __forceinline__ float cvt_f(ushort_t h) {
    return __uint_as_float(((unsigned)h) << 16);
}
__device__ __forceinline__ f32x4 mfma16(short8 a, short8 b, f32x4 c) {
    return __builtin_amdgcn_mfma_f32_16x16x32_bf16(a, b, c, 0, 0, 0);
}

// ---------------- K0: weights -> bf16 ----------------
__global__ __launch_bounds__(256) void k_prep(const float* __restrict__ f1,
                                              const float* __restrict__ f2,
                                              const float* __restrict__ f3,
                                              const float* __restrict__ opW,
                                              const float* __restrict__ pmw,
                                              const float* __restrict__ pgw,
                                              const float* __restrict__ pow_,
                                              const float* __restrict__ paw,
                                              const float* __restrict__ pbw,
                                              const float* __restrict__ pzw,
                                              ushort_t* __restrict__ f1b,
                                              ushort_t* __restrict__ f2b,
                                              ushort_t* __restrict__ f3b,
                                              ushort_t* __restrict__ opWb,
                                              ushort_t* __restrict__ pmwb,
                                              ushort_t* __restrict__ pgwb,
                                              ushort_t* __restrict__ powb,
                                              ushort_t* __restrict__ abwb,
                                              ushort_t* __restrict__ pzwb) {
    int i = blockIdx.x * 256 + threadIdx.x;      // 131072 threads
    opWb[i] = cvt_bf(opW[i]);
    if (i < FF * DM) {
        f1b[i] = cvt_bf(f1[i]);
        f2b[i] = cvt_bf(f2[i]);
        f3b[i] = cvt_bf(f3[i]);
    }
    if (i < HC * DM) {
        pmwb[i] = cvt_bf(pmw[i]);
        pgwb[i] = cvt_bf(pgw[i]);
        powb[i] = cvt_bf(pow_[i]);
    }
    if (i < 2 * DOP * DM) {                      // combined [64][64]: rows 0..31 paw, 32..63 pbw
        abwb[i] = cvt_bf(i < DOP * DM ? paw[i] : pbw[i - DOP * DM]);
    }
    if (i < 16 * DZ) {                           // [16][128]: rows 0..7 pzw, rows 8..15 zero
        pzwb[i] = (i < NH * DZ) ? cvt_bf(pzw[i]) : (ushort_t)0;
    }
}

// ---------------- K1: fused LN(z) + bias proj + mask + softmax -> wsb (one block per i) ----------------
__global__ __launch_bounds__(256) void k_biassm(const float* __restrict__ z,
                                                const float* __restrict__ nzw,
                                                const float* __restrict__ nzb,
                                                const ushort_t* __restrict__ pzwb,
                                                const float* __restrict__ tmask,
                                                ushort_t* __restrict__ wsb) {
    int i = blockIdx.x;                         // 0..383
    __shared__ ushort_t Azl[128][136];
    __shared__ ushort_t Bl[16][136];
    __shared__ float ob[8][388];
    __shared__ float wln[128], bln[128];
    int t = threadIdx.x;
    if (t < 128) { wln[t] = nzw[t]; bln[t] = nzb[t]; }
    int wave = t >> 6, lane = t & 63;
    int lk = (lane >> 4) * 8, lr = lane & 15;
    int wr = wave * 32;
    // stage B once
    for (int idx = t * 8; idx < 16 * DZ; idx += 256 * 8) {
        int row = idx >> 7, col = idx & 127;
        *(short8*)&Bl[row][col] = *(const short8*)&pzwb[idx];
    }
    __syncthreads();
    for (int c = 0; c < 3; c++) {
        // stage A chunk with fused LN: rows j = c*128 .. +127; 2 threads per row
        {
            int jl = t >> 1, cb = (t & 1) * 64;
            const float* src = &z[((size_t)i * NRES + c * 128 + jl) * DZ + cb];
            float4 v[16];
            float s1 = 0.0f, s2 = 0.0f;
            #pragma unroll
            for (int q = 0; q < 16; q++) {
                v[q] = *(const float4*)&src[q * 4];
                s1 += v[q].x + v[q].y + v[q].z + v[q].w;
                s2 += v[q].x * v[q].x + v[q].y * v[q].y + v[q].z * v[q].z + v[q].w * v[q].w;
            }
            s1 += __shfl_xor(s1, 1, 64);
            s2 += __shfl_xor(s2, 1, 64);
            float mu = s1 * (1.0f / 128.0f);
            float var = s2 * (1.0f / 128.0f) - mu * mu;
            float rs = rsqrtf(var + 1e-5f);
            #pragma unroll
            for (int q = 0; q < 8; q++) {
                float4 xa = v[2 * q], xb = v[2 * q + 1];
                int base = cb + q * 8;
                short8 o;
                o[0] = (short)cvt_bf((xa.x - mu) * rs * wln[base + 0] + bln[base + 0]);
                o[1] = (short)cvt_bf((xa.y - mu) * rs * wln[base + 1] + bln[base + 1]);
                o[2] = (short)cvt_bf((xa.z - mu) * rs * wln[base + 2] + bln[base + 2]);
                o[3] = (short)cvt_bf((xa.w - mu) * rs * wln[base + 3] + bln[base + 3]);
                o[4] = (short)cvt_bf((xb.x - mu) * rs * wln[base + 4] + bln[base + 4]);
                o[5] = (short)cvt_bf((xb.y - mu) * rs * wln[base + 5] + bln[base + 5]);
                o[6] = (short)cvt_bf((xb.z - mu) * rs * wln[base + 6] + bln[base + 6]);
                o[7] = (short)cvt_bf((xb.w - mu) * rs * wln[base + 7] + bln[base + 7]);
                *(short8*)&Azl[jl][base] = o;
            }
        }
        __syncthreads();
        f32x4 acc[2] = {};
        #pragma unroll
        for (int ks = 0; ks < 4; ks++) {
            short8 b = *(const short8*)&Bl[lr][ks * 32 + lk];
            short8 a0 = *(const short8*)&Azl[wr + lr][ks * 32 + lk];
            short8 a1 = *(const short8*)&Azl[wr + 16 + lr][ks * 32 + lk];
            acc[0] = mfma16(a0, b, acc[0]);
            acc[1] = mfma16(a1, b, acc[1]);
        }
        if (lr < NH) {
            #pragma unroll
            for (int ri = 0; ri < 2; ri++) {
                int jb = c * 128 + wr + 16 * ri + (lane >> 4) * 4;
                #pragma unroll
                for (int r = 0; r < 4; r++)
                    ob[lr][jb + r] = acc[ri][r];
            }
        }
        __syncthreads();
    }
    // softmax over j per head (half-wave = one head)
    int h = wave * 2 + (lane >> 5);
    int l32 = lane & 31;
    int jb = l32 * 12;
    const float* tm = &tmask[(size_t)i * NRES];
    float vals[12];
    float mx = -1e30f;
    #pragma unroll
    for (int q = 0; q < 12; q++) {
        float v = ob[h][jb + q] + (1.0f - tm[jb + q]) * (-1e9f);
        vals[q] = v;
        mx = fmaxf(mx, v);
    }
    #pragma unroll
    for (int off = 16; off; off >>= 1) mx = fmaxf(mx, __shfl_xor(mx, off, 64));
    float sum = 0.0f;
    #pragma unroll
    for (int q = 0; q < 12; q++) { vals[q] = expf(vals[q] - mx); sum += vals[q]; }
    #pragma unroll
    for (int off = 16; off; off >>= 1) sum += __shfl_xor(sum, off, 64);
    float inv = 1.0f / sum;
    ushort_t* o = &wsb[(size_t)h * NPAIR + (size_t)i * NRES + jb];
    #pragma unroll
    for (int q = 0; q < 12; q++) o[q] = cvt_bf(vals[q] * inv);
}

// ---------------- K3: LN rows (64-wide) fp32 -> bf16 ----------------
__global__ __launch_bounds__(256) void k_ln64(const float* __restrict__ src,
                                              const float* __restrict__ lw,
                                              const float* __restrict__ lb,
                                              ushort_t* __restrict__ dst) {
    int wave = threadIdx.x >> 6, lane = threadIdx.x & 63;
    int r = blockIdx.x * 4 + wave;
    float x = src[(size_t)r * DM + lane];
    float mu = wred_sum(x) * (1.0f / 64.0f);
    float d = x - mu;
    float var = wred_sum(d * d) * (1.0f / 64.0f);
    dst[(size_t)r * DM + lane] = cvt_bf(d * rsqrtf(var + 1e-5f) * lw[lane] + lb[lane]);
}

// ---------------- K3b: v projection GEMM -> vtt[h][s*32+d][n] directly ----------------
__global__ __launch_bounds__(256) void k_vproj_mfma(const ushort_t* __restrict__ A,
                                                    const ushort_t* __restrict__ Bt,
                                                    ushort_t* __restrict__ vtt) {
    int m0 = blockIdx.y * 64, n0c = blockIdx.x * 64;
    __shared__ ushort_t Al[64][40];
    __shared__ ushort_t Bl[64][40];
    __shared__ ushort_t ot[64][72];
    int t = threadIdx.x;
    int srow = t >> 2, sko = (t & 3) * 8;
    int wave = t >> 6, lane = t & 63;
    int wr = (wave >> 1) * 32, wc = (wave & 1) * 32;
    int lk = (lane >> 4) * 8, lr = lane & 15;
    f32x4 acc[2][2] = {};
    for (int k0 = 0; k0 < DM; k0 += 32) {
        *(short8*)&Al[srow][sko] = *(const short8*)&A[(size_t)(m0 + srow) * DM + k0 + sko];
        *(short8*)&Bl[srow][sko] = *(const short8*)&Bt[(size_t)(n0c + srow) * DM + k0 + sko];
        __syncthreads();
        short8 a0 = *(const short8*)&Al[wr + lr][lk];
        short8 a1 = *(const short8*)&Al[wr + 16 + lr][lk];
        short8 b0 = *(const short8*)&Bl[wc + lr][lk];
        short8 b1 = *(const short8*)&Bl[wc + 16 + lr][lk];
        acc[0][0] = mfma16(a0, b0, acc[0][0]);
        acc[0][1] = mfma16(a0, b1, acc[0][1]);
        acc[1][0] = mfma16(a1, b0, acc[1][0]);
        acc[1][1] = mfma16(a1, b1, acc[1][1]);
        __syncthreads();
    }
    // transpose in LDS: ot[col][row]
    #pragma unroll
    for (int ri = 0; ri < 2; ri++)
        #pragma unroll
        for (int ci = 0; ci < 2; ci++) {
            int rowb = wr + 16 * ri + (lane >> 4) * 4;
            int colb = wc + 16 * ci + lr;
            #pragma unroll
            for (int r = 0; r < 4; r++)
                ot[colb][rowb + r] = cvt_bf(acc[ri][ci][r]);
        }
    __syncthreads();
    int s = m0 / NRES, n0 = m0 % NRES;
    int h0 = n0c >> 5;                          // two heads h0, h0+1
    int orow = t >> 2, seg = (t & 3) * 16;
    short8 v0 = *(const short8*)&ot[orow][seg];
    short8 v1 = *(const short8*)&ot[orow][seg + 8];
    int hh = orow >> 5, dd = orow & 31;
    ushort_t* dst = &vtt[(((size_t)(h0 + hh) * SD) + s * DH + dd) * NRES + n0 + seg];
    *(short8*)&dst[0] = v0;
    *(short8*)&dst[8] = v1;
}

// ---------------- generic 64x64 bf16 transpose ----------------
__global__ __launch_bounds__(256) void k_tr(const ushort_t* __restrict__ src,
                                            ushort_t* __restrict__ dst,
                                            int R, int C) {
    size_t bs = (size_t)R * C;
    const ushort_t* s = src + blockIdx.z * bs;
    ushort_t* d = dst + blockIdx.z * bs;
    int r0 = blockIdx.y * 64, c0 = blockIdx.x * 64;
    __shared__ ushort_t tile[64][72];
    int t = threadIdx.x;
    int tr = t >> 2, tc = (t & 3) * 16;
    *(short8*)&tile[tr][tc]     = *(const short8*)&s[(size_t)(r0 + tr) * C + c0 + tc];
    *(short8*)&tile[tr][tc + 8] = *(const short8*)&s[(size_t)(r0 + tr) * C + c0 + tc + 8];
    __syncthreads();
    short8 o0, o1;
    #pragma unroll
    for (int i = 0; i < 8; i++) {
        o0[i] = (short)tile[tc + i][tr];
        o1[i] = (short)tile[tc + 8 + i][tr];
    }
    *(short8*)&d[(size_t)(c0 + tr) * R + r0 + tc]     = o0;
    *(short8*)&d[(size_t)(c0 + tr) * R + r0 + tc + 8] = o1;
}

// ---------------- K4: attention GEMM per head (128x128 tile) -> otb2[(s*N+i)][h*32+d] ----------------
__global__ __launch_bounds__(256) void k_attn_mfma(const ushort_t* __restrict__ wsb,
                                                   const ushort_t* __restrict__ vtt,
                                                   ushort_t* __restrict__ otb2) {
    int h = blockIdx.z;
    const ushort_t* A  = wsb + (size_t)h * NPAIR;        // [384][384]
    const ushort_t* Bt = vtt + (size_t)h * SD * NRES;    // [8192][384]
    int m0 = blockIdx.y * 128, n0 = blockIdx.x * 128;
    __shared__ ushort_t Al[128][40];
    __shared__ ushort_t Bl[128][40];
    int t = threadIdx.x;
    int srow = t >> 1, sko = (t & 1) * 16;
    int wave = t >> 6, lane = t & 63;
    int wr = (wave >> 1) * 64, wc = (wave & 1) * 64;
    int lk = (lane >> 4) * 8, lr = lane & 15;
    f32x4 acc[4][4] = {};
    for (int k0 = 0; k0 < NRES; k0 += 32) {
        *(short8*)&Al[srow][sko]     = *(const short8*)&A[(size_t)(m0 + srow) * NRES + k0 + sko];
        *(short8*)&Al[srow][sko + 8] = *(const short8*)&A[(size_t)(m0 + srow) * NRES + k0 + sko + 8];
        *(short8*)&Bl[srow][sko]     = *(const short8*)&Bt[(size_t)(n0 + srow) * NRES + k0 + sko];
        *(short8*)&Bl[srow][sko + 8] = *(const short8*)&Bt[(size_t)(n0 + srow) * NRES + k0 + sko + 8];
        __syncthreads();
        short8 af[4], bf2[4];
        #pragma unroll
        for (int i = 0; i < 4; i++) {
            af[i]  = *(const short8*)&Al[wr + 16 * i + lr][lk];
            bf2[i] = *(const short8*)&Bl[wc + 16 * i + lr][lk];
        }
        #pragma unroll
        for (int ri = 0; ri < 4; ri++)
            #pragma unroll
            for (int ci = 0; ci < 4; ci++)
                acc[ri][ci] = mfma16(af[ri], bf2[ci], acc[ri][ci]);
        __syncthreads();
    }
    #pragma unroll
    for (int ri = 0; ri < 4; ri++)
        #pragma unroll
        for (int ci = 0; ci < 4; ci++) {
            int row0 = m0 + wr + 16 * ri + (lane >> 4) * 4;   // i
            int col  = n0 + wc + 16 * ci + lr;                // s*32+d
            int s = col >> 5, dd = col & 31;
            #pragma unroll
            for (int r = 0; r < 4; r++)
                otb2[((size_t)s * NRES + row0 + r) * HC + h * DH + dd] = cvt_bf(acc[ri][ci][r]);
        }
}

// ---------------- K5a: gate GEMM + sigmoid*o -> gob ----------------
__global__ __launch_bounds__(256) void k_gate_mfma(const ushort_t* __restrict__ A,
                                                   const ushort_t* __restrict__ Bt,
                                                   const ushort_t* __restrict__ otb2,
                                                   ushort_t* __restrict__ gob) {
    int m0 = blockIdx.y * 64, n0 = blockIdx.x * 64;
    __shared__ ushort_t Al[64][40];
    __shared__ ushort_t Bl[64][40];
    int t = threadIdx.x;
    int srow = t >> 2, sko = (t & 3) * 8;
    int wave = t >> 6, lane = t & 63;
    int wr = (wave >> 1) * 32, wc = (wave & 1) * 32;
    int lk = (lane >> 4) * 8, lr = lane & 15;
    f32x4 acc[2][2] = {};
    for (int k0 = 0; k0 < DM; k0 += 32) {
        *(short8*)&Al[srow][sko] = *(const short8*)&A[(size_t)(m0 + srow) * DM + k0 + sko];
        *(short8*)&Bl[srow][sko] = *(const short8*)&Bt[(size_t)(n0 + srow) * DM + k0 + sko];
        __syncthreads();
        short8 a0 = *(const short8*)&Al[wr + lr][lk];
        short8 a1 = *(const short8*)&Al[wr + 16 + lr][lk];
        short8 b0 = *(const short8*)&Bl[wc + lr][lk];
        short8 b1 = *(const short8*)&Bl[wc + 16 + lr][lk];
        acc[0][0] = mfma16(a0, b0, acc[0][0]);
        acc[0][1] = mfma16(a0, b1, acc[0][1]);
        acc[1][0] = mfma16(a1, b0, acc[1][0]);
        acc[1][1] = mfma16(a1, b1, acc[1][1]);
        __syncthreads();
    }
    #pragma unroll
    for (int ri = 0; ri < 2; ri++)
        #pragma unroll
        for (int ci = 0; ci < 2; ci++) {
            int row0 = m0 + wr + 16 * ri + (lane >> 4) * 4;
            int col  = n0 + wc + 16 * ci + lr;
            #pragma unroll
            for (int r = 0; r < 4; r++) {
                size_t idx = (size_t)(row0 + r) * HC + col;
                float ov = cvt_f(otb2[idx]);
                gob[idx] = cvt_bf(sigm(acc[ri][ci][r]) * ov);
            }
        }
}

// ---------------- K5b: output GEMM + residual -> mout ----------------
__global__ __launch_bounds__(256) void k_out_mfma(const ushort_t* __restrict__ A,
                                                  const ushort_t* __restrict__ Bt,
                                                  const float* __restrict__ m,
                                                  float* __restrict__ mout) {
    int m0 = blockIdx.x * 64;
    __shared__ ushort_t Al[64][40];
    __shared__ ushort_t Bl[64][40];
    int t = threadIdx.x;
    int srow = t >> 2, sko = (t & 3) * 8;
    int wave = t >> 6, lane = t & 63;
    int wr = (wave >> 1) * 32, wc = (wave & 1) * 32;
    int lk = (lane >> 4) * 8, lr = lane & 15;
    f32x4 acc[2][2] = {};
    for (int k0 = 0; k0 < HC; k0 += 32) {
        *(short8*)&Al[srow][sko] = *(const short8*)&A[(size_t)(m0 + srow) * HC + k0 + sko];
        *(short8*)&Bl[srow][sko] = *(const short8*)&Bt[(size_t)srow * HC + k0 + sko];
        __syncthreads();
        short8 a0 = *(const short8*)&Al[wr + lr][lk];
        short8 a1 = *(const short8*)&Al[wr + 16 + lr][lk];
        short8 b0 = *(const short8*)&Bl[wc + lr][lk];
        short8 b1 = *(const short8*)&Bl[wc + 16 + lr][lk];
        acc[0][0] = mfma16(a0, b0, acc[0][0]);
        acc[0][1] = mfma16(a0, b1, acc[0][1]);
        acc[1][0] = mfma16(a1, b0, acc[1][0]);
        acc[1][1] = mfma16(a1, b1, acc[1][1]);
        __syncthreads();
    }
    #pragma unroll
    for (int ri = 0; ri < 2; ri++)
        #pragma unroll
        for (int ci = 0; ci < 2; ci++) {
            int row0 = m0 + wr + 16 * ri + (lane >> 4) * 4;
            int col  = wc + 16 * ci + lr;
            #pragma unroll
            for (int r = 0; r < 4; r++) {
                size_t idx = (size_t)(row0 + r) * DM + col;
                mout[idx] = m[idx] + acc[ri][ci][r];
            }
        }
}

// ---------------- K6b: fc1/fc2 GEMM + SwiGLU -> hh bf16 ----------------
__global__ __launch_bounds__(256) void k_fc12(const ushort_t* __restrict__ A,
                                              const ushort_t* __restrict__ B1t,
                                              const ushort_t* __restrict__ B2t,
                                              ushort_t* __restrict__ hh) {
    int m0 = blockIdx.y * 64, n0 = blockIdx.x * 64;
    __shared__ ushort_t Al[64][40];
    __shared__ ushort_t B1l[64][40];
    __shared__ ushort_t B2l[64][40];
    int t = threadIdx.x;
    int srow = t >> 2, sko = (t & 3) * 8;
    int wave = t >> 6, lane = t & 63;
    int wr = (wave >> 1) * 32, wc = (wave & 1) * 32;
    int lk = (lane >> 4) * 8, lr = lane & 15;
    f32x4 acc1[2][2] = {}, acc2[2][2] = {};
    for (int k0 = 0; k0 < DM; k0 += 32) {
        *(short8*)&Al[srow][sko]  = *(const short8*)&A[(size_t)(m0 + srow) * DM + k0 + sko];
        *(short8*)&B1l[srow][sko] = *(const short8*)&B1t[(size_t)(n0 + srow) * DM + k0 + sko];
        *(short8*)&B2l[srow][sko] = *(const short8*)&B2t[(size_t)(n0 + srow) * DM + k0 + sko];
        __syncthreads();
        short8 a0 = *(const short8*)&Al[wr + lr][lk];
        short8 a1 = *(const short8*)&Al[wr + 16 + lr][lk];
        short8 p0 = *(const short8*)&B1l[wc + lr][lk];
        short8 p1 = *(const short8*)&B1l[wc + 16 + lr][lk];
        short8 q0 = *(const short8*)&B2l[wc + lr][lk];
        short8 q1 = *(const short8*)&B2l[wc + 16 + lr][lk];
        acc1[0][0] = mfma16(a0, p0, acc1[0][0]);
        acc1[0][1] = mfma16(a0, p1, acc1[0][1]);
        acc1[1][0] = mfma16(a1, p0, acc1[1][0]);
        acc1[1][1] = mfma16(a1, p1, acc1[1][1]);
        acc2[0][0] = mfma16(a0, q0, acc2[0][0]);
        acc2[0][1] = mfma16(a0, q1, acc2[0][1]);
        acc2[1][0] = mfma16(a1, q0, acc2[1][0]);
        acc2[1][1] = mfma16(a1, q1, acc2[1][1]);
        __syncthreads();
    }
    #pragma unroll
    for (int ri = 0; ri < 2; ri++)
        #pragma unroll
        for (int ci = 0; ci < 2; ci++) {
            int row0 = m0 + wr + 16 * ri + (lane >> 4) * 4;
            int col  = n0 + wc + 16 * ci + lr;
            #pragma unroll
            for (int r = 0; r < 4; r++) {
                float a1v = acc1[ri][ci][r], a2v = acc2[ri][ci][r];
                hh[(size_t)(row0 + r) * FF + col] = cvt_bf(a1v * sigm(a1v) * a2v);
            }
        }
}

// ---------------- K6c: fc3 GEMM + residual into mout ----------------
__global__ __launch_bounds__(256) void k_fc3(const ushort_t* __restrict__ A,
                                             const ushort_t* __restrict__ Bt,
                                             float* __restrict__ mio) {
    int m0 = blockIdx.x * 64;
    __shared__ ushort_t Al[64][40];
    __shared__ ushort_t Bl[64][40];
    int t = threadIdx.x;
    int srow = t >> 2, sko = (t & 3) * 8;
    int wave = t >> 6, lane = t & 63;
    int wr = (wave >> 1) * 32, wc = (wave & 1) * 32;
    int lk = (lane >> 4) * 8, lr = lane & 15;
    f32x4 acc[2][2] = {};
    for (int k0 = 0; k0 < FF; k0 += 32) {
        *(short8*)&Al[srow][sko] = *(const short8*)&A[(size_t)(m0 + srow) * FF + k0 + sko];
        *(short8*)&Bl[srow][sko] = *(const short8*)&Bt[(size_t)srow * FF + k0 + sko];
        __syncthreads();
        short8 a0 = *(const short8*)&Al[wr + lr][lk];
        short8 a1 = *(const short8*)&Al[wr + 16 + lr][lk];
        short8 b0 = *(const short8*)&Bl[wc + lr][lk];
        short8 b1 = *(const short8*)&Bl[wc + 16 + lr][lk];
        acc[0][0] = mfma16(a0, b0, acc[0][0]);
        acc[0][1] = mfma16(a0, b1, acc[0][1]);
        acc[1][0] = mfma16(a1, b0, acc[1][0]);
        acc[1][1] = mfma16(a1, b1, acc[1][1]);
        __syncthreads();
    }
    #pragma unroll
    for (int ri = 0; ri < 2; ri++)
        #pragma unroll
        for (int ci = 0; ci < 2; ci++) {
            int row0 = m0 + wr + 16 * ri + (lane >> 4) * 4;
            int col  = wc + 16 * ci + lr;
            #pragma unroll
            for (int r = 0; r < 4; r++)
                mio[(size_t)(row0 + r) * DM + col] += acc[ri][ci][r];
        }
}

// ---------------- K7: a/b projection GEMM + mask -> abuf/bbuf [s][n*32+c] ----------------
__global__ __launch_bounds__(256) void k_ab_mfma(const ushort_t* __restrict__ A,
                                                 const ushort_t* __restrict__ Bt,
                                                 const float* __restrict__ smask,
                                                 ushort_t* __restrict__ abuf,
                                                 ushort_t* __restrict__ bbuf) {
    int m0 = blockIdx.x * 64;
    __shared__ ushort_t Al[64][40];
    __shared__ ushort_t Bl[64][40];
    int t = threadIdx.x;
    int srow = t >> 2, sko = (t & 3) * 8;
    int wave = t >> 6, lane = t & 63;
    int wr = (wave >> 1) * 32, wc = (wave & 1) * 32;
    int lk = (lane >> 4) * 8, lr = lane & 15;
    f32x4 acc[2][2] = {};
    for (int k0 = 0; k0 < DM; k0 += 32) {
        *(short8*)&Al[srow][sko] = *(const short8*)&A[(size_t)(m0 + srow) * DM + k0 + sko];
        *(short8*)&Bl[srow][sko] = *(const short8*)&Bt[(size_t)srow * DM + k0 + sko];
        __syncthreads();
        short8 a0 = *(const short8*)&Al[wr + lr][lk];
        short8 a1 = *(const short8*)&Al[wr + 16 + lr][lk];
        short8 b0 = *(const short8*)&Bl[wc + lr][lk];
        short8 b1 = *(const short8*)&Bl[wc + 16 + lr][lk];
        acc[0][0] = mfma16(a0, b0, acc[0][0]);
        acc[0][1] = mfma16(a0, b1, acc[0][1]);
        acc[1][0] = mfma16(a1, b0, acc[1][0]);
        acc[1][1] = mfma16(a1, b1, acc[1][1]);
        __syncthreads();
    }
    #pragma unroll
    for (int ri = 0; ri < 2; ri++)
        #pragma unroll
        for (int ci = 0; ci < 2; ci++) {
            int row0 = m0 + wr + 16 * ri + (lane >> 4) * 4;
            int col  = wc + 16 * ci + lr;               // 0..63
            #pragma unroll
            for (int r = 0; r < 4; r++) {
                int rr = row0 + r;                      // s*NRES+n
                int s = rr / NRES, n = rr % NRES;
                float v = acc[ri][ci][r] * smask[rr];
                if (col < DOP)
                    abuf[(size_t)s * (NRES * DOP) + n * DOP + col] = cvt_bf(v);
                else
                    bbuf[(size_t)s * (NRES * DOP) + n * DOP + (col - DOP)] = cvt_bf(v);
            }
        }
}

// ---------------- K8: mask pair-count Gram tile ----------------
__global__ __launch_bounds__(256) void k_msum(const float* __restrict__ smask,
                                              float* __restrict__ msum) {
    int i0 = blockIdx.y * 64, j0 = blockIdx.x * 64;
    __shared__ float As[16][64];
    __shared__ float Bs[16][64];
    int t = threadIdx.x;
    int ty = t >> 4, tx = t & 15;
    float acc[4][4] = {};
    for (int k0 = 0; k0 < NSEQ; k0 += 16) {
        int kk = t >> 4, x4 = (t & 15) * 4;
        *(float4*)&As[kk][x4] = *(const float4*)&smask[(size_t)(k0 + kk) * NRES + i0 + x4];
        *(float4*)&Bs[kk][x4] = *(const float4*)&smask[(size_t)(k0 + kk) * NRES + j0 + x4];
        __syncthreads();
        #pragma unroll
        for (int k = 0; k < 16; k++) {
            float4 a4 = *(const float4*)&As[k][ty * 4];
            float4 b4 = *(const float4*)&Bs[k][tx * 4];
            float ar[4] = {a4.x, a4.y, a4.z, a4.w};
            float br[4] = {b4.x, b4.y, b4.z, b4.w};
            #pragma unroll
            for (int i2 = 0; i2 < 4; i2++)
                #pragma unroll
                for (int j2 = 0; j2 < 4; j2++)
                    acc[i2][j2] += ar[i2] * br[j2];
        }
        __syncthreads();
    }
    #pragma unroll
    for (int r = 0; r < 4; r++) {
        float4 o4 = make_float4(fmaxf(acc[r][0], 1.0f), fmaxf(acc[r][1], 1.0f),
                                fmaxf(acc[r][2], 1.0f), fmaxf(acc[r][3], 1.0f));
        *(float4*)&msum[(size_t)(i0 + ty * 4 + r) * NRES + j0 + tx * 4] = o4;
    }
}

// ---------------- K9: OPM outer GEMM (bf16 MFMA, 128x128 tile) ----------------
__global__ __launch_bounds__(256) void k_opm_mfma(const ushort_t* __restrict__ At,
                                                  const ushort_t* __restrict__ Bt,
                                                  ushort_t* __restrict__ opmc) {
    int m0 = blockIdx.y * 128;                  // over ICHUNK*32 (il,c)
    int n0 = blockIdx.x * 128;                  // over 12288 (j,d)
    __shared__ ushort_t Al[128][40];
    __shared__ ushort_t Bl[128][40];
    int t = threadIdx.x;
    int srow = t >> 1, sko = (t & 1) * 16;
    int wave = t >> 6, lane = t & 63;
    int wr = (wave >> 1) * 64, wc = (wave & 1) * 64;
    int lk = (lane >> 4) * 8, lr = lane & 15;
    f32x4 acc[4][4] = {};
    for (int k0 = 0; k0 < NSEQ; k0 += 32) {
        *(short8*)&Al[srow][sko]     = *(const short8*)&At[(size_t)(m0 + srow) * NSEQ + k0 + sko];
        *(short8*)&Al[srow][sko + 8] = *(const short8*)&At[(size_t)(m0 + srow) * NSEQ + k0 + sko + 8];
        *(short8*)&Bl[srow][sko]     = *(const short8*)&Bt[(size_t)(n0 + srow) * NSEQ + k0 + sko];
        *(short8*)&Bl[srow][sko + 8] = *(const short8*)&Bt[(size_t)(n0 + srow) * NSEQ + k0 + sko + 8];
        __syncthreads();
        short8 af[4], bf2[4];
        #pragma unroll
        for (int i = 0; i < 4; i++) {
            af[i]  = *(const short8*)&Al[wr + 16 * i + lr][lk];
            bf2[i] = *(const short8*)&Bl[wc + 16 * i + lr][lk];
        }
        #pragma unroll
        for (int ri = 0; ri < 4; ri++)
            #pragma unroll
            for (int ci = 0; ci < 4; ci++)
                acc[ri][ci] = mfma16(af[ri], bf2[ci], acc[ri][ci]);
        __syncthreads();
    }
    #pragma unroll
    for (int ri = 0; ri < 4; ri++)
        #pragma unroll
        for (int ci = 0; ci < 4; ci++) {
            int mb = m0 + wr + 16 * ri + (lane >> 4) * 4;
            int n  = n0 + wc + 16 * ci + lr;
            int j = n >> 5, dd = n & 31;
            #pragma unroll
            for (int r = 0; r < 4; r++) {
                int mm = mb + r;
                int il = mm >> 5, c = mm & 31;
                opmc[((size_t)(il * NRES + j) << 10) + (c << 5) + dd] = cvt_bf(acc[ri][ci][r]);
            }
        }
}

// ---------------- K10: OPM projection + residual (128x64 tile) ----------------
__global__ __launch_bounds__(256) void k_proj_mfma(const ushort_t* __restrict__ A,
                                                   const ushort_t* __restrict__ Bt,
                                                   const float* __restrict__ opB,
                                                   const float* __restrict__ msum,
                                                   const float* __restrict__ zin,
                                                   float* __restrict__ zout,
                                                   int ib) {
    int m0 = blockIdx.y * 128, n0 = blockIdx.x * 64;
    __shared__ ushort_t Al[128][40];
    __shared__ ushort_t Bl[64][40];
    int t = threadIdx.x;
    int wave = t >> 6, lane = t & 63;
    int wr = (wave >> 1) * 64, wc = (wave & 1) * 32;
    int lk = (lane >> 4) * 8, lr = lane & 15;
    int srA = t >> 1, skA = (t & 1) * 16;
    int srB = t >> 2, skB = (t & 3) * 8;
    f32x4 acc[4][2] = {};
    for (int k0 = 0; k0 < 1024; k0 += 32) {
        *(short8*)&Al[srA][skA]     = *(const short8*)&A[(size_t)(m0 + srA) * 1024 + k0 + skA];
        *(short8*)&Al[srA][skA + 8] = *(const short8*)&A[(size_t)(m0 + srA) * 1024 + k0 + skA + 8];
        *(short8*)&Bl[srB][skB]     = *(const short8*)&Bt[(size_t)(n0 + srB) * 1024 + k0 + skB];
        __syncthreads();
        short8 af[4];
        #pragma unroll
        for (int i = 0; i < 4; i++)
            af[i] = *(const short8*)&Al[wr + 16 * i + lr][lk];
        short8 b0 = *(const short8*)&Bl[wc + lr][lk];
        short8 b1 = *(const short8*)&Bl[wc + 16 + lr][lk];
        #pragma unroll
        for (int ri = 0; ri < 4; ri++) {
            acc[ri][0] = mfma16(af[ri], b0, acc[ri][0]);
            acc[ri][1] = mfma16(af[ri], b1, acc[ri][1]);
        }
        __syncthreads();
    }
    #pragma unroll
    for (int ri = 0; ri < 4; ri++)
        #pragma unroll
        for (int ci = 0; ci < 2; ci++) {
            int row0 = m0 + wr + 16 * ri + (lane >> 4) * 4;
            int col  = n0 + wc + 16 * ci + lr;
            #pragma unroll
            for (int r = 0; r < 4; r++) {
                size_t G = (size_t)ib * NRES + row0 + r;
                float inv = 1.0f / msum[G];
                zout[G * DZ + col] = zin[G * DZ + col] + acc[ri][ci][r] * inv + opB[col];
            }
        }
}

// ---------------- launch ----------------
extern "C" void kernel_launch(void* const* d_in, const int* in_sizes, int n_in,
                              void* d_out, int out_size, void* d_ws, size_t ws_size,
                              hipStream_t stream) {
    const float* z     = (const float*)d_in[0];
    const float* m     = (const float*)d_in[1];
    const float* tmask = (const float*)d_in[2];
    const float* smask = (const float*)d_in[3];
    const float* nzw   = (const float*)d_in[4];
    const float* nzb   = (const float*)d_in[5];
    const float* pzw   = (const float*)d_in[6];
    const float* nmw   = (const float*)d_in[7];
    const float* nmb   = (const float*)d_in[8];
    const float* pmw   = (const float*)d_in[9];
    const float* pgw   = (const float*)d_in[10];
    const float* pow_  = (const float*)d_in[11];
    const float* tnw   = (const float*)d_in[12];
    const float* tnb_  = (const float*)d_in[13];
    const float* f1    = (const float*)d_in[14];
    const float* f2    = (const float*)d_in[15];
    const float* f3    = (const float*)d_in[16];
    const float* onw   = (const float*)d_in[17];
    const float* onb   = (const float*)d_in[18];
    const float* paw   = (const float*)d_in[19];
    const float* pbw   = (const float*)d_in[20];
    const float* opW   = (const float*)d_in[21];
    const float* opB   = (const float*)d_in[22];

    float* zout = (float*)d_out;
    float* mout = zout + ZTOT;

    char* W = (char*)d_ws;
    ushort_t* wsb  = (ushort_t*)(W + 4718592);          //  .. 7,077,888 (bf16 softmax wts)
    ushort_t* mnb  = (ushort_t*)(W + 7077888);          //  .. 19,660,800 (12.6MB)
    ushort_t* vtR  = (ushort_t*)(W + 19660800);         //  .. 69,992,448 (50.3MB, multi-use)
    ushort_t* vtt  = (ushort_t*)(W + 69992448);         //  .. 120,324,096 (50.3MB)
    ushort_t* otb2 = (ushort_t*)(W + 120324096);        //  .. 170,655,744 (50.3MB)
    float*    msum = (float*)(W + 170655744);           //  .. 171,245,568
    ushort_t* f1b  = (ushort_t*)(W + 171245568);
    ushort_t* f2b  = (ushort_t*)(W + 171278336);
    ushort_t* f3b  = (ushort_t*)(W + 171311104);
    ushort_t* opWb = (ushort_t*)(W + 171343872);        //  .. 171,606,016
    ushort_t* pmwb = (ushort_t*)(W + 171606016);
    ushort_t* pgwb = (ushort_t*)(W + 171638784);
    ushort_t* powb = (ushort_t*)(W + 171671552);        //  .. 171,704,320
    ushort_t* abwb = (ushort_t*)(W + 171704320);        //  .. 171,712,512 (8KB)
    ushort_t* pzwb = (ushort_t*)(W + 171712512);        //  .. 171,716,608 (4KB)
    // region aliases (dead-by-then):
    ushort_t* gob   = vtR;                  // written after biassm (z read direct now)
    ushort_t* tn_bf = vtt;                  // vtt dead after k_attn_mfma
    ushort_t* onb_bf = mnb;                 // mnb dead after k_gate_mfma
    ushort_t* abuf = (ushort_t*)(W + 69992448 + 12582912);   // vtt+12.6MB
    ushort_t* bbuf = (ushort_t*)(W + 69992448 + 18874368);   // vtt+18.9MB
    ushort_t* hh   = otb2;                  // otb2 dead after k_gate_mfma
    ushort_t* abt  = otb2;                  // hh dead after k_fc3
    ushort_t* bbt  = (ushort_t*)(W + 120324096 + 6291456);
    ushort_t* opmc = vtR;                   // spans vtR..vtt (dead at OPM time; needs 75.5MB < 100.6MB)

    k_prep<<<512, 256, 0, stream>>>(f1, f2, f3, opW, pmw, pgw, pow_, paw, pbw, pzw,
                                    f1b, f2b, f3b, opWb, pmwb, pgwb, powb, abwb, pzwb);

    // PairWeightedAveraging
    k_biassm<<<NRES, 256, 0, stream>>>(z, nzw, nzb, pzwb, tmask, wsb);
    k_ln64<<<NROWS / 4, 256, 0, stream>>>(m, nmw, nmb, mnb);
    k_vproj_mfma<<<dim3(HC / 64, NROWS / 64), 256, 0, stream>>>(mnb, pmwb, vtt);
    k_attn_mfma<<<dim3(SD / 128, NRES / 128, NH), 256, 0, stream>>>(wsb, vtt, otb2);
    k_gate_mfma<<<dim3(HC / 64, NROWS / 64), 256, 0, stream>>>(mnb, pgwb, otb2, gob);
    k_out_mfma<<<NROWS / 64, 256, 0, stream>>>(gob, powb, m, mout);

    // Transition (MFMA)
    k_ln64<<<NROWS / 4, 256, 0, stream>>>(mout, tnw, tnb_, tn_bf);
    k_fc12<<<dim3(FF / 64, NROWS / 64), 256, 0, stream>>>(tn_bf, f1b, f2b, hh);
    k_fc3<<<NROWS / 64, 256, 0, stream>>>(hh, f3b, mout);

    // OuterProductMean
    k_ln64<<<NROWS / 4, 256, 0, stream>>>(mout, onw, onb, onb_bf);
    k_ab_mfma<<<NROWS / 64, 256, 0, stream>>>(onb_bf, abwb, smask, abuf, bbuf);
    k_tr<<<dim3((NRES * DOP) / 64, NSEQ / 64, 2), 256, 0, stream>>>(abuf, abt, NSEQ, NRES * DOP);
    k_msum<<<dim3(NRES / 64, NRES / 64), 256, 0, stream>>>(smask, msum);
    for (int cb = 0; cb < NRES / ICHUNK; cb++) {
        int ib = cb * ICHUNK;
        const ushort_t* Achunk = abt + (size_t)(ib * DOP) * NSEQ;
        k_opm_mfma<<<dim3((NRES * DOP) / 128, (ICHUNK * DOP) / 128), 256, 0, stream>>>(Achunk, bbt, opmc);
        k_proj_mfma<<<dim3(DZ / 64, (ICHUNK * NRES) / 128), 256, 0, stream>>>(opmc, opWb, opB, msum, z, zout, ib);
    }
}

// Round 9
// 578.521 us; speedup vs baseline: 11.5980x; 1.0108x over previous
//
#include <hip/hip_runtime.h>
#include <math.h>

// ---------------- problem constants ----------------
constexpr int NRES = 384;          // N
constexpr int NSEQ = 256;          // S
constexpr int DM   = 64;           // MSA_S
constexpr int DZ   = 128;          // Z_D
constexpr int NH   = 8;            // H
constexpr int DH   = 32;           // C_H
constexpr int HC   = NH * DH;      // 256
constexpr int DOP  = 32;           // C_OPM
constexpr int FF   = 4 * DM;       // 256

constexpr int NPAIR = NRES * NRES;         // 147456
constexpr int NROWS = NSEQ * NRES;         // 98304
constexpr int ZTOT  = NPAIR * DZ;          // 18874368
constexpr int SD    = NSEQ * DH;           // 8192
constexpr int ICHUNK = 96;                 // i-rows per OPM chunk (4 chunks)

typedef unsigned short ushort_t;
typedef __attribute__((ext_vector_type(8))) short short8;
typedef __attribute__((ext_vector_type(4))) float f32x4;

__device__ __forceinline__ float wred_sum(float v) {
    #pragma unroll
    for (int off = 32; off; off >>= 1) v += __shfl_xor(v, off, 64);
    return v;
}
__device__ __forceinline__ float sigm(float x) { return 1.0f / (1.0f + expf(-x)); }
__device__ __forceinline__ ushort_t cvt_bf(float f) {
    unsigned u = __float_as_uint(f);
    unsigned r = (u + 0x7FFFu + ((u >> 16) & 1u)) >> 16;
    return (ushort_t)r;
}
__device__ __forceinline__ float cvt_f(ushort_t h) {
    return __uint_as_float(((unsigned)h) << 16);
}
__device__ __forceinline__ f32x4 mfma16(short8 a, short8 b, f32x4 c) {
    return __builtin_amdgcn_mfma_f32_16x16x32_bf16(a, b, c, 0, 0, 0);
}

// ---------------- K0: weights -> bf16 ----------------
__global__ __launch_bounds__(256) void k_prep(const float* __restrict__ f1,
                                              const float* __restrict__ f2,
                                              const float* __restrict__ f3,
                                              const float* __restrict__ opW,
                                              const float* __restrict__ pmw,
                                              const float* __restrict__ pgw,
                                              const float* __restrict__ pow_,
                                              const float* __restrict__ paw,
                                              const float* __restrict__ pbw,
                                              const float* __restrict__ pzw,
                                              ushort_t* __restrict__ f1b,
                                              ushort_t* __restrict__ f2b,
                                              ushort_t* __restrict__ f3b,
                                              ushort_t* __restrict__ opWb,
                                              ushort_t* __restrict__ pmwb,
                                              ushort_t* __restrict__ pgwb,
                                              ushort_t* __restrict__ powb,
                                              ushort_t* __restrict__ abwb,
                                              ushort_t* __restrict__ pzwb) {
    int i = blockIdx.x * 256 + threadIdx.x;      // 131072 threads
    opWb[i] = cvt_bf(opW[i]);
    if (i < FF * DM) {
        f1b[i] = cvt_bf(f1[i]);
        f2b[i] = cvt_bf(f2[i]);
        f3b[i] = cvt_bf(f3[i]);
    }
    if (i < HC * DM) {
        pmwb[i] = cvt_bf(pmw[i]);
        pgwb[i] = cvt_bf(pgw[i]);
        powb[i] = cvt_bf(pow_[i]);
    }
    if (i < 2 * DOP * DM) {                      // combined [64][64]: rows 0..31 paw, 32..63 pbw
        abwb[i] = cvt_bf(i < DOP * DM ? paw[i] : pbw[i - DOP * DM]);
    }
    if (i < 16 * DZ) {                           // [16][128]: rows 0..7 pzw, rows 8..15 zero
        pzwb[i] = (i < NH * DZ) ? cvt_bf(pzw[i]) : (ushort_t)0;
    }
}

// ---------------- K1: fused LN(z) + bias proj + mask + softmax -> wsb (one block per i) ----------------
__global__ __launch_bounds__(256) void k_biassm(const float* __restrict__ z,
                                                const float* __restrict__ nzw,
                                                const float* __restrict__ nzb,
                                                const ushort_t* __restrict__ pzwb,
                                                const float* __restrict__ tmask,
                                                ushort_t* __restrict__ wsb) {
    int i = blockIdx.x;                         // 0..383
    __shared__ ushort_t Azl[128][136];
    __shared__ ushort_t Bl[16][136];
    __shared__ float ob[8][388];
    __shared__ float wln[128], bln[128];
    int t = threadIdx.x;
    if (t < 128) { wln[t] = nzw[t]; bln[t] = nzb[t]; }
    int wave = t >> 6, lane = t & 63;
    int lk = (lane >> 4) * 8, lr = lane & 15;
    int wr = wave * 32;
    // stage B once
    for (int idx = t * 8; idx < 16 * DZ; idx += 256 * 8) {
        int row = idx >> 7, col = idx & 127;
        *(short8*)&Bl[row][col] = *(const short8*)&pzwb[idx];
    }
    __syncthreads();
    for (int c = 0; c < 3; c++) {
        // stage A chunk with fused LN: rows j = c*128 .. +127; 2 threads per row
        {
            int jl = t >> 1, cb = (t & 1) * 64;
            const float* src = &z[((size_t)i * NRES + c * 128 + jl) * DZ + cb];
            float4 v[16];
            float s1 = 0.0f, s2 = 0.0f;
            #pragma unroll
            for (int q = 0; q < 16; q++) {
                v[q] = *(const float4*)&src[q * 4];
                s1 += v[q].x + v[q].y + v[q].z + v[q].w;
                s2 += v[q].x * v[q].x + v[q].y * v[q].y + v[q].z * v[q].z + v[q].w * v[q].w;
            }
            s1 += __shfl_xor(s1, 1, 64);
            s2 += __shfl_xor(s2, 1, 64);
            float mu = s1 * (1.0f / 128.0f);
            float var = s2 * (1.0f / 128.0f) - mu * mu;
            float rs = rsqrtf(var + 1e-5f);
            #pragma unroll
            for (int q = 0; q < 8; q++) {
                float4 xa = v[2 * q], xb = v[2 * q + 1];
                int base = cb + q * 8;
                short8 o;
                o[0] = (short)cvt_bf((xa.x - mu) * rs * wln[base + 0] + bln[base + 0]);
                o[1] = (short)cvt_bf((xa.y - mu) * rs * wln[base + 1] + bln[base + 1]);
                o[2] = (short)cvt_bf((xa.z - mu) * rs * wln[base + 2] + bln[base + 2]);
                o[3] = (short)cvt_bf((xa.w - mu) * rs * wln[base + 3] + bln[base + 3]);
                o[4] = (short)cvt_bf((xb.x - mu) * rs * wln[base + 4] + bln[base + 4]);
                o[5] = (short)cvt_bf((xb.y - mu) * rs * wln[base + 5] + bln[base + 5]);
                o[6] = (short)cvt_bf((xb.z - mu) * rs * wln[base + 6] + bln[base + 6]);
                o[7] = (short)cvt_bf((xb.w - mu) * rs * wln[base + 7] + bln[base + 7]);
                *(short8*)&Azl[jl][base] = o;
            }
        }
        __syncthreads();
        f32x4 acc[2] = {};
        #pragma unroll
        for (int ks = 0; ks < 4; ks++) {
            short8 b = *(const short8*)&Bl[lr][ks * 32 + lk];
            short8 a0 = *(const short8*)&Azl[wr + lr][ks * 32 + lk];
            short8 a1 = *(const short8*)&Azl[wr + 16 + lr][ks * 32 + lk];
            acc[0] = mfma16(a0, b, acc[0]);
            acc[1] = mfma16(a1, b, acc[1]);
        }
        if (lr < NH) {
            #pragma unroll
            for (int ri = 0; ri < 2; ri++) {
                int jb = c * 128 + wr + 16 * ri + (lane >> 4) * 4;
                #pragma unroll
                for (int r = 0; r < 4; r++)
                    ob[lr][jb + r] = acc[ri][r];
            }
        }
        __syncthreads();
    }
    // softmax over j per head (half-wave = one head)
    int h = wave * 2 + (lane >> 5);
    int l32 = lane & 31;
    int jb = l32 * 12;
    const float* tm = &tmask[(size_t)i * NRES];
    float vals[12];
    float mx = -1e30f;
    #pragma unroll
    for (int q = 0; q < 12; q++) {
        float v = ob[h][jb + q] + (1.0f - tm[jb + q]) * (-1e9f);
        vals[q] = v;
        mx = fmaxf(mx, v);
    }
    #pragma unroll
    for (int off = 16; off; off >>= 1) mx = fmaxf(mx, __shfl_xor(mx, off, 64));
    float sum = 0.0f;
    #pragma unroll
    for (int q = 0; q < 12; q++) { vals[q] = expf(vals[q] - mx); sum += vals[q]; }
    #pragma unroll
    for (int off = 16; off; off >>= 1) sum += __shfl_xor(sum, off, 64);
    float inv = 1.0f / sum;
    ushort_t* o = &wsb[(size_t)h * NPAIR + (size_t)i * NRES + jb];
    #pragma unroll
    for (int q = 0; q < 12; q++) o[q] = cvt_bf(vals[q] * inv);
}

// ---------------- K3: LN rows (64-wide) fp32 -> bf16 ----------------
__global__ __launch_bounds__(256) void k_ln64(const float* __restrict__ src,
                                              const float* __restrict__ lw,
                                              const float* __restrict__ lb,
                                              ushort_t* __restrict__ dst) {
    int wave = threadIdx.x >> 6, lane = threadIdx.x & 63;
    int r = blockIdx.x * 4 + wave;
    float x = src[(size_t)r * DM + lane];
    float mu = wred_sum(x) * (1.0f / 64.0f);
    float d = x - mu;
    float var = wred_sum(d * d) * (1.0f / 64.0f);
    dst[(size_t)r * DM + lane] = cvt_bf(d * rsqrtf(var + 1e-5f) * lw[lane] + lb[lane]);
}

// ---------------- K3b: v projection GEMM -> vtt[h][s*32+d][n] directly ----------------
__global__ __launch_bounds__(256) void k_vproj_mfma(const ushort_t* __restrict__ A,
                                                    const ushort_t* __restrict__ Bt,
                                                    ushort_t* __restrict__ vtt) {
    int m0 = blockIdx.y * 64, n0c = blockIdx.x * 64;
    __shared__ ushort_t Al[64][40];
    __shared__ ushort_t Bl[64][40];
    __shared__ ushort_t ot[64][72];
    int t = threadIdx.x;
    int srow = t >> 2, sko = (t & 3) * 8;
    int wave = t >> 6, lane = t & 63;
    int wr = (wave >> 1) * 32, wc = (wave & 1) * 32;
    int lk = (lane >> 4) * 8, lr = lane & 15;
    f32x4 acc[2][2] = {};
    for (int k0 = 0; k0 < DM; k0 += 32) {
        *(short8*)&Al[srow][sko] = *(const short8*)&A[(size_t)(m0 + srow) * DM + k0 + sko];
        *(short8*)&Bl[srow][sko] = *(const short8*)&Bt[(size_t)(n0c + srow) * DM + k0 + sko];
        __syncthreads();
        short8 a0 = *(const short8*)&Al[wr + lr][lk];
        short8 a1 = *(const short8*)&Al[wr + 16 + lr][lk];
        short8 b0 = *(const short8*)&Bl[wc + lr][lk];
        short8 b1 = *(const short8*)&Bl[wc + 16 + lr][lk];
        acc[0][0] = mfma16(a0, b0, acc[0][0]);
        acc[0][1] = mfma16(a0, b1, acc[0][1]);
        acc[1][0] = mfma16(a1, b0, acc[1][0]);
        acc[1][1] = mfma16(a1, b1, acc[1][1]);
        __syncthreads();
    }
    // transpose in LDS: ot[col][row]
    #pragma unroll
    for (int ri = 0; ri < 2; ri++)
        #pragma unroll
        for (int ci = 0; ci < 2; ci++) {
            int rowb = wr + 16 * ri + (lane >> 4) * 4;
            int colb = wc + 16 * ci + lr;
            #pragma unroll
            for (int r = 0; r < 4; r++)
                ot[colb][rowb + r] = cvt_bf(acc[ri][ci][r]);
        }
    __syncthreads();
    int s = m0 / NRES, n0 = m0 % NRES;
    int h0 = n0c >> 5;                          // two heads h0, h0+1
    int orow = t >> 2, seg = (t & 3) * 16;
    short8 v0 = *(const short8*)&ot[orow][seg];
    short8 v1 = *(const short8*)&ot[orow][seg + 8];
    int hh = orow >> 5, dd = orow & 31;
    ushort_t* dst = &vtt[(((size_t)(h0 + hh) * SD) + s * DH + dd) * NRES + n0 + seg];
    *(short8*)&dst[0] = v0;
    *(short8*)&dst[8] = v1;
}

// ---------------- generic 64x64 bf16 transpose ----------------
__global__ __launch_bounds__(256) void k_tr(const ushort_t* __restrict__ src,
                                            ushort_t* __restrict__ dst,
                                            int R, int C) {
    size_t bs = (size_t)R * C;
    const ushort_t* s = src + blockIdx.z * bs;
    ushort_t* d = dst + blockIdx.z * bs;
    int r0 = blockIdx.y * 64, c0 = blockIdx.x * 64;
    __shared__ ushort_t tile[64][72];
    int t = threadIdx.x;
    int tr = t >> 2, tc = (t & 3) * 16;
    *(short8*)&tile[tr][tc]     = *(const short8*)&s[(size_t)(r0 + tr) * C + c0 + tc];
    *(short8*)&tile[tr][tc + 8] = *(const short8*)&s[(size_t)(r0 + tr) * C + c0 + tc + 8];
    __syncthreads();
    short8 o0, o1;
    #pragma unroll
    for (int i = 0; i < 8; i++) {
        o0[i] = (short)tile[tc + i][tr];
        o1[i] = (short)tile[tc + 8 + i][tr];
    }
    *(short8*)&d[(size_t)(c0 + tr) * R + r0 + tc]     = o0;
    *(short8*)&d[(size_t)(c0 + tr) * R + r0 + tc + 8] = o1;
}

// ---------------- K4: attention GEMM per head (128x128 tile) -> otb2[(s*N+i)][h*32+d] ----------------
__global__ __launch_bounds__(256) void k_attn_mfma(const ushort_t* __restrict__ wsb,
                                                   const ushort_t* __restrict__ vtt,
                                                   ushort_t* __restrict__ otb2) {
    int h = blockIdx.z;
    const ushort_t* A  = wsb + (size_t)h * NPAIR;        // [384][384]
    const ushort_t* Bt = vtt + (size_t)h * SD * NRES;    // [8192][384]
    int m0 = blockIdx.y * 128, n0 = blockIdx.x * 128;
    __shared__ ushort_t Al[128][40];
    __shared__ ushort_t Bl[128][40];
    int t = threadIdx.x;
    int srow = t >> 1, sko = (t & 1) * 16;
    int wave = t >> 6, lane = t & 63;
    int wr = (wave >> 1) * 64, wc = (wave & 1) * 64;
    int lk = (lane >> 4) * 8, lr = lane & 15;
    f32x4 acc[4][4] = {};
    for (int k0 = 0; k0 < NRES; k0 += 32) {
        *(short8*)&Al[srow][sko]     = *(const short8*)&A[(size_t)(m0 + srow) * NRES + k0 + sko];
        *(short8*)&Al[srow][sko + 8] = *(const short8*)&A[(size_t)(m0 + srow) * NRES + k0 + sko + 8];
        *(short8*)&Bl[srow][sko]     = *(const short8*)&Bt[(size_t)(n0 + srow) * NRES + k0 + sko];
        *(short8*)&Bl[srow][sko + 8] = *(const short8*)&Bt[(size_t)(n0 + srow) * NRES + k0 + sko + 8];
        __syncthreads();
        short8 af[4], bf2[4];
        #pragma unroll
        for (int i = 0; i < 4; i++) {
            af[i]  = *(const short8*)&Al[wr + 16 * i + lr][lk];
            bf2[i] = *(const short8*)&Bl[wc + 16 * i + lr][lk];
        }
        #pragma unroll
        for (int ri = 0; ri < 4; ri++)
            #pragma unroll
            for (int ci = 0; ci < 4; ci++)
                acc[ri][ci] = mfma16(af[ri], bf2[ci], acc[ri][ci]);
        __syncthreads();
    }
    #pragma unroll
    for (int ri = 0; ri < 4; ri++)
        #pragma unroll
        for (int ci = 0; ci < 4; ci++) {
            int row0 = m0 + wr + 16 * ri + (lane >> 4) * 4;   // i
            int col  = n0 + wc + 16 * ci + lr;                // s*32+d
            int s = col >> 5, dd = col & 31;
            #pragma unroll
            for (int r = 0; r < 4; r++)
                otb2[((size_t)s * NRES + row0 + r) * HC + h * DH + dd] = cvt_bf(acc[ri][ci][r]);
        }
}

// ---------------- K5: fused gate GEMM + sigmoid*o + out GEMM + residual -> mout ----------------
__global__ __launch_bounds__(256) void k_gateout(const ushort_t* __restrict__ A,   // mnb [NROWS][64]
                                                 const ushort_t* __restrict__ Bg,  // pgwb [256][64]
                                                 const ushort_t* __restrict__ otb2,// [NROWS][256]
                                                 const ushort_t* __restrict__ Bo,  // powb [64][256]
                                                 const float* __restrict__ m,
                                                 float* __restrict__ mout) {
    int m0 = blockIdx.x * 64;
    __shared__ ushort_t Al[64][72];
    __shared__ ushort_t Bl[64][72];
    __shared__ ushort_t go[64][264];
    int t = threadIdx.x;
    int srow = t >> 2, sko = (t & 3) * 16;
    int wave = t >> 6, lane = t & 63;
    int wr = (wave >> 1) * 32, wc = (wave & 1) * 32;
    int lk = (lane >> 4) * 8, lr = lane & 15;
    // stage full A tile [64][64]
    {
        const ushort_t* arow = &A[(size_t)(m0 + srow) * DM + sko];
        *(short8*)&Al[srow][sko]     = *(const short8*)&arow[0];
        *(short8*)&Al[srow][sko + 8] = *(const short8*)&arow[8];
    }
    __syncthreads();
    short8 a[2][2];   // [mi][ks]
    a[0][0] = *(const short8*)&Al[wr + lr][lk];
    a[0][1] = *(const short8*)&Al[wr + lr][32 + lk];
    a[1][0] = *(const short8*)&Al[wr + 16 + lr][lk];
    a[1][1] = *(const short8*)&Al[wr + 16 + lr][32 + lk];
    // ---- gate: 4 n-quarters of 64 ----
    for (int nq = 0; nq < 4; nq++) {
        __syncthreads();
        {
            const ushort_t* brow = &Bg[(size_t)(nq * 64 + srow) * DM + sko];
            *(short8*)&Bl[srow][sko]     = *(const short8*)&brow[0];
            *(short8*)&Bl[srow][sko + 8] = *(const short8*)&brow[8];
        }
        __syncthreads();
        f32x4 acc[2][2] = {};
        #pragma unroll
        for (int ks = 0; ks < 2; ks++) {
            short8 b0 = *(const short8*)&Bl[wc + lr][ks * 32 + lk];
            short8 b1 = *(const short8*)&Bl[wc + 16 + lr][ks * 32 + lk];
            acc[0][0] = mfma16(a[0][ks], b0, acc[0][0]);
            acc[0][1] = mfma16(a[0][ks], b1, acc[0][1]);
            acc[1][0] = mfma16(a[1][ks], b0, acc[1][0]);
            acc[1][1] = mfma16(a[1][ks], b1, acc[1][1]);
        }
        #pragma unroll
        for (int ri = 0; ri < 2; ri++)
            #pragma unroll
            for (int ci = 0; ci < 2; ci++) {
                int lrow = wr + 16 * ri + (lane >> 4) * 4;
                int col  = nq * 64 + wc + 16 * ci + lr;
                #pragma unroll
                for (int r = 0; r < 4; r++) {
                    float ov = cvt_f(otb2[(size_t)(m0 + lrow + r) * HC + col]);
                    go[lrow + r][col] = cvt_bf(sigm(acc[ri][ci][r]) * ov);
                }
            }
    }
    // ---- out GEMM: [64 rows][K=256] @ powb^T -> 64 cols, + residual ----
    f32x4 acc[2][2] = {};
    for (int k0 = 0; k0 < HC; k0 += 32) {
        __syncthreads();
        *(short8*)&Bl[t >> 2][(t & 3) * 8] = *(const short8*)&Bo[(size_t)(t >> 2) * HC + k0 + (t & 3) * 8];
        __syncthreads();
        short8 a0 = *(const short8*)&go[wr + lr][k0 + lk];
        short8 a1 = *(const short8*)&go[wr + 16 + lr][k0 + lk];
        short8 b0 = *(const short8*)&Bl[wc + lr][lk];
        short8 b1 = *(const short8*)&Bl[wc + 16 + lr][lk];
        acc[0][0] = mfma16(a0, b0, acc[0][0]);
        acc[0][1] = mfma16(a0, b1, acc[0][1]);
        acc[1][0] = mfma16(a1, b0, acc[1][0]);
        acc[1][1] = mfma16(a1, b1, acc[1][1]);
    }
    #pragma unroll
    for (int ri = 0; ri < 2; ri++)
        #pragma unroll
        for (int ci = 0; ci < 2; ci++) {
            int row0 = m0 + wr + 16 * ri + (lane >> 4) * 4;
            int col  = wc + 16 * ci + lr;
            #pragma unroll
            for (int r = 0; r < 4; r++) {
                size_t idx = (size_t)(row0 + r) * DM + col;
                mout[idx] = m[idx] + acc[ri][ci][r];
            }
        }
}

// ---------------- K6: fused SwiGLU transition (fc1/fc2 + silu*mul + fc3 + residual) ----------------
__global__ __launch_bounds__(256) void k_fctrans(const ushort_t* __restrict__ A,   // tn_bf [NROWS][64]
                                                 const ushort_t* __restrict__ B1,  // f1b [256][64]
                                                 const ushort_t* __restrict__ B2,  // f2b [256][64]
                                                 const ushort_t* __restrict__ B3,  // f3b [64][256]
                                                 float* __restrict__ mio) {
    int m0 = blockIdx.x * 64;
    __shared__ ushort_t Al[64][72];
    __shared__ ushort_t B1l[64][72];
    __shared__ ushort_t B2l[64][72];
    __shared__ ushort_t hhl[64][264];
    int t = threadIdx.x;
    int srow = t >> 2, sko = (t & 3) * 16;
    int wave = t >> 6, lane = t & 63;
    int wr = (wave >> 1) * 32, wc = (wave & 1) * 32;
    int lk = (lane >> 4) * 8, lr = lane & 15;
    {
        const ushort_t* arow = &A[(size_t)(m0 + srow) * DM + sko];
        *(short8*)&Al[srow][sko]     = *(const short8*)&arow[0];
        *(short8*)&Al[srow][sko + 8] = *(const short8*)&arow[8];
    }
    __syncthreads();
    short8 a[2][2];
    a[0][0] = *(const short8*)&Al[wr + lr][lk];
    a[0][1] = *(const short8*)&Al[wr + lr][32 + lk];
    a[1][0] = *(const short8*)&Al[wr + 16 + lr][lk];
    a[1][1] = *(const short8*)&Al[wr + 16 + lr][32 + lk];
    for (int nq = 0; nq < 4; nq++) {
        __syncthreads();
        {
            const ushort_t* b1r = &B1[(size_t)(nq * 64 + srow) * DM + sko];
            const ushort_t* b2r = &B2[(size_t)(nq * 64 + srow) * DM + sko];
            *(short8*)&B1l[srow][sko]     = *(const short8*)&b1r[0];
            *(short8*)&B1l[srow][sko + 8] = *(const short8*)&b1r[8];
            *(short8*)&B2l[srow][sko]     = *(const short8*)&b2r[0];
            *(short8*)&B2l[srow][sko + 8] = *(const short8*)&b2r[8];
        }
        __syncthreads();
        f32x4 acc1[2][2] = {}, acc2[2][2] = {};
        #pragma unroll
        for (int ks = 0; ks < 2; ks++) {
            short8 p0 = *(const short8*)&B1l[wc + lr][ks * 32 + lk];
            short8 p1 = *(const short8*)&B1l[wc + 16 + lr][ks * 32 + lk];
            short8 q0 = *(const short8*)&B2l[wc + lr][ks * 32 + lk];
            short8 q1 = *(const short8*)&B2l[wc + 16 + lr][ks * 32 + lk];
            acc1[0][0] = mfma16(a[0][ks], p0, acc1[0][0]);
            acc1[0][1] = mfma16(a[0][ks], p1, acc1[0][1]);
            acc1[1][0] = mfma16(a[1][ks], p0, acc1[1][0]);
            acc1[1][1] = mfma16(a[1][ks], p1, acc1[1][1]);
            acc2[0][0] = mfma16(a[0][ks], q0, acc2[0][0]);
            acc2[0][1] = mfma16(a[0][ks], q1, acc2[0][1]);
            acc2[1][0] = mfma16(a[1][ks], q0, acc2[1][0]);
            acc2[1][1] = mfma16(a[1][ks], q1, acc2[1][1]);
        }
        #pragma unroll
        for (int ri = 0; ri < 2; ri++)
            #pragma unroll
            for (int ci = 0; ci < 2; ci++) {
                int lrow = wr + 16 * ri + (lane >> 4) * 4;
                int col  = nq * 64 + wc + 16 * ci + lr;
                #pragma unroll
                for (int r = 0; r < 4; r++) {
                    float a1v = acc1[ri][ci][r], a2v = acc2[ri][ci][r];
                    hhl[lrow + r][col] = cvt_bf(a1v * sigm(a1v) * a2v);
                }
            }
    }
    // fc3: [64][256] @ f3b^T -> 64 cols, residual
    f32x4 acc[2][2] = {};
    for (int k0 = 0; k0 < FF; k0 += 32) {
        __syncthreads();
        *(short8*)&B1l[t >> 2][(t & 3) * 8] = *(const short8*)&B3[(size_t)(t >> 2) * FF + k0 + (t & 3) * 8];
        __syncthreads();
        short8 a0 = *(const short8*)&hhl[wr + lr][k0 + lk];
        short8 a1 = *(const short8*)&hhl[wr + 16 + lr][k0 + lk];
        short8 b0 = *(const short8*)&B1l[wc + lr][lk];
        short8 b1 = *(const short8*)&B1l[wc + 16 + lr][lk];
        acc[0][0] = mfma16(a0, b0, acc[0][0]);
        acc[0][1] = mfma16(a0, b1, acc[0][1]);
        acc[1][0] = mfma16(a1, b0, acc[1][0]);
        acc[1][1] = mfma16(a1, b1, acc[1][1]);
    }
    #pragma unroll
    for (int ri = 0; ri < 2; ri++)
        #pragma unroll
        for (int ci = 0; ci < 2; ci++) {
            int row0 = m0 + wr + 16 * ri + (lane >> 4) * 4;
            int col  = wc + 16 * ci + lr;
            #pragma unroll
            for (int r = 0; r < 4; r++)
                mio[(size_t)(row0 + r) * DM + col] += acc[ri][ci][r];
        }
}

// ---------------- K7: a/b projection GEMM + mask -> abuf/bbuf [s][n*32+c] ----------------
__global__ __launch_bounds__(256) void k_ab_mfma(const ushort_t* __restrict__ A,
                                                 const ushort_t* __restrict__ Bt,
                                                 const float* __restrict__ smask,
                                                 ushort_t* __restrict__ abuf,
                                                 ushort_t* __restrict__ bbuf) {
    int m0 = blockIdx.x * 64;
    __shared__ ushort_t Al[64][40];
    __shared__ ushort_t Bl[64][40];
    int t = threadIdx.x;
    int srow = t >> 2, sko = (t & 3) * 8;
    int wave = t >> 6, lane = t & 63;
    int wr = (wave >> 1) * 32, wc = (wave & 1) * 32;
    int lk = (lane >> 4) * 8, lr = lane & 15;
    f32x4 acc[2][2] = {};
    for (int k0 = 0; k0 < DM; k0 += 32) {
        *(short8*)&Al[srow][sko] = *(const short8*)&A[(size_t)(m0 + srow) * DM + k0 + sko];
        *(short8*)&Bl[srow][sko] = *(const short8*)&Bt[(size_t)srow * DM + k0 + sko];
        __syncthreads();
        short8 a0 = *(const short8*)&Al[wr + lr][lk];
        short8 a1 = *(const short8*)&Al[wr + 16 + lr][lk];
        short8 b0 = *(const short8*)&Bl[wc + lr][lk];
        short8 b1 = *(const short8*)&Bl[wc + 16 + lr][lk];
        acc[0][0] = mfma16(a0, b0, acc[0][0]);
        acc[0][1] = mfma16(a0, b1, acc[0][1]);
        acc[1][0] = mfma16(a1, b0, acc[1][0]);
        acc[1][1] = mfma16(a1, b1, acc[1][1]);
        __syncthreads();
    }
    #pragma unroll
    for (int ri = 0; ri < 2; ri++)
        #pragma unroll
        for (int ci = 0; ci < 2; ci++) {
            int row0 = m0 + wr + 16 * ri + (lane >> 4) * 4;
            int col  = wc + 16 * ci + lr;               // 0..63
            #pragma unroll
            for (int r = 0; r < 4; r++) {
                int rr = row0 + r;                      // s*NRES+n
                int s = rr / NRES, n = rr % NRES;
                float v = acc[ri][ci][r] * smask[rr];
                if (col < DOP)
                    abuf[(size_t)s * (NRES * DOP) + n * DOP + col] = cvt_bf(v);
                else
                    bbuf[(size_t)s * (NRES * DOP) + n * DOP + (col - DOP)] = cvt_bf(v);
            }
        }
}

// ---------------- K8: mask pair-count Gram tile ----------------
__global__ __launch_bounds__(256) void k_msum(const float* __restrict__ smask,
                                              float* __restrict__ msum) {
    int i0 = blockIdx.y * 64, j0 = blockIdx.x * 64;
    __shared__ float As[16][64];
    __shared__ float Bs[16][64];
    int t = threadIdx.x;
    int ty = t >> 4, tx = t & 15;
    float acc[4][4] = {};
    for (int k0 = 0; k0 < NSEQ; k0 += 16) {
        int kk = t >> 4, x4 = (t & 15) * 4;
        *(float4*)&As[kk][x4] = *(const float4*)&smask[(size_t)(k0 + kk) * NRES + i0 + x4];
        *(float4*)&Bs[kk][x4] = *(const float4*)&smask[(size_t)(k0 + kk) * NRES + j0 + x4];
        __syncthreads();
        #pragma unroll
        for (int k = 0; k < 16; k++) {
            float4 a4 = *(const float4*)&As[k][ty * 4];
            float4 b4 = *(const float4*)&Bs[k][tx * 4];
            float ar[4] = {a4.x, a4.y, a4.z, a4.w};
            float br[4] = {b4.x, b4.y, b4.z, b4.w};
            #pragma unroll
            for (int i2 = 0; i2 < 4; i2++)
                #pragma unroll
                for (int j2 = 0; j2 < 4; j2++)
                    acc[i2][j2] += ar[i2] * br[j2];
        }
        __syncthreads();
    }
    #pragma unroll
    for (int r = 0; r < 4; r++) {
        float4 o4 = make_float4(fmaxf(acc[r][0], 1.0f), fmaxf(acc[r][1], 1.0f),
                                fmaxf(acc[r][2], 1.0f), fmaxf(acc[r][3], 1.0f));
        *(float4*)&msum[(size_t)(i0 + ty * 4 + r) * NRES + j0 + tx * 4] = o4;
    }
}

// ---------------- K9: OPM outer GEMM (bf16 MFMA, 128x128 tile) ----------------
__global__ __launch_bounds__(256) void k_opm_mfma(const ushort_t* __restrict__ At,
                                                  const ushort_t* __restrict__ Bt,
                                                  ushort_t* __restrict__ opmc) {
    int m0 = blockIdx.y * 128;                  // over ICHUNK*32 (il,c)
    int n0 = blockIdx.x * 128;                  // over 12288 (j,d)
    __shared__ ushort_t Al[128][40];
    __shared__ ushort_t Bl[128][40];
    int t = threadIdx.x;
    int srow = t >> 1, sko = (t & 1) * 16;
    int wave = t >> 6, lane = t & 63;
    int wr = (wave >> 1) * 64, wc = (wave & 1) * 64;
    int lk = (lane >> 4) * 8, lr = lane & 15;
    f32x4 acc[4][4] = {};
    for (int k0 = 0; k0 < NSEQ; k0 += 32) {
        *(short8*)&Al[srow][sko]     = *(const short8*)&At[(size_t)(m0 + srow) * NSEQ + k0 + sko];
        *(short8*)&Al[srow][sko + 8] = *(const short8*)&At[(size_t)(m0 + srow) * NSEQ + k0 + sko + 8];
        *(short8*)&Bl[srow][sko]     = *(const short8*)&Bt[(size_t)(n0 + srow) * NSEQ + k0 + sko];
        *(short8*)&Bl[srow][sko + 8] = *(const short8*)&Bt[(size_t)(n0 + srow) * NSEQ + k0 + sko + 8];
        __syncthreads();
        short8 af[4], bf2[4];
        #pragma unroll
        for (int i = 0; i < 4; i++) {
            af[i]  = *(const short8*)&Al[wr + 16 * i + lr][lk];
            bf2[i] = *(const short8*)&Bl[wc + 16 * i + lr][lk];
        }
        #pragma unroll
        for (int ri = 0; ri < 4; ri++)
            #pragma unroll
            for (int ci = 0; ci < 4; ci++)
                acc[ri][ci] = mfma16(af[ri], bf2[ci], acc[ri][ci]);
        __syncthreads();
    }
    #pragma unroll
    for (int ri = 0; ri < 4; ri++)
        #pragma unroll
        for (int ci = 0; ci < 4; ci++) {
            int mb = m0 + wr + 16 * ri + (lane >> 4) * 4;
            int n  = n0 + wc + 16 * ci + lr;
            int j = n >> 5, dd = n & 31;
            #pragma unroll
            for (int r = 0; r < 4; r++) {
                int mm = mb + r;
                int il = mm >> 5, c = mm & 31;
                opmc[((size_t)(il * NRES + j) << 10) + (c << 5) + dd] = cvt_bf(acc[ri][ci][r]);
            }
        }
}

// ---------------- K10: OPM projection + residual (128x128 tile, opmc read once) ----------------
__global__ __launch_bounds__(256) void k_proj_mfma(const ushort_t* __restrict__ A,
                                                   const ushort_t* __restrict__ Bt,
                                                   const float* __restrict__ opB,
                                                   const float* __restrict__ msum,
                                                   const float* __restrict__ zin,
                                                   float* __restrict__ zout,
                                                   int ib) {
    int m0 = blockIdx.x * 128;                  // over ICHUNK*NRES
    __shared__ ushort_t Al[128][40];
    __shared__ ushort_t Bl[128][40];
    int t = threadIdx.x;
    int wave = t >> 6, lane = t & 63;
    int wr = (wave >> 1) * 64, wc = (wave & 1) * 64;
    int lk = (lane >> 4) * 8, lr = lane & 15;
    int sr = t >> 1, sk = (t & 1) * 16;
    f32x4 acc[4][4] = {};
    for (int k0 = 0; k0 < 1024; k0 += 32) {
        *(short8*)&Al[sr][sk]     = *(const short8*)&A[(size_t)(m0 + sr) * 1024 + k0 + sk];
        *(short8*)&Al[sr][sk + 8] = *(const short8*)&A[(size_t)(m0 + sr) * 1024 + k0 + sk + 8];
        *(short8*)&Bl[sr][sk]     = *(const short8*)&Bt[(size_t)sr * 1024 + k0 + sk];
        *(short8*)&Bl[sr][sk + 8] = *(const short8*)&Bt[(size_t)sr * 1024 + k0 + sk + 8];
        __syncthreads();
        short8 af[4], bf2[4];
        #pragma unroll
        for (int i = 0; i < 4; i++) {
            af[i]  = *(const short8*)&Al[wr + 16 * i + lr][lk];
            bf2[i] = *(const short8*)&Bl[wc + 16 * i + lr][lk];
        }
        #pragma unroll
        for (int ri = 0; ri < 4; ri++)
            #pragma unroll
            for (int ci = 0; ci < 4; ci++)
                acc[ri][ci] = mfma16(af[ri], bf2[ci], acc[ri][ci]);
        __syncthreads();
    }
    #pragma unroll
    for (int ri = 0; ri < 4; ri++)
        #pragma unroll
        for (int ci = 0; ci < 4; ci++) {
            int row0 = m0 + wr + 16 * ri + (lane >> 4) * 4;
            int col  = wc + 16 * ci + lr;               // 0..127 = full DZ
            #pragma unroll
            for (int r = 0; r < 4; r++) {
                size_t G = (size_t)ib * NRES + row0 + r;
                float inv = 1.0f / msum[G];
                zout[G * DZ + col] = zin[G * DZ + col] + acc[ri][ci][r] * inv + opB[col];
            }
        }
}

// ---------------- launch ----------------
extern "C" void kernel_launch(void* const* d_in, const int* in_sizes, int n_in,
                              void* d_out, int out_size, void* d_ws, size_t ws_size,
                              hipStream_t stream) {
    const float* z     = (const float*)d_in[0];
    const float* m     = (const float*)d_in[1];
    const float* tmask = (const float*)d_in[2];
    const float* smask = (const float*)d_in[3];
    const float* nzw   = (const float*)d_in[4];
    const float* nzb   = (const float*)d_in[5];
    const float* pzw   = (const float*)d_in[6];
    const float* nmw   = (const float*)d_in[7];
    const float* nmb   = (const float*)d_in[8];
    const float* pmw   = (const float*)d_in[9];
    const float* pgw   = (const float*)d_in[10];
    const float* pow_  = (const float*)d_in[11];
    const float* tnw   = (const float*)d_in[12];
    const float* tnb_  = (const float*)d_in[13];
    const float* f1    = (const float*)d_in[14];
    const float* f2    = (const float*)d_in[15];
    const float* f3    = (const float*)d_in[16];
    const float* onw   = (const float*)d_in[17];
    const float* onb   = (const float*)d_in[18];
    const float* paw   = (const float*)d_in[19];
    const float* pbw   = (const float*)d_in[20];
    const float* opW   = (const float*)d_in[21];
    const float* opB   = (const float*)d_in[22];

    float* zout = (float*)d_out;
    float* mout = zout + ZTOT;

    char* W = (char*)d_ws;
    ushort_t* wsb  = (ushort_t*)(W + 4718592);          //  .. 7,077,888 (bf16 softmax wts)
    ushort_t* mnb  = (ushort_t*)(W + 7077888);          //  .. 19,660,800 (12.6MB)
    ushort_t* vtR  = (ushort_t*)(W + 19660800);         //  .. 69,992,448 (50.3MB, multi-use)
    ushort_t* vtt  = (ushort_t*)(W + 69992448);         //  .. 120,324,096 (50.3MB)
    ushort_t* otb2 = (ushort_t*)(W + 120324096);        //  .. 170,655,744 (50.3MB)
    float*    msum = (float*)(W + 170655744);           //  .. 171,245,568
    ushort_t* f1b  = (ushort_t*)(W + 171245568);
    ushort_t* f2b  = (ushort_t*)(W + 171278336);
    ushort_t* f3b  = (ushort_t*)(W + 171311104);
    ushort_t* opWb = (ushort_t*)(W + 171343872);        //  .. 171,606,016
    ushort_t* pmwb = (ushort_t*)(W + 171606016);
    ushort_t* pgwb = (ushort_t*)(W + 171638784);
    ushort_t* powb = (ushort_t*)(W + 171671552);        //  .. 171,704,320
    ushort_t* abwb = (ushort_t*)(W + 171704320);        //  .. 171,712,512 (8KB)
    ushort_t* pzwb = (ushort_t*)(W + 171712512);        //  .. 171,716,608 (4KB)
    // region aliases (dead-by-then):
    ushort_t* tn_bf = vtt;                  // vtt dead after k_attn_mfma
    ushort_t* onb_bf = mnb;                 // mnb dead after k_gateout
    ushort_t* abuf = (ushort_t*)(W + 69992448 + 12582912);   // vtt+12.6MB
    ushort_t* bbuf = (ushort_t*)(W + 69992448 + 18874368);   // vtt+18.9MB
    ushort_t* abt  = otb2;                  // otb2 dead after k_gateout
    ushort_t* bbt  = (ushort_t*)(W + 120324096 + 6291456);
    ushort_t* opmc = vtR;                   // vtR free at OPM time (needs 75.5MB < 100.6MB span)

    k_prep<<<512, 256, 0, stream>>>(f1, f2, f3, opW, pmw, pgw, pow_, paw, pbw, pzw,
                                    f1b, f2b, f3b, opWb, pmwb, pgwb, powb, abwb, pzwb);

    // PairWeightedAveraging
    k_biassm<<<NRES, 256, 0, stream>>>(z, nzw, nzb, pzwb, tmask, wsb);
    k_ln64<<<NROWS / 4, 256, 0, stream>>>(m, nmw, nmb, mnb);
    k_vproj_mfma<<<dim3(HC / 64, NROWS / 64), 256, 0, stream>>>(mnb, pmwb, vtt);
    k_attn_mfma<<<dim3(SD / 128, NRES / 128, NH), 256, 0, stream>>>(wsb, vtt, otb2);
    k_gateout<<<NROWS / 64, 256, 0, stream>>>(mnb, pgwb, otb2, powb, m, mout);

    // Transition (fused)
    k_ln64<<<NROWS / 4, 256, 0, stream>>>(mout, tnw, tnb_, tn_bf);
    k_fctrans<<<NROWS / 64, 256, 0, stream>>>(tn_bf, f1b, f2b, f3b, mout);

    // OuterProductMean
    k_ln64<<<NROWS / 4, 256, 0, stream>>>(mout, onw, onb, onb_bf);
    k_ab_mfma<<<NROWS / 64, 256, 0, stream>>>(onb_bf, abwb, smask, abuf, bbuf);
    k_tr<<<dim3((NRES * DOP) / 64, NSEQ / 64, 2), 256, 0, stream>>>(abuf, abt, NSEQ, NRES * DOP);
    k_msum<<<dim3(NRES / 64, NRES / 64), 256, 0, stream>>>(smask, msum);
    for (int cb = 0; cb < NRES / ICHUNK; cb++) {
        int ib = cb * ICHUNK;
        const ushort_t* Achunk = abt + (size_t)(ib * DOP) * NSEQ;
        k_opm_mfma<<<dim3((NRES * DOP) / 128, (ICHUNK * DOP) / 128), 256, 0, stream>>>(Achunk, bbt, opmc);
        k_proj_mfma<<<(ICHUNK * NRES) / 128, 256, 0, stream>>>(opmc, opWb, opB, msum, z, zout, ib);
    }
}

// Round 10
// 499.908 us; speedup vs baseline: 13.4219x; 1.1573x over previous
//
#include <hip/hip_runtime.h>
#include <math.h>

// ---------------- problem constants ----------------
constexpr int NRES = 384;          // N
constexpr int NSEQ = 256;          // S
constexpr int DM   = 64;           // MSA_S
constexpr int DZ   = 128;          // Z_D
constexpr int NH   = 8;            // H
constexpr int DH   = 32;           // C_H
constexpr int HC   = NH * DH;      // 256
constexpr int DOP  = 32;           // C_OPM
constexpr int FF   = 4 * DM;       // 256

constexpr int NPAIR = NRES * NRES;         // 147456
constexpr int NROWS = NSEQ * NRES;         // 98304
constexpr int ZTOT  = NPAIR * DZ;          // 18874368
constexpr int SD    = NSEQ * DH;           // 8192
constexpr int ICHUNK = 96;                 // i-rows per OPM chunk (4 chunks)

typedef unsigned short ushort_t;
typedef __attribute__((ext_vector_type(8))) short short8;
typedef __attribute__((ext_vector_type(4))) float f32x4;

__device__ __forceinline__ float wred_sum(float v) {
    #pragma unroll
    for (int off = 32; off; off >>= 1) v += __shfl_xor(v, off, 64);
    return v;
}
__device__ __forceinline__ float sigm(float x) { return 1.0f / (1.0f + expf(-x)); }
__device__ __forceinline__ ushort_t cvt_bf(float f) {
    unsigned u = __float_as_uint(f);
    unsigned r = (u + 0x7FFFu + ((u >> 16) & 1u)) >> 16;
    return (ushort_t)r;
}
__device__ __forceinline__ float cvt_f(ushort_t h) {
    return __uint_as_float(((unsigned)h) << 16);
}
__device__ __forceinline__ f32x4 mfma16(short8 a, short8 b, f32x4 c) {
    return __builtin_amdgcn_mfma_f32_16x16x32_bf16(a, b, c, 0, 0, 0);
}
// async global->LDS, 16B per lane; LDS dest = wave-uniform base + lane*16
__device__ __forceinline__ void gld16(const ushort_t* g, ushort_t* l) {
    __builtin_amdgcn_global_load_lds(
        (const __attribute__((address_space(1))) unsigned int*)g,
        (__attribute__((address_space(3))) unsigned int*)l, 16, 0, 0);
}

// ---------------- K0: weights -> bf16 ----------------
__global__ __launch_bounds__(256) void k_prep(const float* __restrict__ f1,
                                              const float* __restrict__ f2,
                                              const float* __restrict__ f3,
                                              const float* __restrict__ opW,
                                              const float* __restrict__ pmw,
                                              const float* __restrict__ pgw,
                                              const float* __restrict__ pow_,
                                              const float* __restrict__ paw,
                                              const float* __restrict__ pbw,
                                              const float* __restrict__ pzw,
                                              ushort_t* __restrict__ f1b,
                                              ushort_t* __restrict__ f2b,
                                              ushort_t* __restrict__ f3b,
                                              ushort_t* __restrict__ opWb,
                                              ushort_t* __restrict__ pmwb,
                                              ushort_t* __restrict__ pgwb,
                                              ushort_t* __restrict__ powb,
                                              ushort_t* __restrict__ abwb,
                                              ushort_t* __restrict__ pzwb) {
    int i = blockIdx.x * 256 + threadIdx.x;      // 131072 threads
    opWb[i] = cvt_bf(opW[i]);
    if (i < FF * DM) {
        f1b[i] = cvt_bf(f1[i]);
        f2b[i] = cvt_bf(f2[i]);
        f3b[i] = cvt_bf(f3[i]);
    }
    if (i < HC * DM) {
        pmwb[i] = cvt_bf(pmw[i]);
        pgwb[i] = cvt_bf(pgw[i]);
        powb[i] = cvt_bf(pow_[i]);
    }
    if (i < 2 * DOP * DM) {                      // combined [64][64]: rows 0..31 paw, 32..63 pbw
        abwb[i] = cvt_bf(i < DOP * DM ? paw[i] : pbw[i - DOP * DM]);
    }
    if (i < 16 * DZ) {                           // [16][128]: rows 0..7 pzw, rows 8..15 zero
        pzwb[i] = (i < NH * DZ) ? cvt_bf(pzw[i]) : (ushort_t)0;
    }
}

// ---------------- K1: fused LN(z) + bias proj + mask + softmax -> wsb (one block per i) ----------------
__global__ __launch_bounds__(256) void k_biassm(const float* __restrict__ z,
                                                const float* __restrict__ nzw,
                                                const float* __restrict__ nzb,
                                                const ushort_t* __restrict__ pzwb,
                                                const float* __restrict__ tmask,
                                                ushort_t* __restrict__ wsb) {
    int i = blockIdx.x;                         // 0..383
    __shared__ ushort_t Azl[128][136];
    __shared__ ushort_t Bl[16][136];
    __shared__ float ob[8][388];
    __shared__ float wln[128], bln[128];
    int t = threadIdx.x;
    if (t < 128) { wln[t] = nzw[t]; bln[t] = nzb[t]; }
    int wave = t >> 6, lane = t & 63;
    int lk = (lane >> 4) * 8, lr = lane & 15;
    int wr = wave * 32;
    // stage B once
    for (int idx = t * 8; idx < 16 * DZ; idx += 256 * 8) {
        int row = idx >> 7, col = idx & 127;
        *(short8*)&Bl[row][col] = *(const short8*)&pzwb[idx];
    }
    __syncthreads();
    for (int c = 0; c < 3; c++) {
        // stage A chunk with fused LN: rows j = c*128 .. +127; 2 threads per row
        {
            int jl = t >> 1, cb = (t & 1) * 64;
            const float* src = &z[((size_t)i * NRES + c * 128 + jl) * DZ + cb];
            float4 v[16];
            float s1 = 0.0f, s2 = 0.0f;
            #pragma unroll
            for (int q = 0; q < 16; q++) {
                v[q] = *(const float4*)&src[q * 4];
                s1 += v[q].x + v[q].y + v[q].z + v[q].w;
                s2 += v[q].x * v[q].x + v[q].y * v[q].y + v[q].z * v[q].z + v[q].w * v[q].w;
            }
            s1 += __shfl_xor(s1, 1, 64);
            s2 += __shfl_xor(s2, 1, 64);
            float mu = s1 * (1.0f / 128.0f);
            float var = s2 * (1.0f / 128.0f) - mu * mu;
            float rs = rsqrtf(var + 1e-5f);
            #pragma unroll
            for (int q = 0; q < 8; q++) {
                float4 xa = v[2 * q], xb = v[2 * q + 1];
                int base = cb + q * 8;
                short8 o;
                o[0] = (short)cvt_bf((xa.x - mu) * rs * wln[base + 0] + bln[base + 0]);
                o[1] = (short)cvt_bf((xa.y - mu) * rs * wln[base + 1] + bln[base + 1]);
                o[2] = (short)cvt_bf((xa.z - mu) * rs * wln[base + 2] + bln[base + 2]);
                o[3] = (short)cvt_bf((xa.w - mu) * rs * wln[base + 3] + bln[base + 3]);
                o[4] = (short)cvt_bf((xb.x - mu) * rs * wln[base + 4] + bln[base + 4]);
                o[5] = (short)cvt_bf((xb.y - mu) * rs * wln[base + 5] + bln[base + 5]);
                o[6] = (short)cvt_bf((xb.z - mu) * rs * wln[base + 6] + bln[base + 6]);
                o[7] = (short)cvt_bf((xb.w - mu) * rs * wln[base + 7] + bln[base + 7]);
                *(short8*)&Azl[jl][base] = o;
            }
        }
        __syncthreads();
        f32x4 acc[2] = {};
        #pragma unroll
        for (int ks = 0; ks < 4; ks++) {
            short8 b = *(const short8*)&Bl[lr][ks * 32 + lk];
            short8 a0 = *(const short8*)&Azl[wr + lr][ks * 32 + lk];
            short8 a1 = *(const short8*)&Azl[wr + 16 + lr][ks * 32 + lk];
            acc[0] = mfma16(a0, b, acc[0]);
            acc[1] = mfma16(a1, b, acc[1]);
        }
        if (lr < NH) {
            #pragma unroll
            for (int ri = 0; ri < 2; ri++) {
                int jb = c * 128 + wr + 16 * ri + (lane >> 4) * 4;
                #pragma unroll
                for (int r = 0; r < 4; r++)
                    ob[lr][jb + r] = acc[ri][r];
            }
        }
        __syncthreads();
    }
    // softmax over j per head (half-wave = one head)
    int h = wave * 2 + (lane >> 5);
    int l32 = lane & 31;
    int jb = l32 * 12;
    const float* tm = &tmask[(size_t)i * NRES];
    float vals[12];
    float mx = -1e30f;
    #pragma unroll
    for (int q = 0; q < 12; q++) {
        float v = ob[h][jb + q] + (1.0f - tm[jb + q]) * (-1e9f);
        vals[q] = v;
        mx = fmaxf(mx, v);
    }
    #pragma unroll
    for (int off = 16; off; off >>= 1) mx = fmaxf(mx, __shfl_xor(mx, off, 64));
    float sum = 0.0f;
    #pragma unroll
    for (int q = 0; q < 12; q++) { vals[q] = expf(vals[q] - mx); sum += vals[q]; }
    #pragma unroll
    for (int off = 16; off; off >>= 1) sum += __shfl_xor(sum, off, 64);
    float inv = 1.0f / sum;
    ushort_t* o = &wsb[(size_t)h * NPAIR + (size_t)i * NRES + jb];
    #pragma unroll
    for (int q = 0; q < 12; q++) o[q] = cvt_bf(vals[q] * inv);
}

// ---------------- K3: LN rows (64-wide) fp32 -> bf16 ----------------
__global__ __launch_bounds__(256) void k_ln64(const float* __restrict__ src,
                                              const float* __restrict__ lw,
                                              const float* __restrict__ lb,
                                              ushort_t* __restrict__ dst) {
    int wave = threadIdx.x >> 6, lane = threadIdx.x & 63;
    int r = blockIdx.x * 4 + wave;
    float x = src[(size_t)r * DM + lane];
    float mu = wred_sum(x) * (1.0f / 64.0f);
    float d = x - mu;
    float var = wred_sum(d * d) * (1.0f / 64.0f);
    dst[(size_t)r * DM + lane] = cvt_bf(d * rsqrtf(var + 1e-5f) * lw[lane] + lb[lane]);
}

// ---------------- K3b: v projection GEMM -> vtt[h][s*32+d][n] directly ----------------
__global__ __launch_bounds__(256) void k_vproj_mfma(const ushort_t* __restrict__ A,
                                                    const ushort_t* __restrict__ Bt,
                                                    ushort_t* __restrict__ vtt) {
    int m0 = blockIdx.y * 64, n0c = blockIdx.x * 64;
    __shared__ ushort_t Al[64][40];
    __shared__ ushort_t Bl[64][40];
    __shared__ ushort_t ot[64][72];
    int t = threadIdx.x;
    int srow = t >> 2, sko = (t & 3) * 8;
    int wave = t >> 6, lane = t & 63;
    int wr = (wave >> 1) * 32, wc = (wave & 1) * 32;
    int lk = (lane >> 4) * 8, lr = lane & 15;
    f32x4 acc[2][2] = {};
    for (int k0 = 0; k0 < DM; k0 += 32) {
        *(short8*)&Al[srow][sko] = *(const short8*)&A[(size_t)(m0 + srow) * DM + k0 + sko];
        *(short8*)&Bl[srow][sko] = *(const short8*)&Bt[(size_t)(n0c + srow) * DM + k0 + sko];
        __syncthreads();
        short8 a0 = *(const short8*)&Al[wr + lr][lk];
        short8 a1 = *(const short8*)&Al[wr + 16 + lr][lk];
        short8 b0 = *(const short8*)&Bl[wc + lr][lk];
        short8 b1 = *(const short8*)&Bl[wc + 16 + lr][lk];
        acc[0][0] = mfma16(a0, b0, acc[0][0]);
        acc[0][1] = mfma16(a0, b1, acc[0][1]);
        acc[1][0] = mfma16(a1, b0, acc[1][0]);
        acc[1][1] = mfma16(a1, b1, acc[1][1]);
        __syncthreads();
    }
    // transpose in LDS: ot[col][row]
    #pragma unroll
    for (int ri = 0; ri < 2; ri++)
        #pragma unroll
        for (int ci = 0; ci < 2; ci++) {
            int rowb = wr + 16 * ri + (lane >> 4) * 4;
            int colb = wc + 16 * ci + lr;
            #pragma unroll
            for (int r = 0; r < 4; r++)
                ot[colb][rowb + r] = cvt_bf(acc[ri][ci][r]);
        }
    __syncthreads();
    int s = m0 / NRES, n0 = m0 % NRES;
    int h0 = n0c >> 5;                          // two heads h0, h0+1
    int orow = t >> 2, seg = (t & 3) * 16;
    short8 v0 = *(const short8*)&ot[orow][seg];
    short8 v1 = *(const short8*)&ot[orow][seg + 8];
    int hh = orow >> 5, dd = orow & 31;
    ushort_t* dst = &vtt[(((size_t)(h0 + hh) * SD) + s * DH + dd) * NRES + n0 + seg];
    *(short8*)&dst[0] = v0;
    *(short8*)&dst[8] = v1;
}

// ---------------- generic 64x64 bf16 transpose ----------------
__global__ __launch_bounds__(256) void k_tr(const ushort_t* __restrict__ src,
                                            ushort_t* __restrict__ dst,
                                            int R, int C) {
    size_t bs = (size_t)R * C;
    const ushort_t* s = src + blockIdx.z * bs;
    ushort_t* d = dst + blockIdx.z * bs;
    int r0 = blockIdx.y * 64, c0 = blockIdx.x * 64;
    __shared__ ushort_t tile[64][72];
    int t = threadIdx.x;
    int tr = t >> 2, tc = (t & 3) * 16;
    *(short8*)&tile[tr][tc]     = *(const short8*)&s[(size_t)(r0 + tr) * C + c0 + tc];
    *(short8*)&tile[tr][tc + 8] = *(const short8*)&s[(size_t)(r0 + tr) * C + c0 + tc + 8];
    __syncthreads();
    short8 o0, o1;
    #pragma unroll
    for (int i = 0; i < 8; i++) {
        o0[i] = (short)tile[tc + i][tr];
        o1[i] = (short)tile[tc + 8 + i][tr];
    }
    *(short8*)&d[(size_t)(c0 + tr) * R + r0 + tc]     = o0;
    *(short8*)&d[(size_t)(c0 + tr) * R + r0 + tc + 8] = o1;
}

// ---------------- K4: attention GEMM per head (128x128 tile, gload_lds) ----------------
__global__ __launch_bounds__(256) void k_attn_mfma(const ushort_t* __restrict__ wsb,
                                                   const ushort_t* __restrict__ vtt,
                                                   ushort_t* __restrict__ otb2) {
    int h = blockIdx.z;
    const ushort_t* A  = wsb + (size_t)h * NPAIR;        // [384][384]
    const ushort_t* Bt = vtt + (size_t)h * SD * NRES;    // [8192][384]
    int m0 = blockIdx.y * 128, n0 = blockIdx.x * 128;
    __shared__ ushort_t Al[128 * 32];
    __shared__ ushort_t Bl[128 * 32];
    int t = threadIdx.x;
    int w = t >> 6, lane = t & 63;
    int wr = (w >> 1) * 64, wc = (w & 1) * 64;
    int lq = lane >> 4, lr = lane & 15;
    int rS = w * 16 + (lane >> 2);              // staging row within 64-row half
    int cqs = (((lane & 3) ^ ((rS >> 1) & 3)) << 3);   // swizzled source quad (ushorts)
    f32x4 acc[4][4] = {};
    for (int k0 = 0; k0 < NRES; k0 += 32) {
        gld16(&A [(size_t)(m0 + rS)      * NRES + k0 + cqs], &Al[(w * 16) * 32]);
        gld16(&A [(size_t)(m0 + 64 + rS) * NRES + k0 + cqs], &Al[(64 + w * 16) * 32]);
        gld16(&Bt[(size_t)(n0 + rS)      * NRES + k0 + cqs], &Bl[(w * 16) * 32]);
        gld16(&Bt[(size_t)(n0 + 64 + rS) * NRES + k0 + cqs], &Bl[(64 + w * 16) * 32]);
        __syncthreads();
        short8 af[4], bf2[4];
        #pragma unroll
        for (int i = 0; i < 4; i++) {
            int ra = wr + 16 * i + lr;
            int rb = wc + 16 * i + lr;
            af[i]  = *(const short8*)&Al[ra * 32 + ((lq ^ ((ra >> 1) & 3)) << 3)];
            bf2[i] = *(const short8*)&Bl[rb * 32 + ((lq ^ ((rb >> 1) & 3)) << 3)];
        }
        #pragma unroll
        for (int ri = 0; ri < 4; ri++)
            #pragma unroll
            for (int ci = 0; ci < 4; ci++)
                acc[ri][ci] = mfma16(af[ri], bf2[ci], acc[ri][ci]);
        __syncthreads();
    }
    #pragma unroll
    for (int ri = 0; ri < 4; ri++)
        #pragma unroll
        for (int ci = 0; ci < 4; ci++) {
            int row0 = m0 + wr + 16 * ri + (lane >> 4) * 4;   // i
            int col  = n0 + wc + 16 * ci + lr;                // s*32+d
            int s = col >> 5, dd = col & 31;
            #pragma unroll
            for (int r = 0; r < 4; r++)
                otb2[((size_t)s * NRES + row0 + r) * HC + h * DH + dd] = cvt_bf(acc[ri][ci][r]);
        }
}

// ---------------- K5: fused gate GEMM + sigmoid*o + out GEMM + residual -> mout ----------------
__global__ __launch_bounds__(256) void k_gateout(const ushort_t* __restrict__ A,   // mnb [NROWS][64]
                                                 const ushort_t* __restrict__ Bg,  // pgwb [256][64]
                                                 const ushort_t* __restrict__ otb2,// [NROWS][256]
                                                 const ushort_t* __restrict__ Bo,  // powb [64][256]
                                                 const float* __restrict__ m,
                                                 float* __restrict__ mout) {
    int m0 = blockIdx.x * 64;
    __shared__ ushort_t Al[64][72];
    __shared__ ushort_t Bl[64][72];
    __shared__ ushort_t go[64][264];
    int t = threadIdx.x;
    int srow = t >> 2, sko = (t & 3) * 16;
    int wave = t >> 6, lane = t & 63;
    int wr = (wave >> 1) * 32, wc = (wave & 1) * 32;
    int lk = (lane >> 4) * 8, lr = lane & 15;
    // stage full A tile [64][64]
    {
        const ushort_t* arow = &A[(size_t)(m0 + srow) * DM + sko];
        *(short8*)&Al[srow][sko]     = *(const short8*)&arow[0];
        *(short8*)&Al[srow][sko + 8] = *(const short8*)&arow[8];
    }
    __syncthreads();
    short8 a[2][2];   // [mi][ks]
    a[0][0] = *(const short8*)&Al[wr + lr][lk];
    a[0][1] = *(const short8*)&Al[wr + lr][32 + lk];
    a[1][0] = *(const short8*)&Al[wr + 16 + lr][lk];
    a[1][1] = *(const short8*)&Al[wr + 16 + lr][32 + lk];
    // ---- gate: 4 n-quarters of 64 ----
    for (int nq = 0; nq < 4; nq++) {
        __syncthreads();
        {
            const ushort_t* brow = &Bg[(size_t)(nq * 64 + srow) * DM + sko];
            *(short8*)&Bl[srow][sko]     = *(const short8*)&brow[0];
            *(short8*)&Bl[srow][sko + 8] = *(const short8*)&brow[8];
        }
        __syncthreads();
        f32x4 acc[2][2] = {};
        #pragma unroll
        for (int ks = 0; ks < 2; ks++) {
            short8 b0 = *(const short8*)&Bl[wc + lr][ks * 32 + lk];
            short8 b1 = *(const short8*)&Bl[wc + 16 + lr][ks * 32 + lk];
            acc[0][0] = mfma16(a[0][ks], b0, acc[0][0]);
            acc[0][1] = mfma16(a[0][ks], b1, acc[0][1]);
            acc[1][0] = mfma16(a[1][ks], b0, acc[1][0]);
            acc[1][1] = mfma16(a[1][ks], b1, acc[1][1]);
        }
        #pragma unroll
        for (int ri = 0; ri < 2; ri++)
            #pragma unroll
            for (int ci = 0; ci < 2; ci++) {
                int lrow = wr + 16 * ri + (lane >> 4) * 4;
                int col  = nq * 64 + wc + 16 * ci + lr;
                #pragma unroll
                for (int r = 0; r < 4; r++) {
                    float ov = cvt_f(otb2[(size_t)(m0 + lrow + r) * HC + col]);
                    go[lrow + r][col] = cvt_bf(sigm(acc[ri][ci][r]) * ov);
                }
            }
    }
    // ---- out GEMM: [64 rows][K=256] @ powb^T -> 64 cols, + residual ----
    f32x4 acc[2][2] = {};
    for (int k0 = 0; k0 < HC; k0 += 32) {
        __syncthreads();
        *(short8*)&Bl[t >> 2][(t & 3) * 8] = *(const short8*)&Bo[(size_t)(t >> 2) * HC + k0 + (t & 3) * 8];
        __syncthreads();
        short8 a0 = *(const short8*)&go[wr + lr][k0 + lk];
        short8 a1 = *(const short8*)&go[wr + 16 + lr][k0 + lk];
        short8 b0 = *(const short8*)&Bl[wc + lr][lk];
        short8 b1 = *(const short8*)&Bl[wc + 16 + lr][lk];
        acc[0][0] = mfma16(a0, b0, acc[0][0]);
        acc[0][1] = mfma16(a0, b1, acc[0][1]);
        acc[1][0] = mfma16(a1, b0, acc[1][0]);
        acc[1][1] = mfma16(a1, b1, acc[1][1]);
    }
    #pragma unroll
    for (int ri = 0; ri < 2; ri++)
        #pragma unroll
        for (int ci = 0; ci < 2; ci++) {
            int row0 = m0 + wr + 16 * ri + (lane >> 4) * 4;
            int col  = wc + 16 * ci + lr;
            #pragma unroll
            for (int r = 0; r < 4; r++) {
                size_t idx = (size_t)(row0 + r) * DM + col;
                mout[idx] = m[idx] + acc[ri][ci][r];
            }
        }
}

// ---------------- K6: fused SwiGLU transition (fc1/fc2 + silu*mul + fc3 + residual) ----------------
__global__ __launch_bounds__(256) void k_fctrans(const ushort_t* __restrict__ A,   // tn_bf [NROWS][64]
                                                 const ushort_t* __restrict__ B1,  // f1b [256][64]
                                                 const ushort_t* __restrict__ B2,  // f2b [256][64]
                                                 const ushort_t* __restrict__ B3,  // f3b [64][256]
                                                 float* __restrict__ mio) {
    int m0 = blockIdx.x * 64;
    __shared__ ushort_t Al[64][72];
    __shared__ ushort_t B1l[64][72];
    __shared__ ushort_t B2l[64][72];
    __shared__ ushort_t hhl[64][264];
    int t = threadIdx.x;
    int srow = t >> 2, sko = (t & 3) * 16;
    int wave = t >> 6, lane = t & 63;
    int wr = (wave >> 1) * 32, wc = (wave & 1) * 32;
    int lk = (lane >> 4) * 8, lr = lane & 15;
    {
        const ushort_t* arow = &A[(size_t)(m0 + srow) * DM + sko];
        *(short8*)&Al[srow][sko]     = *(const short8*)&arow[0];
        *(short8*)&Al[srow][sko + 8] = *(const short8*)&arow[8];
    }
    __syncthreads();
    short8 a[2][2];
    a[0][0] = *(const short8*)&Al[wr + lr][lk];
    a[0][1] = *(const short8*)&Al[wr + lr][32 + lk];
    a[1][0] = *(const short8*)&Al[wr + 16 + lr][lk];
    a[1][1] = *(const short8*)&Al[wr + 16 + lr][32 + lk];
    for (int nq = 0; nq < 4; nq++) {
        __syncthreads();
        {
            const ushort_t* b1r = &B1[(size_t)(nq * 64 + srow) * DM + sko];
            const ushort_t* b2r = &B2[(size_t)(nq * 64 + srow) * DM + sko];
            *(short8*)&B1l[srow][sko]     = *(const short8*)&b1r[0];
            *(short8*)&B1l[srow][sko + 8] = *(const short8*)&b1r[8];
            *(short8*)&B2l[srow][sko]     = *(const short8*)&b2r[0];
            *(short8*)&B2l[srow][sko + 8] = *(const short8*)&b2r[8];
        }
        __syncthreads();
        f32x4 acc1[2][2] = {}, acc2[2][2] = {};
        #pragma unroll
        for (int ks = 0; ks < 2; ks++) {
            short8 p0 = *(const short8*)&B1l[wc + lr][ks * 32 + lk];
            short8 p1 = *(const short8*)&B1l[wc + 16 + lr][ks * 32 + lk];
            short8 q0 = *(const short8*)&B2l[wc + lr][ks * 32 + lk];
            short8 q1 = *(const short8*)&B2l[wc + 16 + lr][ks * 32 + lk];
            acc1[0][0] = mfma16(a[0][ks], p0, acc1[0][0]);
            acc1[0][1] = mfma16(a[0][ks], p1, acc1[0][1]);
            acc1[1][0] = mfma16(a[1][ks], p0, acc1[1][0]);
            acc1[1][1] = mfma16(a[1][ks], p1, acc1[1][1]);
            acc2[0][0] = mfma16(a[0][ks], q0, acc2[0][0]);
            acc2[0][1] = mfma16(a[0][ks], q1, acc2[0][1]);
            acc2[1][0] = mfma16(a[1][ks], q0, acc2[1][0]);
            acc2[1][1] = mfma16(a[1][ks], q1, acc2[1][1]);
        }
        #pragma unroll
        for (int ri = 0; ri < 2; ri++)
            #pragma unroll
            for (int ci = 0; ci < 2; ci++) {
                int lrow = wr + 16 * ri + (lane >> 4) * 4;
                int col  = nq * 64 + wc + 16 * ci + lr;
                #pragma unroll
                for (int r = 0; r < 4; r++) {
                    float a1v = acc1[ri][ci][r], a2v = acc2[ri][ci][r];
                    hhl[lrow + r][col] = cvt_bf(a1v * sigm(a1v) * a2v);
                }
            }
    }
    // fc3: [64][256] @ f3b^T -> 64 cols, residual
    f32x4 acc[2][2] = {};
    for (int k0 = 0; k0 < FF; k0 += 32) {
        __syncthreads();
        *(short8*)&B1l[t >> 2][(t & 3) * 8] = *(const short8*)&B3[(size_t)(t >> 2) * FF + k0 + (t & 3) * 8];
        __syncthreads();
        short8 a0 = *(const short8*)&hhl[wr + lr][k0 + lk];
        short8 a1 = *(const short8*)&hhl[wr + 16 + lr][k0 + lk];
        short8 b0 = *(const short8*)&B1l[wc + lr][lk];
        short8 b1 = *(const short8*)&B1l[wc + 16 + lr][lk];
        acc[0][0] = mfma16(a0, b0, acc[0][0]);
        acc[0][1] = mfma16(a0, b1, acc[0][1]);
        acc[1][0] = mfma16(a1, b0, acc[1][0]);
        acc[1][1] = mfma16(a1, b1, acc[1][1]);
    }
    #pragma unroll
    for (int ri = 0; ri < 2; ri++)
        #pragma unroll
        for (int ci = 0; ci < 2; ci++) {
            int row0 = m0 + wr + 16 * ri + (lane >> 4) * 4;
            int col  = wc + 16 * ci + lr;
            #pragma unroll
            for (int r = 0; r < 4; r++)
                mio[(size_t)(row0 + r) * DM + col] += acc[ri][ci][r];
        }
}

// ---------------- K7: a/b projection GEMM + mask -> abuf/bbuf [s][n*32+c] ----------------
__global__ __launch_bounds__(256) void k_ab_mfma(const ushort_t* __restrict__ A,
                                                 const ushort_t* __restrict__ Bt,
                                                 const float* __restrict__ smask,
                                                 ushort_t* __restrict__ abuf,
                                                 ushort_t* __restrict__ bbuf) {
    int m0 = blockIdx.x * 64;
    __shared__ ushort_t Al[64][40];
    __shared__ ushort_t Bl[64][40];
    int t = threadIdx.x;
    int srow = t >> 2, sko = (t & 3) * 8;
    int wave = t >> 6, lane = t & 63;
    int wr = (wave >> 1) * 32, wc = (wave & 1) * 32;
    int lk = (lane >> 4) * 8, lr = lane & 15;
    f32x4 acc[2][2] = {};
    for (int k0 = 0; k0 < DM; k0 += 32) {
        *(short8*)&Al[srow][sko] = *(const short8*)&A[(size_t)(m0 + srow) * DM + k0 + sko];
        *(short8*)&Bl[srow][sko] = *(const short8*)&Bt[(size_t)srow * DM + k0 + sko];
        __syncthreads();
        short8 a0 = *(const short8*)&Al[wr + lr][lk];
        short8 a1 = *(const short8*)&Al[wr + 16 + lr][lk];
        short8 b0 = *(const short8*)&Bl[wc + lr][lk];
        short8 b1 = *(const short8*)&Bl[wc + 16 + lr][lk];
        acc[0][0] = mfma16(a0, b0, acc[0][0]);
        acc[0][1] = mfma16(a0, b1, acc[0][1]);
        acc[1][0] = mfma16(a1, b0, acc[1][0]);
        acc[1][1] = mfma16(a1, b1, acc[1][1]);
        __syncthreads();
    }
    #pragma unroll
    for (int ri = 0; ri < 2; ri++)
        #pragma unroll
        for (int ci = 0; ci < 2; ci++) {
            int row0 = m0 + wr + 16 * ri + (lane >> 4) * 4;
            int col  = wc + 16 * ci + lr;               // 0..63
            #pragma unroll
            for (int r = 0; r < 4; r++) {
                int rr = row0 + r;                      // s*NRES+n
                int s = rr / NRES, n = rr % NRES;
                float v = acc[ri][ci][r] * smask[rr];
                if (col < DOP)
                    abuf[(size_t)s * (NRES * DOP) + n * DOP + col] = cvt_bf(v);
                else
                    bbuf[(size_t)s * (NRES * DOP) + n * DOP + (col - DOP)] = cvt_bf(v);
            }
        }
}

// ---------------- K8: mask pair-count Gram tile ----------------
__global__ __launch_bounds__(256) void k_msum(const float* __restrict__ smask,
                                              float* __restrict__ msum) {
    int i0 = blockIdx.y * 64, j0 = blockIdx.x * 64;
    __shared__ float As[16][64];
    __shared__ float Bs[16][64];
    int t = threadIdx.x;
    int ty = t >> 4, tx = t & 15;
    float acc[4][4] = {};
    for (int k0 = 0; k0 < NSEQ; k0 += 16) {
        int kk = t >> 4, x4 = (t & 15) * 4;
        *(float4*)&As[kk][x4] = *(const float4*)&smask[(size_t)(k0 + kk) * NRES + i0 + x4];
        *(float4*)&Bs[kk][x4] = *(const float4*)&smask[(size_t)(k0 + kk) * NRES + j0 + x4];
        __syncthreads();
        #pragma unroll
        for (int k = 0; k < 16; k++) {
            float4 a4 = *(const float4*)&As[k][ty * 4];
            float4 b4 = *(const float4*)&Bs[k][tx * 4];
            float ar[4] = {a4.x, a4.y, a4.z, a4.w};
            float br[4] = {b4.x, b4.y, b4.z, b4.w};
            #pragma unroll
            for (int i2 = 0; i2 < 4; i2++)
                #pragma unroll
                for (int j2 = 0; j2 < 4; j2++)
                    acc[i2][j2] += ar[i2] * br[j2];
        }
        __syncthreads();
    }
    #pragma unroll
    for (int r = 0; r < 4; r++) {
        float4 o4 = make_float4(fmaxf(acc[r][0], 1.0f), fmaxf(acc[r][1], 1.0f),
                                fmaxf(acc[r][2], 1.0f), fmaxf(acc[r][3], 1.0f));
        *(float4*)&msum[(size_t)(i0 + ty * 4 + r) * NRES + j0 + tx * 4] = o4;
    }
}

// ---------------- K9: OPM outer GEMM (128x128 tile, gload_lds) ----------------
__global__ __launch_bounds__(256) void k_opm_mfma(const ushort_t* __restrict__ At,
                                                  const ushort_t* __restrict__ Bt,
                                                  ushort_t* __restrict__ opmc) {
    int m0 = blockIdx.y * 128;                  // over ICHUNK*32 (il,c)
    int n0 = blockIdx.x * 128;                  // over 12288 (j,d)
    __shared__ ushort_t Al[128 * 32];
    __shared__ ushort_t Bl[128 * 32];
    int t = threadIdx.x;
    int w = t >> 6, lane = t & 63;
    int wr = (w >> 1) * 64, wc = (w & 1) * 64;
    int lq = lane >> 4, lr = lane & 15;
    int rS = w * 16 + (lane >> 2);
    int cqs = (((lane & 3) ^ ((rS >> 1) & 3)) << 3);
    f32x4 acc[4][4] = {};
    for (int k0 = 0; k0 < NSEQ; k0 += 32) {
        gld16(&At[(size_t)(m0 + rS)      * NSEQ + k0 + cqs], &Al[(w * 16) * 32]);
        gld16(&At[(size_t)(m0 + 64 + rS) * NSEQ + k0 + cqs], &Al[(64 + w * 16) * 32]);
        gld16(&Bt[(size_t)(n0 + rS)      * NSEQ + k0 + cqs], &Bl[(w * 16) * 32]);
        gld16(&Bt[(size_t)(n0 + 64 + rS) * NSEQ + k0 + cqs], &Bl[(64 + w * 16) * 32]);
        __syncthreads();
        short8 af[4], bf2[4];
        #pragma unroll
        for (int i = 0; i < 4; i++) {
            int ra = wr + 16 * i + lr;
            int rb = wc + 16 * i + lr;
            af[i]  = *(const short8*)&Al[ra * 32 + ((lq ^ ((ra >> 1) & 3)) << 3)];
            bf2[i] = *(const short8*)&Bl[rb * 32 + ((lq ^ ((rb >> 1) & 3)) << 3)];
        }
        #pragma unroll
        for (int ri = 0; ri < 4; ri++)
            #pragma unroll
            for (int ci = 0; ci < 4; ci++)
                acc[ri][ci] = mfma16(af[ri], bf2[ci], acc[ri][ci]);
        __syncthreads();
    }
    #pragma unroll
    for (int ri = 0; ri < 4; ri++)
        #pragma unroll
        for (int ci = 0; ci < 4; ci++) {
            int mb = m0 + wr + 16 * ri + (lane >> 4) * 4;
            int n  = n0 + wc + 16 * ci + lr;
            int j = n >> 5, dd = n & 31;
            #pragma unroll
            for (int r = 0; r < 4; r++) {
                int mm = mb + r;
                int il = mm >> 5, c = mm & 31;
                opmc[((size_t)(il * NRES + j) << 10) + (c << 5) + dd] = cvt_bf(acc[ri][ci][r]);
            }
        }
}

// ---------------- K10: OPM projection + residual (128x128 tile, gload_lds) ----------------
__global__ __launch_bounds__(256) void k_proj_mfma(const ushort_t* __restrict__ A,
                                                   const ushort_t* __restrict__ Bt,
                                                   const float* __restrict__ opB,
                                                   const float* __restrict__ msum,
                                                   const float* __restrict__ zin,
                                                   float* __restrict__ zout,
                                                   int ib) {
    int m0 = blockIdx.x * 128;                  // over ICHUNK*NRES
    __shared__ ushort_t Al[128 * 32];
    __shared__ ushort_t Bl[128 * 32];
    int t = threadIdx.x;
    int w = t >> 6, lane = t & 63;
    int wr = (w >> 1) * 64, wc = (w & 1) * 64;
    int lq = lane >> 4, lr = lane & 15;
    int rS = w * 16 + (lane >> 2);
    int cqs = (((lane & 3) ^ ((rS >> 1) & 3)) << 3);
    f32x4 acc[4][4] = {};
    for (int k0 = 0; k0 < 1024; k0 += 32) {
        gld16(&A [(size_t)(m0 + rS)      * 1024 + k0 + cqs], &Al[(w * 16) * 32]);
        gld16(&A [(size_t)(m0 + 64 + rS) * 1024 + k0 + cqs], &Al[(64 + w * 16) * 32]);
        gld16(&Bt[(size_t)(rS)           * 1024 + k0 + cqs], &Bl[(w * 16) * 32]);
        gld16(&Bt[(size_t)(64 + rS)      * 1024 + k0 + cqs], &Bl[(64 + w * 16) * 32]);
        __syncthreads();
        short8 af[4], bf2[4];
        #pragma unroll
        for (int i = 0; i < 4; i++) {
            int ra = wr + 16 * i + lr;
            int rb = wc + 16 * i + lr;
            af[i]  = *(const short8*)&Al[ra * 32 + ((lq ^ ((ra >> 1) & 3)) << 3)];
            bf2[i] = *(const short8*)&Bl[rb * 32 + ((lq ^ ((rb >> 1) & 3)) << 3)];
        }
        #pragma unroll
        for (int ri = 0; ri < 4; ri++)
            #pragma unroll
            for (int ci = 0; ci < 4; ci++)
                acc[ri][ci] = mfma16(af[ri], bf2[ci], acc[ri][ci]);
        __syncthreads();
    }
    #pragma unroll
    for (int ri = 0; ri < 4; ri++)
        #pragma unroll
        for (int ci = 0; ci < 4; ci++) {
            int row0 = m0 + wr + 16 * ri + (lane >> 4) * 4;
            int col  = wc + 16 * ci + lr;               // 0..127 = full DZ
            #pragma unroll
            for (int r = 0; r < 4; r++) {
                size_t G = (size_t)ib * NRES + row0 + r;
                float inv = 1.0f / msum[G];
                zout[G * DZ + col] = zin[G * DZ + col] + acc[ri][ci][r] * inv + opB[col];
            }
        }
}

// ---------------- launch ----------------
extern "C" void kernel_launch(void* const* d_in, const int* in_sizes, int n_in,
                              void* d_out, int out_size, void* d_ws, size_t ws_size,
                              hipStream_t stream) {
    const float* z     = (const float*)d_in[0];
    const float* m     = (const float*)d_in[1];
    const float* tmask = (const float*)d_in[2];
    const float* smask = (const float*)d_in[3];
    const float* nzw   = (const float*)d_in[4];
    const float* nzb   = (const float*)d_in[5];
    const float* pzw   = (const float*)d_in[6];
    const float* nmw   = (const float*)d_in[7];
    const float* nmb   = (const float*)d_in[8];
    const float* pmw   = (const float*)d_in[9];
    const float* pgw   = (const float*)d_in[10];
    const float* pow_  = (const float*)d_in[11];
    const float* tnw   = (const float*)d_in[12];
    const float* tnb_  = (const float*)d_in[13];
    const float* f1    = (const float*)d_in[14];
    const float* f2    = (const float*)d_in[15];
    const float* f3    = (const float*)d_in[16];
    const float* onw   = (const float*)d_in[17];
    const float* onb   = (const float*)d_in[18];
    const float* paw   = (const float*)d_in[19];
    const float* pbw   = (const float*)d_in[20];
    const float* opW   = (const float*)d_in[21];
    const float* opB   = (const float*)d_in[22];

    float* zout = (float*)d_out;
    float* mout = zout + ZTOT;

    char* W = (char*)d_ws;
    ushort_t* wsb  = (ushort_t*)(W + 4718592);          //  .. 7,077,888 (bf16 softmax wts)
    ushort_t* mnb  = (ushort_t*)(W + 7077888);          //  .. 19,660,800 (12.6MB)
    ushort_t* vtR  = (ushort_t*)(W + 19660800);         //  .. 69,992,448 (50.3MB, multi-use)
    ushort_t* vtt  = (ushort_t*)(W + 69992448);         //  .. 120,324,096 (50.3MB)
    ushort_t* otb2 = (ushort_t*)(W + 120324096);        //  .. 170,655,744 (50.3MB)
    float*    msum = (float*)(W + 170655744);           //  .. 171,245,568
    ushort_t* f1b  = (ushort_t*)(W + 171245568);
    ushort_t* f2b  = (ushort_t*)(W + 171278336);
    ushort_t* f3b  = (ushort_t*)(W + 171311104);
    ushort_t* opWb = (ushort_t*)(W + 171343872);        //  .. 171,606,016
    ushort_t* pmwb = (ushort_t*)(W + 171606016);
    ushort_t* pgwb = (ushort_t*)(W + 171638784);
    ushort_t* powb = (ushort_t*)(W + 171671552);        //  .. 171,704,320
    ushort_t* abwb = (ushort_t*)(W + 171704320);        //  .. 171,712,512 (8KB)
    ushort_t* pzwb = (ushort_t*)(W + 171712512);        //  .. 171,716,608 (4KB)
    // region aliases (dead-by-then):
    ushort_t* tn_bf = vtt;                  // vtt dead after k_attn_mfma
    ushort_t* onb_bf = mnb;                 // mnb dead after k_gateout
    ushort_t* abuf = (ushort_t*)(W + 69992448 + 12582912);   // vtt+12.6MB
    ushort_t* bbuf = (ushort_t*)(W + 69992448 + 18874368);   // vtt+18.9MB
    ushort_t* abt  = otb2;                  // otb2 dead after k_gateout
    ushort_t* bbt  = (ushort_t*)(W + 120324096 + 6291456);
    ushort_t* opmc = vtR;                   // vtR free at OPM time (needs 75.5MB < 100.6MB span)

    k_prep<<<512, 256, 0, stream>>>(f1, f2, f3, opW, pmw, pgw, pow_, paw, pbw, pzw,
                                    f1b, f2b, f3b, opWb, pmwb, pgwb, powb, abwb, pzwb);

    // PairWeightedAveraging
    k_biassm<<<NRES, 256, 0, stream>>>(z, nzw, nzb, pzwb, tmask, wsb);
    k_ln64<<<NROWS / 4, 256, 0, stream>>>(m, nmw, nmb, mnb);
    k_vproj_mfma<<<dim3(HC / 64, NROWS / 64), 256, 0, stream>>>(mnb, pmwb, vtt);
    k_attn_mfma<<<dim3(SD / 128, NRES / 128, NH), 256, 0, stream>>>(wsb, vtt, otb2);
    k_gateout<<<NROWS / 64, 256, 0, stream>>>(mnb, pgwb, otb2, powb, m, mout);

    // Transition (fused)
    k_ln64<<<NROWS / 4, 256, 0, stream>>>(mout, tnw, tnb_, tn_bf);
    k_fctrans<<<NROWS / 64, 256, 0, stream>>>(tn_bf, f1b, f2b, f3b, mout);

    // OuterProductMean
    k_ln64<<<NROWS / 4, 256, 0, stream>>>(mout, onw, onb, onb_bf);
    k_ab_mfma<<<NROWS / 64, 256, 0, stream>>>(onb_bf, abwb, smask, abuf, bbuf);
    k_tr<<<dim3((NRES * DOP) / 64, NSEQ / 64, 2), 256, 0, stream>>>(abuf, abt, NSEQ, NRES * DOP);
    k_msum<<<dim3(NRES / 64, NRES / 64), 256, 0, stream>>>(smask, msum);
    for (int cb = 0; cb < NRES / ICHUNK; cb++) {
        int ib = cb * ICHUNK;
        const ushort_t* Achunk = abt + (size_t)(ib * DOP) * NSEQ;
        k_opm_mfma<<<dim3((NRES * DOP) / 128, (ICHUNK * DOP) / 128), 256, 0, stream>>>(Achunk, bbt, opmc);
        k_proj_mfma<<<(ICHUNK * NRES) / 128, 256, 0, stream>>>(opmc, opWb, opB, msum, z, zout, ib);
    }
}

// Round 12
// 479.376 us; speedup vs baseline: 13.9967x; 1.0428x over previous
//
#include <hip/hip_runtime.h>
#include <math.h>

// ---------------- problem constants ----------------
constexpr int NRES = 384;          // N
constexpr int NSEQ = 256;          // S
constexpr int DM   = 64;           // MSA_S
constexpr int DZ   = 128;          // Z_D
constexpr int NH   = 8;            // H
constexpr int DH   = 32;           // C_H
constexpr int HC   = NH * DH;      // 256
constexpr int DOP  = 32;           // C_OPM
constexpr int FF   = 4 * DM;       // 256

constexpr int NPAIR = NRES * NRES;         // 147456
constexpr int NROWS = NSEQ * NRES;         // 98304
constexpr int ZTOT  = NPAIR * DZ;          // 18874368
constexpr int SD    = NSEQ * DH;           // 8192

typedef unsigned short ushort_t;
typedef __attribute__((ext_vector_type(8))) short short8;
typedef __attribute__((ext_vector_type(4))) float f32x4;

__device__ __forceinline__ float wred_sum(float v) {
    #pragma unroll
    for (int off = 32; off; off >>= 1) v += __shfl_xor(v, off, 64);
    return v;
}
__device__ __forceinline__ float sigm(float x) { return 1.0f / (1.0f + expf(-x)); }
__device__ __forceinline__ ushort_t cvt_bf(float f) {
    unsigned u = __float_as_uint(f);
    unsigned r = (u + 0x7FFFu + ((u >> 16) & 1u)) >> 16;
    return (ushort_t)r;
}
__device__ __forceinline__ float cvt_f(ushort_t h) {
    return __uint_as_float(((unsigned)h) << 16);
}
__device__ __forceinline__ f32x4 mfma16(short8 a, short8 b, f32x4 c) {
    return __builtin_amdgcn_mfma_f32_16x16x32_bf16(a, b, c, 0, 0, 0);
}
// async global->LDS, 16B per lane; LDS dest = wave-uniform base + lane*16
__device__ __forceinline__ void gld16(const ushort_t* g, ushort_t* l) {
    __builtin_amdgcn_global_load_lds(
        (const __attribute__((address_space(1))) unsigned int*)g,
        (__attribute__((address_space(3))) unsigned int*)l, 16, 0, 0);
}

// ---------------- K0: weights -> bf16 ----------------
__global__ __launch_bounds__(256) void k_prep(const float* __restrict__ f1,
                                              const float* __restrict__ f2,
                                              const float* __restrict__ f3,
                                              const float* __restrict__ opW,
                                              const float* __restrict__ pmw,
                                              const float* __restrict__ pgw,
                                              const float* __restrict__ pow_,
                                              const float* __restrict__ paw,
                                              const float* __restrict__ pbw,
                                              const float* __restrict__ pzw,
                                              ushort_t* __restrict__ f1b,
                                              ushort_t* __restrict__ f2b,
                                              ushort_t* __restrict__ f3b,
                                              ushort_t* __restrict__ opWb,
                                              ushort_t* __restrict__ pmwb,
                                              ushort_t* __restrict__ pgwb,
                                              ushort_t* __restrict__ powb,
                                              ushort_t* __restrict__ abwb,
                                              ushort_t* __restrict__ pzwb) {
    int i = blockIdx.x * 256 + threadIdx.x;      // 131072 threads
    opWb[i] = cvt_bf(opW[i]);
    if (i < FF * DM) {
        f1b[i] = cvt_bf(f1[i]);
        f2b[i] = cvt_bf(f2[i]);
        f3b[i] = cvt_bf(f3[i]);
    }
    if (i < HC * DM) {
        pmwb[i] = cvt_bf(pmw[i]);
        pgwb[i] = cvt_bf(pgw[i]);
        powb[i] = cvt_bf(pow_[i]);
    }
    if (i < 2 * DOP * DM) {                      // combined [64][64]: rows 0..31 paw, 32..63 pbw
        abwb[i] = cvt_bf(i < DOP * DM ? paw[i] : pbw[i - DOP * DM]);
    }
    if (i < 16 * DZ) {                           // [16][128]: rows 0..7 pzw, rows 8..15 zero
        pzwb[i] = (i < NH * DZ) ? cvt_bf(pzw[i]) : (ushort_t)0;
    }
}

// ---------------- K1: fused LN(z) + bias proj + mask + softmax -> wsb (one block per i) ----------------
__global__ __launch_bounds__(256) void k_biassm(const float* __restrict__ z,
                                                const float* __restrict__ nzw,
                                                const float* __restrict__ nzb,
                                                const ushort_t* __restrict__ pzwb,
                                                const float* __restrict__ tmask,
                                                ushort_t* __restrict__ wsb) {
    int i = blockIdx.x;                         // 0..383
    __shared__ ushort_t Azl[128][136];
    __shared__ ushort_t Bl[16][136];
    __shared__ float ob[8][388];
    __shared__ float wln[128], bln[128];
    int t = threadIdx.x;
    if (t < 128) { wln[t] = nzw[t]; bln[t] = nzb[t]; }
    int wave = t >> 6, lane = t & 63;
    int lk = (lane >> 4) * 8, lr = lane & 15;
    int wr = wave * 32;
    // stage B once
    for (int idx = t * 8; idx < 16 * DZ; idx += 256 * 8) {
        int row = idx >> 7, col = idx & 127;
        *(short8*)&Bl[row][col] = *(const short8*)&pzwb[idx];
    }
    __syncthreads();
    for (int c = 0; c < 3; c++) {
        // stage A chunk with fused LN: rows j = c*128 .. +127; 2 threads per row
        {
            int jl = t >> 1, cb = (t & 1) * 64;
            const float* src = &z[((size_t)i * NRES + c * 128 + jl) * DZ + cb];
            float4 v[16];
            float s1 = 0.0f, s2 = 0.0f;
            #pragma unroll
            for (int q = 0; q < 16; q++) {
                v[q] = *(const float4*)&src[q * 4];
                s1 += v[q].x + v[q].y + v[q].z + v[q].w;
                s2 += v[q].x * v[q].x + v[q].y * v[q].y + v[q].z * v[q].z + v[q].w * v[q].w;
            }
            s1 += __shfl_xor(s1, 1, 64);
            s2 += __shfl_xor(s2, 1, 64);
            float mu = s1 * (1.0f / 128.0f);
            float var = s2 * (1.0f / 128.0f) - mu * mu;
            float rs = rsqrtf(var + 1e-5f);
            #pragma unroll
            for (int q = 0; q < 8; q++) {
                float4 xa = v[2 * q], xb = v[2 * q + 1];
                int base = cb + q * 8;
                short8 o;
                o[0] = (short)cvt_bf((xa.x - mu) * rs * wln[base + 0] + bln[base + 0]);
                o[1] = (short)cvt_bf((xa.y - mu) * rs * wln[base + 1] + bln[base + 1]);
                o[2] = (short)cvt_bf((xa.z - mu) * rs * wln[base + 2] + bln[base + 2]);
                o[3] = (short)cvt_bf((xa.w - mu) * rs * wln[base + 3] + bln[base + 3]);
                o[4] = (short)cvt_bf((xb.x - mu) * rs * wln[base + 4] + bln[base + 4]);
                o[5] = (short)cvt_bf((xb.y - mu) * rs * wln[base + 5] + bln[base + 5]);
                o[6] = (short)cvt_bf((xb.z - mu) * rs * wln[base + 6] + bln[base + 6]);
                o[7] = (short)cvt_bf((xb.w - mu) * rs * wln[base + 7] + bln[base + 7]);
                *(short8*)&Azl[jl][base] = o;
            }
        }
        __syncthreads();
        f32x4 acc[2] = {};
        #pragma unroll
        for (int ks = 0; ks < 4; ks++) {
            short8 b = *(const short8*)&Bl[lr][ks * 32 + lk];
            short8 a0 = *(const short8*)&Azl[wr + lr][ks * 32 + lk];
            short8 a1 = *(const short8*)&Azl[wr + 16 + lr][ks * 32 + lk];
            acc[0] = mfma16(a0, b, acc[0]);
            acc[1] = mfma16(a1, b, acc[1]);
        }
        if (lr < NH) {
            #pragma unroll
            for (int ri = 0; ri < 2; ri++) {
                int jb = c * 128 + wr + 16 * ri + (lane >> 4) * 4;
                #pragma unroll
                for (int r = 0; r < 4; r++)
                    ob[lr][jb + r] = acc[ri][r];
            }
        }
        __syncthreads();
    }
    // softmax over j per head (half-wave = one head)
    int h = wave * 2 + (lane >> 5);
    int l32 = lane & 31;
    int jb = l32 * 12;
    const float* tm = &tmask[(size_t)i * NRES];
    float vals[12];
    float mx = -1e30f;
    #pragma unroll
    for (int q = 0; q < 12; q++) {
        float v = ob[h][jb + q] + (1.0f - tm[jb + q]) * (-1e9f);
        vals[q] = v;
        mx = fmaxf(mx, v);
    }
    #pragma unroll
    for (int off = 16; off; off >>= 1) mx = fmaxf(mx, __shfl_xor(mx, off, 64));
    float sum = 0.0f;
    #pragma unroll
    for (int q = 0; q < 12; q++) { vals[q] = expf(vals[q] - mx); sum += vals[q]; }
    #pragma unroll
    for (int off = 16; off; off >>= 1) sum += __shfl_xor(sum, off, 64);
    float inv = 1.0f / sum;
    ushort_t* o = &wsb[(size_t)h * NPAIR + (size_t)i * NRES + jb];
    #pragma unroll
    for (int q = 0; q < 12; q++) o[q] = cvt_bf(vals[q] * inv);
}

// ---------------- K3: LN rows (64-wide) fp32 -> bf16 ----------------
__global__ __launch_bounds__(256) void k_ln64(const float* __restrict__ src,
                                              const float* __restrict__ lw,
                                              const float* __restrict__ lb,
                                              ushort_t* __restrict__ dst) {
    int wave = threadIdx.x >> 6, lane = threadIdx.x & 63;
    int r = blockIdx.x * 4 + wave;
    float x = src[(size_t)r * DM + lane];
    float mu = wred_sum(x) * (1.0f / 64.0f);
    float d = x - mu;
    float var = wred_sum(d * d) * (1.0f / 64.0f);
    dst[(size_t)r * DM + lane] = cvt_bf(d * rsqrtf(var + 1e-5f) * lw[lane] + lb[lane]);
}

// ---------------- K3b: v projection GEMM -> vtt[h][s*32+d][n] directly ----------------
__global__ __launch_bounds__(256) void k_vproj_mfma(const ushort_t* __restrict__ A,
                                                    const ushort_t* __restrict__ Bt,
                                                    ushort_t* __restrict__ vtt) {
    int m0 = blockIdx.y * 64, n0c = blockIdx.x * 64;
    __shared__ ushort_t Al[64][40];
    __shared__ ushort_t Bl[64][40];
    __shared__ ushort_t ot[64][72];
    int t = threadIdx.x;
    int srow = t >> 2, sko = (t & 3) * 8;
    int wave = t >> 6, lane = t & 63;
    int wr = (wave >> 1) * 32, wc = (wave & 1) * 32;
    int lk = (lane >> 4) * 8, lr = lane & 15;
    f32x4 acc[2][2] = {};
    for (int k0 = 0; k0 < DM; k0 += 32) {
        *(short8*)&Al[srow][sko] = *(const short8*)&A[(size_t)(m0 + srow) * DM + k0 + sko];
        *(short8*)&Bl[srow][sko] = *(const short8*)&Bt[(size_t)(n0c + srow) * DM + k0 + sko];
        __syncthreads();
        short8 a0 = *(const short8*)&Al[wr + lr][lk];
        short8 a1 = *(const short8*)&Al[wr + 16 + lr][lk];
        short8 b0 = *(const short8*)&Bl[wc + lr][lk];
        short8 b1 = *(const short8*)&Bl[wc + 16 + lr][lk];
        acc[0][0] = mfma16(a0, b0, acc[0][0]);
        acc[0][1] = mfma16(a0, b1, acc[0][1]);
        acc[1][0] = mfma16(a1, b0, acc[1][0]);
        acc[1][1] = mfma16(a1, b1, acc[1][1]);
        __syncthreads();
    }
    // transpose in LDS: ot[col][row]
    #pragma unroll
    for (int ri = 0; ri < 2; ri++)
        #pragma unroll
        for (int ci = 0; ci < 2; ci++) {
            int rowb = wr + 16 * ri + (lane >> 4) * 4;
            int colb = wc + 16 * ci + lr;
            #pragma unroll
            for (int r = 0; r < 4; r++)
                ot[colb][rowb + r] = cvt_bf(acc[ri][ci][r]);
        }
    __syncthreads();
    int s = m0 / NRES, n0 = m0 % NRES;
    int h0 = n0c >> 5;                          // two heads h0, h0+1
    int orow = t >> 2, seg = (t & 3) * 16;
    short8 v0 = *(const short8*)&ot[orow][seg];
    short8 v1 = *(const short8*)&ot[orow][seg + 8];
    int hh = orow >> 5, dd = orow & 31;
    ushort_t* dst = &vtt[(((size_t)(h0 + hh) * SD) + s * DH + dd) * NRES + n0 + seg];
    *(short8*)&dst[0] = v0;
    *(short8*)&dst[8] = v1;
}

// ---------------- generic 64x64 bf16 transpose ----------------
__global__ __launch_bounds__(256) void k_tr(const ushort_t* __restrict__ src,
                                            ushort_t* __restrict__ dst,
                                            int R, int C) {
    size_t bs = (size_t)R * C;
    const ushort_t* s = src + blockIdx.z * bs;
    ushort_t* d = dst + blockIdx.z * bs;
    int r0 = blockIdx.y * 64, c0 = blockIdx.x * 64;
    __shared__ ushort_t tile[64][72];
    int t = threadIdx.x;
    int tr = t >> 2, tc = (t & 3) * 16;
    *(short8*)&tile[tr][tc]     = *(const short8*)&s[(size_t)(r0 + tr) * C + c0 + tc];
    *(short8*)&tile[tr][tc + 8] = *(const short8*)&s[(size_t)(r0 + tr) * C + c0 + tc + 8];
    __syncthreads();
    short8 o0, o1;
    #pragma unroll
    for (int i = 0; i < 8; i++) {
        o0[i] = (short)tile[tc + i][tr];
        o1[i] = (short)tile[tc + 8 + i][tr];
    }
    *(short8*)&d[(size_t)(c0 + tr) * R + r0 + tc]     = o0;
    *(short8*)&d[(size_t)(c0 + tr) * R + r0 + tc + 8] = o1;
}

// ---------------- K4: attention GEMM per head (128x128 tile, gload_lds) ----------------
__global__ __launch_bounds__(256) void k_attn_mfma(const ushort_t* __restrict__ wsb,
                                                   const ushort_t* __restrict__ vtt,
                                                   ushort_t* __restrict__ otb2) {
    int h = blockIdx.z;
    const ushort_t* A  = wsb + (size_t)h * NPAIR;        // [384][384]
    const ushort_t* Bt = vtt + (size_t)h * SD * NRES;    // [8192][384]
    int m0 = blockIdx.y * 128, n0 = blockIdx.x * 128;
    __shared__ ushort_t Al[128 * 32];
    __shared__ ushort_t Bl[128 * 32];
    int t = threadIdx.x;
    int w = t >> 6, lane = t & 63;
    int wr = (w >> 1) * 64, wc = (w & 1) * 64;
    int lq = lane >> 4, lr = lane & 15;
    int rS = w * 16 + (lane >> 2);              // staging row within 64-row half
    int cqs = (((lane & 3) ^ ((rS >> 1) & 3)) << 3);   // swizzled source quad (ushorts)
    f32x4 acc[4][4] = {};
    for (int k0 = 0; k0 < NRES; k0 += 32) {
        gld16(&A [(size_t)(m0 + rS)      * NRES + k0 + cqs], &Al[(w * 16) * 32]);
        gld16(&A [(size_t)(m0 + 64 + rS) * NRES + k0 + cqs], &Al[(64 + w * 16) * 32]);
        gld16(&Bt[(size_t)(n0 + rS)      * NRES + k0 + cqs], &Bl[(w * 16) * 32]);
        gld16(&Bt[(size_t)(n0 + 64 + rS) * NRES + k0 + cqs], &Bl[(64 + w * 16) * 32]);
        __syncthreads();
        short8 af[4], bf2[4];
        #pragma unroll
        for (int i = 0; i < 4; i++) {
            int ra = wr + 16 * i + lr;
            int rb = wc + 16 * i + lr;
            af[i]  = *(const short8*)&Al[ra * 32 + ((lq ^ ((ra >> 1) & 3)) << 3)];
            bf2[i] = *(const short8*)&Bl[rb * 32 + ((lq ^ ((rb >> 1) & 3)) << 3)];
        }
        #pragma unroll
        for (int ri = 0; ri < 4; ri++)
            #pragma unroll
            for (int ci = 0; ci < 4; ci++)
                acc[ri][ci] = mfma16(af[ri], bf2[ci], acc[ri][ci]);
        __syncthreads();
    }
    #pragma unroll
    for (int ri = 0; ri < 4; ri++)
        #pragma unroll
        for (int ci = 0; ci < 4; ci++) {
            int row0 = m0 + wr + 16 * ri + (lane >> 4) * 4;   // i
            int col  = n0 + wc + 16 * ci + lr;                // s*32+d
            int s = col >> 5, dd = col & 31;
            #pragma unroll
            for (int r = 0; r < 4; r++)
                otb2[((size_t)s * NRES + row0 + r) * HC + h * DH + dd] = cvt_bf(acc[ri][ci][r]);
        }
}

// ---------------- K5: fused gate GEMM + sigmoid*o + out GEMM + residual -> mout ----------------
__global__ __launch_bounds__(256) void k_gateout(const ushort_t* __restrict__ A,   // mnb [NROWS][64]
                                                 const ushort_t* __restrict__ Bg,  // pgwb [256][64]
                                                 const ushort_t* __restrict__ otb2,// [NROWS][256]
                                                 const ushort_t* __restrict__ Bo,  // powb [64][256]
                                                 const float* __restrict__ m,
                                                 float* __restrict__ mout) {
    int m0 = blockIdx.x * 64;
    __shared__ ushort_t Al[64][72];
    __shared__ ushort_t Bl[64][72];
    __shared__ ushort_t go[64][264];
    int t = threadIdx.x;
    int srow = t >> 2, sko = (t & 3) * 16;
    int wave = t >> 6, lane = t & 63;
    int wr = (wave >> 1) * 32, wc = (wave & 1) * 32;
    int lk = (lane >> 4) * 8, lr = lane & 15;
    // stage full A tile [64][64]
    {
        const ushort_t* arow = &A[(size_t)(m0 + srow) * DM + sko];
        *(short8*)&Al[srow][sko]     = *(const short8*)&arow[0];
        *(short8*)&Al[srow][sko + 8] = *(const short8*)&arow[8];
    }
    __syncthreads();
    short8 a[2][2];   // [mi][ks]
    a[0][0] = *(const short8*)&Al[wr + lr][lk];
    a[0][1] = *(const short8*)&Al[wr + lr][32 + lk];
    a[1][0] = *(const short8*)&Al[wr + 16 + lr][lk];
    a[1][1] = *(const short8*)&Al[wr + 16 + lr][32 + lk];
    // ---- gate: 4 n-quarters of 64 ----
    for (int nq = 0; nq < 4; nq++) {
        __syncthreads();
        {
            const ushort_t* brow = &Bg[(size_t)(nq * 64 + srow) * DM + sko];
            *(short8*)&Bl[srow][sko]     = *(const short8*)&brow[0];
            *(short8*)&Bl[srow][sko + 8] = *(const short8*)&brow[8];
        }
        __syncthreads();
        f32x4 acc[2][2] = {};
        #pragma unroll
        for (int ks = 0; ks < 2; ks++) {
            short8 b0 = *(const short8*)&Bl[wc + lr][ks * 32 + lk];
            short8 b1 = *(const short8*)&Bl[wc + 16 + lr][ks * 32 + lk];
            acc[0][0] = mfma16(a[0][ks], b0, acc[0][0]);
            acc[0][1] = mfma16(a[0][ks], b1, acc[0][1]);
            acc[1][0] = mfma16(a[1][ks], b0, acc[1][0]);
            acc[1][1] = mfma16(a[1][ks], b1, acc[1][1]);
        }
        #pragma unroll
        for (int ri = 0; ri < 2; ri++)
            #pragma unroll
            for (int ci = 0; ci < 2; ci++) {
                int lrow = wr + 16 * ri + (lane >> 4) * 4;
                int col  = nq * 64 + wc + 16 * ci + lr;
                #pragma unroll
                for (int r = 0; r < 4; r++) {
                    float ov = cvt_f(otb2[(size_t)(m0 + lrow + r) * HC + col]);
                    go[lrow + r][col] = cvt_bf(sigm(acc[ri][ci][r]) * ov);
                }
            }
    }
    // ---- out GEMM: [64 rows][K=256] @ powb^T -> 64 cols, + residual ----
    f32x4 acc[2][2] = {};
    for (int k0 = 0; k0 < HC; k0 += 32) {
        __syncthreads();
        *(short8*)&Bl[t >> 2][(t & 3) * 8] = *(const short8*)&Bo[(size_t)(t >> 2) * HC + k0 + (t & 3) * 8];
        __syncthreads();
        short8 a0 = *(const short8*)&go[wr + lr][k0 + lk];
        short8 a1 = *(const short8*)&go[wr + 16 + lr][k0 + lk];
        short8 b0 = *(const short8*)&Bl[wc + lr][lk];
        short8 b1 = *(const short8*)&Bl[wc + 16 + lr][lk];
        acc[0][0] = mfma16(a0, b0, acc[0][0]);
        acc[0][1] = mfma16(a0, b1, acc[0][1]);
        acc[1][0] = mfma16(a1, b0, acc[1][0]);
        acc[1][1] = mfma16(a1, b1, acc[1][1]);
    }
    #pragma unroll
    for (int ri = 0; ri < 2; ri++)
        #pragma unroll
        for (int ci = 0; ci < 2; ci++) {
            int row0 = m0 + wr + 16 * ri + (lane >> 4) * 4;
            int col  = wc + 16 * ci + lr;
            #pragma unroll
            for (int r = 0; r < 4; r++) {
                size_t idx = (size_t)(row0 + r) * DM + col;
                mout[idx] = m[idx] + acc[ri][ci][r];
            }
        }
}

// ---------------- K6: fused SwiGLU transition (fc1/fc2 + silu*mul + fc3 + residual) ----------------
__global__ __launch_bounds__(256) void k_fctrans(const ushort_t* __restrict__ A,   // tn_bf [NROWS][64]
                                                 const ushort_t* __restrict__ B1,  // f1b [256][64]
                                                 const ushort_t* __restrict__ B2,  // f2b [256][64]
                                                 const ushort_t* __restrict__ B3,  // f3b [64][256]
                                                 float* __restrict__ mio) {
    int m0 = blockIdx.x * 64;
    __shared__ ushort_t Al[64][72];
    __shared__ ushort_t B1l[64][72];
    __shared__ ushort_t B2l[64][72];
    __shared__ ushort_t hhl[64][264];
    int t = threadIdx.x;
    int srow = t >> 2, sko = (t & 3) * 16;
    int wave = t >> 6, lane = t & 63;
    int wr = (wave >> 1) * 32, wc = (wave & 1) * 32;
    int lk = (lane >> 4) * 8, lr = lane & 15;
    {
        const ushort_t* arow = &A[(size_t)(m0 + srow) * DM + sko];
        *(short8*)&Al[srow][sko]     = *(const short8*)&arow[0];
        *(short8*)&Al[srow][sko + 8] = *(const short8*)&arow[8];
    }
    __syncthreads();
    short8 a[2][2];
    a[0][0] = *(const short8*)&Al[wr + lr][lk];
    a[0][1] = *(const short8*)&Al[wr + lr][32 + lk];
    a[1][0] = *(const short8*)&Al[wr + 16 + lr][lk];
    a[1][1] = *(const short8*)&Al[wr + 16 + lr][32 + lk];
    for (int nq = 0; nq < 4; nq++) {
        __syncthreads();
        {
            const ushort_t* b1r = &B1[(size_t)(nq * 64 + srow) * DM + sko];
            const ushort_t* b2r = &B2[(size_t)(nq * 64 + srow) * DM + sko];
            *(short8*)&B1l[srow][sko]     = *(const short8*)&b1r[0];
            *(short8*)&B1l[srow][sko + 8] = *(const short8*)&b1r[8];
            *(short8*)&B2l[srow][sko]     = *(const short8*)&b2r[0];
            *(short8*)&B2l[srow][sko + 8] = *(const short8*)&b2r[8];
        }
        __syncthreads();
        f32x4 acc1[2][2] = {}, acc2[2][2] = {};
        #pragma unroll
        for (int ks = 0; ks < 2; ks++) {
            short8 p0 = *(const short8*)&B1l[wc + lr][ks * 32 + lk];
            short8 p1 = *(const short8*)&B1l[wc + 16 + lr][ks * 32 + lk];
            short8 q0 = *(const short8*)&B2l[wc + lr][ks * 32 + lk];
            short8 q1 = *(const short8*)&B2l[wc + 16 + lr][ks * 32 + lk];
            acc1[0][0] = mfma16(a[0][ks], p0, acc1[0][0]);
            acc1[0][1] = mfma16(a[0][ks], p1, acc1[0][1]);
            acc1[1][0] = mfma16(a[1][ks], p0, acc1[1][0]);
            acc1[1][1] = mfma16(a[1][ks], p1, acc1[1][1]);
            acc2[0][0] = mfma16(a[0][ks], q0, acc2[0][0]);
            acc2[0][1] = mfma16(a[0][ks], q1, acc2[0][1]);
            acc2[1][0] = mfma16(a[1][ks], q0, acc2[1][0]);
            acc2[1][1] = mfma16(a[1][ks], q1, acc2[1][1]);
        }
        #pragma unroll
        for (int ri = 0; ri < 2; ri++)
            #pragma unroll
            for (int ci = 0; ci < 2; ci++) {
                int lrow = wr + 16 * ri + (lane >> 4) * 4;
                int col  = nq * 64 + wc + 16 * ci + lr;
                #pragma unroll
                for (int r = 0; r < 4; r++) {
                    float a1v = acc1[ri][ci][r], a2v = acc2[ri][ci][r];
                    hhl[lrow + r][col] = cvt_bf(a1v * sigm(a1v) * a2v);
                }
            }
    }
    // fc3: [64][256] @ f3b^T -> 64 cols, residual
    f32x4 acc[2][2] = {};
    for (int k0 = 0; k0 < FF; k0 += 32) {
        __syncthreads();
        *(short8*)&B1l[t >> 2][(t & 3) * 8] = *(const short8*)&B3[(size_t)(t >> 2) * FF + k0 + (t & 3) * 8];
        __syncthreads();
        short8 a0 = *(const short8*)&hhl[wr + lr][k0 + lk];
        short8 a1 = *(const short8*)&hhl[wr + 16 + lr][k0 + lk];
        short8 b0 = *(const short8*)&B1l[wc + lr][lk];
        short8 b1 = *(const short8*)&B1l[wc + 16 + lr][lk];
        acc[0][0] = mfma16(a0, b0, acc[0][0]);
        acc[0][1] = mfma16(a0, b1, acc[0][1]);
        acc[1][0] = mfma16(a1, b0, acc[1][0]);
        acc[1][1] = mfma16(a1, b1, acc[1][1]);
    }
    #pragma unroll
    for (int ri = 0; ri < 2; ri++)
        #pragma unroll
        for (int ci = 0; ci < 2; ci++) {
            int row0 = m0 + wr + 16 * ri + (lane >> 4) * 4;
            int col  = wc + 16 * ci + lr;
            #pragma unroll
            for (int r = 0; r < 4; r++)
                mio[(size_t)(row0 + r) * DM + col] += acc[ri][ci][r];
        }
}

// ---------------- K7: a/b projection GEMM + mask -> abuf/bbuf [s][n*32+c] ----------------
__global__ __launch_bounds__(256) void k_ab_mfma(const ushort_t* __restrict__ A,
                                                 const ushort_t* __restrict__ Bt,
                                                 const float* __restrict__ smask,
                                                 ushort_t* __restrict__ abuf,
                                                 ushort_t* __restrict__ bbuf) {
    int m0 = blockIdx.x * 64;
    __shared__ ushort_t Al[64][40];
    __shared__ ushort_t Bl[64][40];
    int t = threadIdx.x;
    int srow = t >> 2, sko = (t & 3) * 8;
    int wave = t >> 6, lane = t & 63;
    int wr = (wave >> 1) * 32, wc = (wave & 1) * 32;
    int lk = (lane >> 4) * 8, lr = lane & 15;
    f32x4 acc[2][2] = {};
    for (int k0 = 0; k0 < DM; k0 += 32) {
        *(short8*)&Al[srow][sko] = *(const short8*)&A[(size_t)(m0 + srow) * DM + k0 + sko];
        *(short8*)&Bl[srow][sko] = *(const short8*)&Bt[(size_t)srow * DM + k0 + sko];
        __syncthreads();
        short8 a0 = *(const short8*)&Al[wr + lr][lk];
        short8 a1 = *(const short8*)&Al[wr + 16 + lr][lk];
        short8 b0 = *(const short8*)&Bl[wc + lr][lk];
        short8 b1 = *(const short8*)&Bl[wc + 16 + lr][lk];
        acc[0][0] = mfma16(a0, b0, acc[0][0]);
        acc[0][1] = mfma16(a0, b1, acc[0][1]);
        acc[1][0] = mfma16(a1, b0, acc[1][0]);
        acc[1][1] = mfma16(a1, b1, acc[1][1]);
        __syncthreads();
    }
    #pragma unroll
    for (int ri = 0; ri < 2; ri++)
        #pragma unroll
        for (int ci = 0; ci < 2; ci++) {
            int row0 = m0 + wr + 16 * ri + (lane >> 4) * 4;
            int col  = wc + 16 * ci + lr;               // 0..63
            #pragma unroll
            for (int r = 0; r < 4; r++) {
                int rr = row0 + r;                      // s*NRES+n
                int s = rr / NRES, n = rr % NRES;
                float v = acc[ri][ci][r] * smask[rr];
                if (col < DOP)
                    abuf[(size_t)s * (NRES * DOP) + n * DOP + col] = cvt_bf(v);
                else
                    bbuf[(size_t)s * (NRES * DOP) + n * DOP + (col - DOP)] = cvt_bf(v);
            }
        }
}

// ---------------- K8: mask pair-count Gram tile ----------------
__global__ __launch_bounds__(256) void k_msum(const float* __restrict__ smask,
                                              float* __restrict__ msum) {
    int i0 = blockIdx.y * 64, j0 = blockIdx.x * 64;
    __shared__ float As[16][64];
    __shared__ float Bs[16][64];
    int t = threadIdx.x;
    int ty = t >> 4, tx = t & 15;
    float acc[4][4] = {};
    for (int k0 = 0; k0 < NSEQ; k0 += 16) {
        int kk = t >> 4, x4 = (t & 15) * 4;
        *(float4*)&As[kk][x4] = *(const float4*)&smask[(size_t)(k0 + kk) * NRES + i0 + x4];
        *(float4*)&Bs[kk][x4] = *(const float4*)&smask[(size_t)(k0 + kk) * NRES + j0 + x4];
        __syncthreads();
        #pragma unroll
        for (int k = 0; k < 16; k++) {
            float4 a4 = *(const float4*)&As[k][ty * 4];
            float4 b4 = *(const float4*)&Bs[k][tx * 4];
            float ar[4] = {a4.x, a4.y, a4.z, a4.w};
            float br[4] = {b4.x, b4.y, b4.z, b4.w};
            #pragma unroll
            for (int i2 = 0; i2 < 4; i2++)
                #pragma unroll
                for (int j2 = 0; j2 < 4; j2++)
                    acc[i2][j2] += ar[i2] * br[j2];
        }
        __syncthreads();
    }
    #pragma unroll
    for (int r = 0; r < 4; r++) {
        float4 o4 = make_float4(fmaxf(acc[r][0], 1.0f), fmaxf(acc[r][1], 1.0f),
                                fmaxf(acc[r][2], 1.0f), fmaxf(acc[r][3], 1.0f));
        *(float4*)&msum[(size_t)(i0 + ty * 4 + r) * NRES + j0 + tx * 4] = o4;
    }
}

// ---------------- K9: OPM outer GEMM (128x128 tile, gload_lds) ----------------
__global__ __launch_bounds__(256) void k_opm_mfma(const ushort_t* __restrict__ At,
                                                  const ushort_t* __restrict__ Bt,
                                                  ushort_t* __restrict__ opmc) {
    int m0 = blockIdx.y * 128;                  // over ichunk*32 (il,c)
    int n0 = blockIdx.x * 128;                  // over 12288 (j,d)
    __shared__ ushort_t Al[128 * 32];
    __shared__ ushort_t Bl[128 * 32];
    int t = threadIdx.x;
    int w = t >> 6, lane = t & 63;
    int wr = (w >> 1) * 64, wc = (w & 1) * 64;
    int lq = lane >> 4, lr = lane & 15;
    int rS = w * 16 + (lane >> 2);
    int cqs = (((lane & 3) ^ ((rS >> 1) & 3)) << 3);
    f32x4 acc[4][4] = {};
    for (int k0 = 0; k0 < NSEQ; k0 += 32) {
        gld16(&At[(size_t)(m0 + rS)      * NSEQ + k0 + cqs], &Al[(w * 16) * 32]);
        gld16(&At[(size_t)(m0 + 64 + rS) * NSEQ + k0 + cqs], &Al[(64 + w * 16) * 32]);
        gld16(&Bt[(size_t)(n0 + rS)      * NSEQ + k0 + cqs], &Bl[(w * 16) * 32]);
        gld16(&Bt[(size_t)(n0 + 64 + rS) * NSEQ + k0 + cqs], &Bl[(64 + w * 16) * 32]);
        __syncthreads();
        short8 af[4], bf2[4];
        #pragma unroll
        for (int i = 0; i < 4; i++) {
            int ra = wr + 16 * i + lr;
            int rb = wc + 16 * i + lr;
            af[i]  = *(const short8*)&Al[ra * 32 + ((lq ^ ((ra >> 1) & 3)) << 3)];
            bf2[i] = *(const short8*)&Bl[rb * 32 + ((lq ^ ((rb >> 1) & 3)) << 3)];
        }
        #pragma unroll
        for (int ri = 0; ri < 4; ri++)
            #pragma unroll
            for (int ci = 0; ci < 4; ci++)
                acc[ri][ci] = mfma16(af[ri], bf2[ci], acc[ri][ci]);
        __syncthreads();
    }
    #pragma unroll
    for (int ri = 0; ri < 4; ri++)
        #pragma unroll
        for (int ci = 0; ci < 4; ci++) {
            int mb = m0 + wr + 16 * ri + (lane >> 4) * 4;
            int n  = n0 + wc + 16 * ci + lr;
            int j = n >> 5, dd = n & 31;
            #pragma unroll
            for (int r = 0; r < 4; r++) {
                int mm = mb + r;
                int il = mm >> 5, c = mm & 31;
                opmc[((size_t)(il * NRES + j) << 10) + (c << 5) + dd] = cvt_bf(acc[ri][ci][r]);
            }
        }
}

// ---------------- K10: OPM projection + residual (128x128 tile, gload_lds) ----------------
__global__ __launch_bounds__(256) void k_proj_mfma(const ushort_t* __restrict__ A,
                                                   const ushort_t* __restrict__ Bt,
                                                   const float* __restrict__ opB,
                                                   const float* __restrict__ msum,
                                                   const float* __restrict__ zin,
                                                   float* __restrict__ zout,
                                                   int ib) {
    int m0 = blockIdx.x * 128;                  // over ichunk*NRES
    __shared__ ushort_t Al[128 * 32];
    __shared__ ushort_t Bl[128 * 32];
    int t = threadIdx.x;
    int w = t >> 6, lane = t & 63;
    int wr = (w >> 1) * 64, wc = (w & 1) * 64;
    int lq = lane >> 4, lr = lane & 15;
    int rS = w * 16 + (lane >> 2);
    int cqs = (((lane & 3) ^ ((rS >> 1) & 3)) << 3);
    f32x4 acc[4][4] = {};
    for (int k0 = 0; k0 < 1024; k0 += 32) {
        gld16(&A [(size_t)(m0 + rS)      * 1024 + k0 + cqs], &Al[(w * 16) * 32]);
        gld16(&A [(size_t)(m0 + 64 + rS) * 1024 + k0 + cqs], &Al[(64 + w * 16) * 32]);
        gld16(&Bt[(size_t)(rS)           * 1024 + k0 + cqs], &Bl[(w * 16) * 32]);
        gld16(&Bt[(size_t)(64 + rS)      * 1024 + k0 + cqs], &Bl[(64 + w * 16) * 32]);
        __syncthreads();
        short8 af[4], bf2[4];
        #pragma unroll
        for (int i = 0; i < 4; i++) {
            int ra = wr + 16 * i + lr;
            int rb = wc + 16 * i + lr;
            af[i]  = *(const short8*)&Al[ra * 32 + ((lq ^ ((ra >> 1) & 3)) << 3)];
            bf2[i] = *(const short8*)&Bl[rb * 32 + ((lq ^ ((rb >> 1) & 3)) << 3)];
        }
        #pragma unroll
        for (int ri = 0; ri < 4; ri++)
            #pragma unroll
            for (int ci = 0; ci < 4; ci++)
                acc[ri][ci] = mfma16(af[ri], bf2[ci], acc[ri][ci]);
        __syncthreads();
    }
    #pragma unroll
    for (int ri = 0; ri < 4; ri++)
        #pragma unroll
        for (int ci = 0; ci < 4; ci++) {
            int row0 = m0 + wr + 16 * ri + (lane >> 4) * 4;
            int col  = wc + 16 * ci + lr;               // 0..127 = full DZ
            #pragma unroll
            for (int r = 0; r < 4; r++) {
                size_t G = (size_t)ib * NRES + row0 + r;
                float inv = 1.0f / msum[G];
                zout[G * DZ + col] = zin[G * DZ + col] + acc[ri][ci][r] * inv + opB[col];
            }
        }
}

// ---------------- launch ----------------
extern "C" void kernel_launch(void* const* d_in, const int* in_sizes, int n_in,
                              void* d_out, int out_size, void* d_ws, size_t ws_size,
                              hipStream_t stream) {
    const float* z     = (const float*)d_in[0];
    const float* m     = (const float*)d_in[1];
    const float* tmask = (const float*)d_in[2];
    const float* smask = (const float*)d_in[3];
    const float* nzw   = (const float*)d_in[4];
    const float* nzb   = (const float*)d_in[5];
    const float* pzw   = (const float*)d_in[6];
    const float* nmw   = (const float*)d_in[7];
    const float* nmb   = (const float*)d_in[8];
    const float* pmw   = (const float*)d_in[9];
    const float* pgw   = (const float*)d_in[10];
    const float* pow_  = (const float*)d_in[11];
    const float* tnw   = (const float*)d_in[12];
    const float* tnb_  = (const float*)d_in[13];
    const float* f1    = (const float*)d_in[14];
    const float* f2    = (const float*)d_in[15];
    const float* f3    = (const float*)d_in[16];
    const float* onw   = (const float*)d_in[17];
    const float* onb   = (const float*)d_in[18];
    const float* paw   = (const float*)d_in[19];
    const float* pbw   = (const float*)d_in[20];
    const float* opW   = (const float*)d_in[21];
    const float* opB   = (const float*)d_in[22];

    float* zout = (float*)d_out;
    float* mout = zout + ZTOT;

    char* W = (char*)d_ws;
    // fixed low region
    ushort_t* wsb  = (ushort_t*)(W + 4718592);          //  .. 7,077,888 (bf16 softmax wts)
    ushort_t* mnb  = (ushort_t*)(W + 7077888);          //  .. 19,660,800 (12.6MB)
    ushort_t* vtt  = (ushort_t*)(W + 69992448);         //  .. 120,324,096 (50.3MB)
    ushort_t* otb2 = (ushort_t*)(W + 120324096);        //  .. 170,655,744 (50.3MB)
    // aliases in low region
    ushort_t* tn_bf  = vtt;                 // vtt dead after k_attn_mfma
    ushort_t* onb_bf = mnb;                 // mnb dead after k_gateout
    ushort_t* abuf = (ushort_t*)(W + 69992448 + 12582912);   // vtt+12.6MB (dead after k_tr)
    ushort_t* bbuf = (ushort_t*)(W + 69992448 + 18874368);   // vtt+18.9MB

    // OPM layout: single-pass if workspace is large enough (ws=384MiB observed),
    // else proven 4-chunk fallback.
    bool big = ws_size >= 348200000ull;
    int ichunk, nchunks;
    ushort_t *opmc, *abt, *bbt;
    float* msum;
    ushort_t *f1b, *f2b, *f3b, *opWb, *pmwb, *pgwb, *powb, *abwb, *pzwb;
    if (big) {
        ichunk = NRES; nchunks = 1;
        opmc = (ushort_t*)(W + 19660800);               // 302.0MB .. 321,650,688
        abt  = (ushort_t*)(W + 321650688);              // 6.29MB  .. 327,942,144
        bbt  = (ushort_t*)(W + 327942144);              // 6.29MB  .. 334,233,600 (= abt + R*C, matches k_tr z-stride)
        msum = (float*)(W + 346816512);                 // 0.59MB  .. 347,406,336
        f1b  = (ushort_t*)(W + 347406336);
        f2b  = (ushort_t*)(W + 347439104);
        f3b  = (ushort_t*)(W + 347471872);
        opWb = (ushort_t*)(W + 347504640);              // 262,144 .. 347,766,784
        pmwb = (ushort_t*)(W + 347766784);
        pgwb = (ushort_t*)(W + 347799552);
        powb = (ushort_t*)(W + 347832320);
        abwb = (ushort_t*)(W + 347865088);
        pzwb = (ushort_t*)(W + 347873280);              // .. 347,877,376
    } else {
        ichunk = 96; nchunks = 4;
        opmc = (ushort_t*)(W + 19660800);               // 75.5MB needed, spans dead vtR..vtt
        abt  = otb2;                                    // otb2 dead after k_gateout
        bbt  = (ushort_t*)(W + 120324096 + 6291456);
        msum = (float*)(W + 170655744);
        f1b  = (ushort_t*)(W + 171245568);
        f2b  = (ushort_t*)(W + 171278336);
        f3b  = (ushort_t*)(W + 171311104);
        opWb = (ushort_t*)(W + 171343872);
        pmwb = (ushort_t*)(W + 171606016);
        pgwb = (ushort_t*)(W + 171638784);
        powb = (ushort_t*)(W + 171671552);
        abwb = (ushort_t*)(W + 171704320);
        pzwb = (ushort_t*)(W + 171712512);
    }

    k_prep<<<512, 256, 0, stream>>>(f1, f2, f3, opW, pmw, pgw, pow_, paw, pbw, pzw,
                                    f1b, f2b, f3b, opWb, pmwb, pgwb, powb, abwb, pzwb);

    // PairWeightedAveraging
    k_biassm<<<NRES, 256, 0, stream>>>(z, nzw, nzb, pzwb, tmask, wsb);
    k_ln64<<<NROWS / 4, 256, 0, stream>>>(m, nmw, nmb, mnb);
    k_vproj_mfma<<<dim3(HC / 64, NROWS / 64), 256, 0, stream>>>(mnb, pmwb, vtt);
    k_attn_mfma<<<dim3(SD / 128, NRES / 128, NH), 256, 0, stream>>>(wsb, vtt, otb2);
    k_gateout<<<NROWS / 64, 256, 0, stream>>>(mnb, pgwb, otb2, powb, m, mout);

    // Transition (fused)
    k_ln64<<<NROWS / 4, 256, 0, stream>>>(mout, tnw, tnb_, tn_bf);
    k_fctrans<<<NROWS / 64, 256, 0, stream>>>(tn_bf, f1b, f2b, f3b, mout);

    // OuterProductMean
    k_ln64<<<NROWS / 4, 256, 0, stream>>>(mout, onw, onb, onb_bf);
    k_ab_mfma<<<NROWS / 64, 256, 0, stream>>>(onb_bf, abwb, smask, abuf, bbuf);
    k_tr<<<dim3((NRES * DOP) / 64, NSEQ / 64, 2), 256, 0, stream>>>(abuf, abt, NSEQ, NRES * DOP);
    k_msum<<<dim3(NRES / 64, NRES / 64), 256, 0, stream>>>(smask, msum);
    for (int cb = 0; cb < nchunks; cb++) {
        int ib = cb * ichunk;
        const ushort_t* Achunk = abt + (size_t)(ib * DOP) * NSEQ;
        k_opm_mfma<<<dim3((NRES * DOP) / 128, (ichunk * DOP) / 128), 256, 0, stream>>>(Achunk, bbt, opmc);
        k_proj_mfma<<<(ichunk * NRES) / 128, 256, 0, stream>>>(opmc, opWb, opB, msum, z, zout, ib);
    }
}